// Round 1
// baseline (11884.640 us; speedup 1.0000x reference)
//
#include <hip/hip_runtime.h>
#include <math.h>

// ---------------- constants (problem shapes) ----------------
#define B_    2
#define SSRC_ 4093
#define D_    768
#define H_    12
#define DH_   64
#define FF_   3072
#define NG_   3
#define W_    256
#define S_    4096
#define NC_   16

// ---------------- helpers ----------------
__device__ __forceinline__ float block_sum(float v, float* red) {
    int tid = threadIdx.x;
    red[tid] = v;
    __syncthreads();
#pragma unroll
    for (int off = 128; off >= 1; off >>= 1) {
        if (tid < off) red[tid] += red[tid + off];
        __syncthreads();
    }
    float r = red[0];
    __syncthreads();
    return r;
}

__device__ __forceinline__ float block_max(float v, float* red) {
    int tid = threadIdx.x;
    red[tid] = v;
    __syncthreads();
#pragma unroll
    for (int off = 128; off >= 1; off >>= 1) {
        if (tid < off) red[tid] = fmaxf(red[tid], red[tid + off]);
        __syncthreads();
    }
    float r = red[0];
    __syncthreads();
    return r;
}

__device__ __forceinline__ float dot64(const float* qv, const float* __restrict__ kp) {
    float s = 0.f;
#pragma unroll
    for (int d = 0; d < DH_; d += 4) {
        float4 t = *(const float4*)(kp + d);
        s += qv[d] * t.x + qv[d + 1] * t.y + qv[d + 2] * t.z + qv[d + 3] * t.w;
    }
    return s;
}

// ---------------- embedding + LN ----------------
__global__ __launch_bounds__(256) void embed_ln_k(
    const int* __restrict__ src, const float* __restrict__ we,
    const float* __restrict__ pe, const float* __restrict__ gam,
    const float* __restrict__ bet, float* __restrict__ X) {
    __shared__ float red[256];
    int row = blockIdx.x;           // b*S + s
    int b = row >> 12;              // S_ = 4096
    int s = row & (S_ - 1);
    int tid = threadIdx.x;
    int id = (s < NG_) ? (50261 + s) : src[b * SSRC_ + (s - NG_)];
    const float* wr = we + (size_t)id * D_;
    const float* pr = pe + (size_t)s * D_;
    float v[3];
    float lsum = 0.f;
#pragma unroll
    for (int j = 0; j < 3; ++j) {
        int c = tid + j * 256;
        v[j] = wr[c] + pr[c];
        lsum += v[j];
    }
    float mu = block_sum(lsum, red) * (1.0f / 768.0f);
    float ls2 = 0.f;
#pragma unroll
    for (int j = 0; j < 3; ++j) { float d = v[j] - mu; ls2 += d * d; }
    float var = block_sum(ls2, red) * (1.0f / 768.0f);
    float rs = rsqrtf(var + 1e-5f);
    float* xr = X + (size_t)row * D_;
#pragma unroll
    for (int j = 0; j < 3; ++j) {
        int c = tid + j * 256;
        xr[c] = (v[j] - mu) * rs * gam[c] + bet[c];
    }
}

// ---------------- residual + LN : out[r] = LN(x[r] + y[r]) ----------------
__global__ __launch_bounds__(256) void residual_ln_k(
    const float* __restrict__ x, const float* __restrict__ y,
    const float* __restrict__ gam, const float* __restrict__ bet,
    float* __restrict__ out) {
    __shared__ float red[256];
    int row = blockIdx.x;
    int tid = threadIdx.x;
    const float* xr = x + (size_t)row * D_;
    const float* yr = y + (size_t)row * D_;
    float v[3];
    float lsum = 0.f;
#pragma unroll
    for (int j = 0; j < 3; ++j) {
        int c = tid + j * 256;
        v[j] = xr[c] + yr[c];
        lsum += v[j];
    }
    float mu = block_sum(lsum, red) * (1.0f / 768.0f);
    float ls2 = 0.f;
#pragma unroll
    for (int j = 0; j < 3; ++j) { float d = v[j] - mu; ls2 += d * d; }
    float var = block_sum(ls2, red) * (1.0f / 768.0f);
    float rs = rsqrtf(var + 1e-5f);
    float* orow = out + (size_t)row * D_;
#pragma unroll
    for (int j = 0; j < 3; ++j) {
        int c = tid + j * 256;
        orow[c] = (v[j] - mu) * rs * gam[c] + bet[c];
    }
}

// ---------------- tiled f32 GEMM : C[M,N] = A[M,K] @ Wm[K,N] + bias ----------------
// block 256 threads, 128x128 tile, BK=16, 8x8 per thread
__global__ __launch_bounds__(256) void gemm_bias_k(
    const float* __restrict__ A, const float* __restrict__ Wm,
    const float* __restrict__ bias, float* __restrict__ C,
    int M, int N, int K) {
    __shared__ float As[16][128];
    __shared__ float Bs[16][128];
    int tid = threadIdx.x;
    int bx = blockIdx.x, by = blockIdx.y;
    int tx = tid & 15, ty = tid >> 4;
    float acc[8][8];
#pragma unroll
    for (int i = 0; i < 8; ++i)
#pragma unroll
        for (int j = 0; j < 8; ++j) acc[i][j] = 0.f;

    for (int kt = 0; kt < K; kt += 16) {
#pragma unroll
        for (int i = 0; i < 2; ++i) {
            int f4 = tid + i * 256;
            // A: 128 rows x 16 k
            int m = f4 >> 2;
            int ks = (f4 & 3) * 4;
            int gr = by * 128 + m;
            float4 va = make_float4(0.f, 0.f, 0.f, 0.f);
            if (gr < M) va = *(const float4*)(A + (size_t)gr * K + kt + ks);
            As[ks + 0][m] = va.x;
            As[ks + 1][m] = va.y;
            As[ks + 2][m] = va.z;
            As[ks + 3][m] = va.w;
            // B: 16 rows x 128 cols
            int r = f4 >> 5;
            int c4 = (f4 & 31) * 4;
            float4 vb = *(const float4*)(Wm + (size_t)(kt + r) * N + bx * 128 + c4);
            *(float4*)&Bs[r][c4] = vb;
        }
        __syncthreads();
#pragma unroll
        for (int kk = 0; kk < 16; ++kk) {
            float a[8], bb[8];
            *(float4*)&a[0] = *(const float4*)&As[kk][ty * 8];
            *(float4*)&a[4] = *(const float4*)&As[kk][ty * 8 + 4];
            *(float4*)&bb[0] = *(const float4*)&Bs[kk][tx * 8];
            *(float4*)&bb[4] = *(const float4*)&Bs[kk][tx * 8 + 4];
#pragma unroll
            for (int i = 0; i < 8; ++i)
#pragma unroll
                for (int j = 0; j < 8; ++j) acc[i][j] += a[i] * bb[j];
        }
        __syncthreads();
    }
#pragma unroll
    for (int i = 0; i < 8; ++i) {
        int row = by * 128 + ty * 8 + i;
        if (row < M) {
#pragma unroll
            for (int j = 0; j < 8; j += 4) {
                int col = bx * 128 + tx * 8 + j;
                float4 o;
                o.x = acc[i][j + 0] + bias[col + 0];
                o.y = acc[i][j + 1] + bias[col + 1];
                o.z = acc[i][j + 2] + bias[col + 2];
                o.w = acc[i][j + 3] + bias[col + 3];
                *(float4*)(C + (size_t)row * N + col) = o;
            }
        }
    }
}

// ---------------- sliding-window local attention ----------------
// grid (NC, H, B), 256 threads = 1 query each. Q,K,V,O layout (B,S,D) with col h*64+d.
__global__ __launch_bounds__(256, 1) void local_attn_k(
    const float* __restrict__ Q, const float* __restrict__ K,
    const float* __restrict__ V, float* __restrict__ O) {
    int c = blockIdx.x, h = blockIdx.y, b = blockIdx.z;
    int q = threadIdx.x;
    int qa = c * W_ + q;
    float qv[DH_];
    const float* qp = Q + (size_t)(b * S_ + qa) * D_ + h * DH_;
#pragma unroll
    for (int d = 0; d < DH_; d += 4) {
        float4 t = *(const float4*)(qp + d);
        qv[d] = t.x * 0.125f; qv[d + 1] = t.y * 0.125f;
        qv[d + 2] = t.z * 0.125f; qv[d + 3] = t.w * 0.125f;
    }
    int klo = qa - W_; if (klo < NG_) klo = NG_;
    int khi = qa + W_; if (khi > S_ - 1) khi = S_ - 1;
    const float* Kb = K + (size_t)b * S_ * D_ + h * DH_;
    const float* Vb = V + (size_t)b * S_ * D_ + h * DH_;
    // pass 1: running max + denominator
    float m = -1e30f, l = 0.f;
#pragma unroll
    for (int g = 0; g < NG_; ++g) {
        float s = dot64(qv, Kb + (size_t)g * D_);
        if (s > m) { l = l * __expf(m - s) + 1.0f; m = s; }
        else l += __expf(s - m);
    }
    for (int kp = klo; kp <= khi; ++kp) {
        float s = dot64(qv, Kb + (size_t)kp * D_);
        if (s > m) { l = l * __expf(m - s) + 1.0f; m = s; }
        else l += __expf(s - m);
    }
    float linv = 1.0f / l;
    float out[DH_];
#pragma unroll
    for (int d = 0; d < DH_; ++d) out[d] = 0.f;
    // pass 2: accumulate
#pragma unroll
    for (int g = 0; g < NG_; ++g) {
        float p = __expf(dot64(qv, Kb + (size_t)g * D_) - m) * linv;
        const float* vp = Vb + (size_t)g * D_;
#pragma unroll
        for (int d = 0; d < DH_; d += 4) {
            float4 t = *(const float4*)(vp + d);
            out[d] += p * t.x; out[d + 1] += p * t.y;
            out[d + 2] += p * t.z; out[d + 3] += p * t.w;
        }
    }
    for (int kp = klo; kp <= khi; ++kp) {
        float p = __expf(dot64(qv, Kb + (size_t)kp * D_) - m) * linv;
        const float* vp = Vb + (size_t)kp * D_;
#pragma unroll
        for (int d = 0; d < DH_; d += 4) {
            float4 t = *(const float4*)(vp + d);
            out[d] += p * t.x; out[d + 1] += p * t.y;
            out[d + 2] += p * t.z; out[d + 3] += p * t.w;
        }
    }
    float* op = O + (size_t)(b * S_ + qa) * D_ + h * DH_;
#pragma unroll
    for (int d = 0; d < DH_; d += 4) {
        float4 t;
        t.x = out[d]; t.y = out[d + 1]; t.z = out[d + 2]; t.w = out[d + 3];
        *(float4*)(op + d) = t;
    }
}

// ---------------- global attention (3 queries attend to all S) ----------------
// grid (NG, H, B). qg compact (B*NG, D). out row index = b*rowStride + g.
__global__ __launch_bounds__(256) void global_attn_k(
    const float* __restrict__ qg, const float* __restrict__ KG,
    const float* __restrict__ VG, float* __restrict__ outp, int rowStride) {
    __shared__ float sc[S_];
    __shared__ float qs[DH_];
    __shared__ float red[256];
    int g = blockIdx.x, h = blockIdx.y, b = blockIdx.z;
    int tid = threadIdx.x;
    if (tid < DH_) qs[tid] = qg[(size_t)(b * NG_ + g) * D_ + h * DH_ + tid] * 0.125f;
    __syncthreads();
    float mloc = -1e30f;
    for (int s0 = tid; s0 < S_; s0 += 256) {
        const float* kp = KG + (size_t)(b * S_ + s0) * D_ + h * DH_;
        float acc = 0.f;
#pragma unroll
        for (int d = 0; d < DH_; d += 4) {
            float4 t = *(const float4*)(kp + d);
            acc += qs[d] * t.x + qs[d + 1] * t.y + qs[d + 2] * t.z + qs[d + 3] * t.w;
        }
        sc[s0] = acc;
        mloc = fmaxf(mloc, acc);
    }
    float m = block_max(mloc, red);
    float lsum = 0.f;
    for (int s0 = tid; s0 < S_; s0 += 256) {
        float e = __expf(sc[s0] - m);
        sc[s0] = e;
        lsum += e;
    }
    float l = block_sum(lsum, red);
    if (tid < DH_) {
        float linv = 1.0f / l;
        const float* vp = VG + (size_t)(b * S_) * D_ + h * DH_ + tid;
        float a0 = 0.f, a1 = 0.f, a2 = 0.f, a3 = 0.f;
        for (int s0 = 0; s0 < S_; s0 += 4) {
            a0 += sc[s0 + 0] * vp[(size_t)(s0 + 0) * D_];
            a1 += sc[s0 + 1] * vp[(size_t)(s0 + 1) * D_];
            a2 += sc[s0 + 2] * vp[(size_t)(s0 + 2) * D_];
            a3 += sc[s0 + 3] * vp[(size_t)(s0 + 3) * D_];
        }
        outp[(size_t)(b * rowStride + g) * D_ + h * DH_ + tid] = (a0 + a1 + a2 + a3) * linv;
    }
}

// ---------------- elementwise exact GELU ----------------
__global__ void gelu_k(float* __restrict__ x, int n) {
    int i = blockIdx.x * blockDim.x + threadIdx.x;
    int stride = gridDim.x * blockDim.x;
    for (; i < n; i += stride) {
        float v = x[i];
        x[i] = 0.5f * v * (1.0f + erff(v * 0.70710678118654752f));
    }
}

// ---------------- gather the 6 global-token rows ----------------
__global__ void gather6_k(const float* __restrict__ X, float* __restrict__ xg) {
    int r = blockIdx.x;  // b*NG + g
    int b = r / NG_, g = r % NG_;
    for (int c = threadIdx.x; c < D_; c += blockDim.x)
        xg[(size_t)r * D_ + c] = X[(size_t)(b * S_ + g) * D_ + c];
}

// ---------------- classifier heads ----------------
__global__ __launch_bounds__(256) void classifier_k(
    const float* __restrict__ x26, const float* __restrict__ cw,
    const float* __restrict__ cb, float* __restrict__ out) {
    __shared__ float red[256];
    int tid = threadIdx.x;
    for (int i = 0; i < 3; ++i) {
        for (int b = 0; b < B_; ++b) {
            const float* xr = x26 + (size_t)(b * NG_ + i) * D_;
            const float* wr = cw + (size_t)i * D_;
            float p = 0.f;
            for (int c = tid; c < D_; c += 256) p += xr[c] * wr[c];
            float dotv = block_sum(p, red);
            if (tid == 0) out[i * B_ + b] = 1.0f / (1.0f + __expf(-(dotv + cb[i])));
        }
    }
    if (tid == 0) { out[6] = 1.0f; out[7] = 1.0f; }
}

// ---------------- host launcher ----------------
extern "C" void kernel_launch(void* const* d_in, const int* in_sizes, int n_in,
                              void* d_out, int out_size, void* d_ws, size_t ws_size,
                              hipStream_t stream) {
    const int*   src     = (const int*)d_in[0];
    const float* word_emb = (const float*)d_in[3];
    const float* pos_emb  = (const float*)d_in[4];
    const float* emb_ln   = (const float*)d_in[5];
    const float* attn_w   = (const float*)d_in[6];
    const float* attn_b   = (const float*)d_in[7];
    const float* ln_p     = (const float*)d_in[8];
    const float* ffn_w1   = (const float*)d_in[9];
    const float* ffn_b1   = (const float*)d_in[10];
    const float* ffn_w2   = (const float*)d_in[11];
    const float* ffn_b2   = (const float*)d_in[12];
    const float* cls_w    = (const float*)d_in[13];
    const float* cls_b    = (const float*)d_in[14];
    float* out = (float*)d_out;

    const size_t NT = (size_t)B_ * S_ * D_;  // 6291456
    float* X  = (float*)d_ws;
    float* P1 = X + NT;   // Q / KG / ffn2-out
    float* P2 = P1 + NT;  // K / VG
    float* P3 = P2 + NT;  // V / attn-proj
    float* P4 = P3 + NT;  // attnout / xa
    float* HC = P4 + NT;  // ffn hidden chunk (2048 x 3072 == NT)
    float* SB = HC + NT;  // small buffers
    float* xg  = SB;            // 6 x 768
    float* qg6 = xg + 6 * D_;   // 6 x 768
    float* og6 = qg6 + 6 * D_;  // 6 x 768
    float* pr6 = og6 + 6 * D_;  // 6 x 768
    float* xa6 = pr6 + 6 * D_;  // 6 x 768
    float* h6  = xa6 + 6 * D_;  // 6 x 3072
    float* f6  = h6 + 6 * FF_;  // 6 x 768
    float* x26 = f6 + 6 * D_;   // 6 x 768

    const int M = B_ * S_;  // 8192
    dim3 blk(256);

    auto aw = [&](int l, int i) { return attn_w + ((size_t)(l * 7 + i)) * D_ * D_; };
    auto ab = [&](int l, int i) { return attn_b + (size_t)(l * 7 + i) * D_; };
    auto lnp = [&](int l, int i) { return ln_p + (size_t)(l * 4 + i) * D_; };

    // ---- embedding + LN ----
    embed_ln_k<<<M, blk, 0, stream>>>(src, word_emb, pos_emb, emb_ln, emb_ln + D_, X);

    // ================= layer 0 (full) =================
    gemm_bias_k<<<dim3(D_ / 128, M / 128), blk, 0, stream>>>(X, aw(0, 0), ab(0, 0), P1, M, D_, D_);
    gemm_bias_k<<<dim3(D_ / 128, M / 128), blk, 0, stream>>>(X, aw(0, 1), ab(0, 1), P2, M, D_, D_);
    gemm_bias_k<<<dim3(D_ / 128, M / 128), blk, 0, stream>>>(X, aw(0, 2), ab(0, 2), P3, M, D_, D_);
    local_attn_k<<<dim3(NC_, H_, B_), blk, 0, stream>>>(P1, P2, P3, P4);
    // global path (overwrites rows 0..2 of P4)
    gemm_bias_k<<<dim3(D_ / 128, M / 128), blk, 0, stream>>>(X, aw(0, 4), ab(0, 4), P1, M, D_, D_);
    gemm_bias_k<<<dim3(D_ / 128, M / 128), blk, 0, stream>>>(X, aw(0, 5), ab(0, 5), P2, M, D_, D_);
    gather6_k<<<B_ * NG_, blk, 0, stream>>>(X, xg);
    gemm_bias_k<<<dim3(D_ / 128, 1), blk, 0, stream>>>(xg, aw(0, 3), ab(0, 3), qg6, B_ * NG_, D_, D_);
    global_attn_k<<<dim3(NG_, H_, B_), blk, 0, stream>>>(qg6, P1, P2, P4, S_);
    // output projection + LN
    gemm_bias_k<<<dim3(D_ / 128, M / 128), blk, 0, stream>>>(P4, aw(0, 6), ab(0, 6), P3, M, D_, D_);
    residual_ln_k<<<M, blk, 0, stream>>>(X, P3, lnp(0, 0), lnp(0, 1), P4);  // xa -> P4
    // FFN in 4 row-chunks of 2048
    for (int ch = 0; ch < 4; ++ch) {
        const float* xac = P4 + (size_t)ch * 2048 * D_;
        gemm_bias_k<<<dim3(FF_ / 128, 2048 / 128), blk, 0, stream>>>(xac, ffn_w1, ffn_b1, HC, 2048, FF_, D_);
        gelu_k<<<4096, blk, 0, stream>>>(HC, 2048 * FF_);
        gemm_bias_k<<<dim3(D_ / 128, 2048 / 128), blk, 0, stream>>>(HC, ffn_w2, ffn_b2, P1 + (size_t)ch * 2048 * D_, 2048, D_, FF_);
    }
    residual_ln_k<<<M, blk, 0, stream>>>(P4, P1, lnp(0, 2), lnp(0, 3), X);  // x1 -> X

    // ================= layer 1 (pruned: only global path feeds the classifier) ====
    const float* w1l = ffn_w1 + (size_t)1 * D_ * FF_;
    const float* b1l = ffn_b1 + (size_t)1 * FF_;
    const float* w2l = ffn_w2 + (size_t)1 * FF_ * D_;
    const float* b2l = ffn_b2 + (size_t)1 * D_;
    gemm_bias_k<<<dim3(D_ / 128, M / 128), blk, 0, stream>>>(X, aw(1, 4), ab(1, 4), P1, M, D_, D_);
    gemm_bias_k<<<dim3(D_ / 128, M / 128), blk, 0, stream>>>(X, aw(1, 5), ab(1, 5), P2, M, D_, D_);
    gather6_k<<<B_ * NG_, blk, 0, stream>>>(X, xg);
    gemm_bias_k<<<dim3(D_ / 128, 1), blk, 0, stream>>>(xg, aw(1, 3), ab(1, 3), qg6, B_ * NG_, D_, D_);
    global_attn_k<<<dim3(NG_, H_, B_), blk, 0, stream>>>(qg6, P1, P2, og6, NG_);
    gemm_bias_k<<<dim3(D_ / 128, 1), blk, 0, stream>>>(og6, aw(1, 6), ab(1, 6), pr6, B_ * NG_, D_, D_);
    residual_ln_k<<<B_ * NG_, blk, 0, stream>>>(xg, pr6, lnp(1, 0), lnp(1, 1), xa6);
    gemm_bias_k<<<dim3(FF_ / 128, 1), blk, 0, stream>>>(xa6, w1l, b1l, h6, B_ * NG_, FF_, D_);
    gelu_k<<<72, blk, 0, stream>>>(h6, B_ * NG_ * FF_);
    gemm_bias_k<<<dim3(D_ / 128, 1), blk, 0, stream>>>(h6, w2l, b2l, f6, B_ * NG_, D_, FF_);
    residual_ln_k<<<B_ * NG_, blk, 0, stream>>>(xa6, f6, lnp(1, 2), lnp(1, 3), x26);
    classifier_k<<<1, blk, 0, stream>>>(x26, cls_w, cls_b, out);
}

// Round 2
// 5748.232 us; speedup vs baseline: 2.0675x; 2.0675x over previous
//
#include <hip/hip_runtime.h>
#include <math.h>

// ---------------- constants (problem shapes) ----------------
#define B_    2
#define SSRC_ 4093
#define D_    768
#define H_    12
#define DH_   64
#define FF_   3072
#define NG_   3
#define W_    256
#define S_    4096
#define NC_   16
#define TK_   120   // key-tile size for local attention (2*120*64*4 = 61440 B LDS)

// ---------------- helpers ----------------
__device__ __forceinline__ float block_sum(float v, float* red) {
    int tid = threadIdx.x;
    red[tid] = v;
    __syncthreads();
#pragma unroll
    for (int off = 128; off >= 1; off >>= 1) {
        if (tid < off) red[tid] += red[tid + off];
        __syncthreads();
    }
    float r = red[0];
    __syncthreads();
    return r;
}

__device__ __forceinline__ float block_max(float v, float* red) {
    int tid = threadIdx.x;
    red[tid] = v;
    __syncthreads();
#pragma unroll
    for (int off = 128; off >= 1; off >>= 1) {
        if (tid < off) red[tid] = fmaxf(red[tid], red[tid + off]);
        __syncthreads();
    }
    float r = red[0];
    __syncthreads();
    return r;
}

__device__ __forceinline__ float dot64(const float* qv, const float* __restrict__ kp) {
    float s = 0.f;
#pragma unroll
    for (int d = 0; d < DH_; d += 4) {
        float4 t = *(const float4*)(kp + d);
        s += qv[d] * t.x + qv[d + 1] * t.y + qv[d + 2] * t.z + qv[d + 3] * t.w;
    }
    return s;
}

// ---------------- embedding + LN ----------------
__global__ __launch_bounds__(256) void embed_ln_k(
    const int* __restrict__ src, const float* __restrict__ we,
    const float* __restrict__ pe, const float* __restrict__ gam,
    const float* __restrict__ bet, float* __restrict__ X) {
    __shared__ float red[256];
    int row = blockIdx.x;           // b*S + s
    int b = row >> 12;              // S_ = 4096
    int s = row & (S_ - 1);
    int tid = threadIdx.x;
    int id = (s < NG_) ? (50261 + s) : src[b * SSRC_ + (s - NG_)];
    const float* wr = we + (size_t)id * D_;
    const float* pr = pe + (size_t)s * D_;
    float v[3];
    float lsum = 0.f;
#pragma unroll
    for (int j = 0; j < 3; ++j) {
        int c = tid + j * 256;
        v[j] = wr[c] + pr[c];
        lsum += v[j];
    }
    float mu = block_sum(lsum, red) * (1.0f / 768.0f);
    float ls2 = 0.f;
#pragma unroll
    for (int j = 0; j < 3; ++j) { float d = v[j] - mu; ls2 += d * d; }
    float var = block_sum(ls2, red) * (1.0f / 768.0f);
    float rs = rsqrtf(var + 1e-5f);
    float* xr = X + (size_t)row * D_;
#pragma unroll
    for (int j = 0; j < 3; ++j) {
        int c = tid + j * 256;
        xr[c] = (v[j] - mu) * rs * gam[c] + bet[c];
    }
}

// ---------------- residual + LN : out[r] = LN(x[r] + y[r]) ----------------
__global__ __launch_bounds__(256) void residual_ln_k(
    const float* __restrict__ x, const float* __restrict__ y,
    const float* __restrict__ gam, const float* __restrict__ bet,
    float* __restrict__ out) {
    __shared__ float red[256];
    int row = blockIdx.x;
    int tid = threadIdx.x;
    const float* xr = x + (size_t)row * D_;
    const float* yr = y + (size_t)row * D_;
    float v[3];
    float lsum = 0.f;
#pragma unroll
    for (int j = 0; j < 3; ++j) {
        int c = tid + j * 256;
        v[j] = xr[c] + yr[c];
        lsum += v[j];
    }
    float mu = block_sum(lsum, red) * (1.0f / 768.0f);
    float ls2 = 0.f;
#pragma unroll
    for (int j = 0; j < 3; ++j) { float d = v[j] - mu; ls2 += d * d; }
    float var = block_sum(ls2, red) * (1.0f / 768.0f);
    float rs = rsqrtf(var + 1e-5f);
    float* orow = out + (size_t)row * D_;
#pragma unroll
    for (int j = 0; j < 3; ++j) {
        int c = tid + j * 256;
        orow[c] = (v[j] - mu) * rs * gam[c] + bet[c];
    }
}

// ---------------- tiled f32 GEMM : C[M,N] = A[M,K] @ Wm[K,N] + bias ----------------
// block 256 threads, 128x128 tile, BK=16, 8x8 per thread
__global__ __launch_bounds__(256) void gemm_bias_k(
    const float* __restrict__ A, const float* __restrict__ Wm,
    const float* __restrict__ bias, float* __restrict__ C,
    int M, int N, int K) {
    __shared__ float As[16][128];
    __shared__ float Bs[16][128];
    int tid = threadIdx.x;
    int bx = blockIdx.x, by = blockIdx.y;
    int tx = tid & 15, ty = tid >> 4;
    float acc[8][8];
#pragma unroll
    for (int i = 0; i < 8; ++i)
#pragma unroll
        for (int j = 0; j < 8; ++j) acc[i][j] = 0.f;

    for (int kt = 0; kt < K; kt += 16) {
#pragma unroll
        for (int i = 0; i < 2; ++i) {
            int f4 = tid + i * 256;
            // A: 128 rows x 16 k
            int m = f4 >> 2;
            int ks = (f4 & 3) * 4;
            int gr = by * 128 + m;
            float4 va = make_float4(0.f, 0.f, 0.f, 0.f);
            if (gr < M) va = *(const float4*)(A + (size_t)gr * K + kt + ks);
            As[ks + 0][m] = va.x;
            As[ks + 1][m] = va.y;
            As[ks + 2][m] = va.z;
            As[ks + 3][m] = va.w;
            // B: 16 rows x 128 cols
            int r = f4 >> 5;
            int c4 = (f4 & 31) * 4;
            float4 vb = *(const float4*)(Wm + (size_t)(kt + r) * N + bx * 128 + c4);
            *(float4*)&Bs[r][c4] = vb;
        }
        __syncthreads();
#pragma unroll
        for (int kk = 0; kk < 16; ++kk) {
            float a[8], bb[8];
            *(float4*)&a[0] = *(const float4*)&As[kk][ty * 8];
            *(float4*)&a[4] = *(const float4*)&As[kk][ty * 8 + 4];
            *(float4*)&bb[0] = *(const float4*)&Bs[kk][tx * 8];
            *(float4*)&bb[4] = *(const float4*)&Bs[kk][tx * 8 + 4];
#pragma unroll
            for (int i = 0; i < 8; ++i)
#pragma unroll
                for (int j = 0; j < 8; ++j) acc[i][j] += a[i] * bb[j];
        }
        __syncthreads();
    }
#pragma unroll
    for (int i = 0; i < 8; ++i) {
        int row = by * 128 + ty * 8 + i;
        if (row < M) {
#pragma unroll
            for (int j = 0; j < 8; j += 4) {
                int col = bx * 128 + tx * 8 + j;
                float4 o;
                o.x = acc[i][j + 0] + bias[col + 0];
                o.y = acc[i][j + 1] + bias[col + 1];
                o.z = acc[i][j + 2] + bias[col + 2];
                o.w = acc[i][j + 3] + bias[col + 3];
                *(float4*)(C + (size_t)row * N + col) = o;
            }
        }
    }
}

// ---------------- sliding-window local attention (LDS-staged flash) ----------------
// grid (NC, H, B), 256 threads = 1 query each. Q,K,V,O layout (B,S,D) col h*64+d.
// Single-pass online softmax; K/V staged through LDS in tiles of TK_ keys.
__global__ __launch_bounds__(256, 2) void local_attn_k(
    const float* __restrict__ Q, const float* __restrict__ K,
    const float* __restrict__ V, float* __restrict__ O) {
    __shared__ float Ks[TK_][DH_];
    __shared__ float Vs[TK_][DH_];
    int c = blockIdx.x, h = blockIdx.y, b = blockIdx.z;
    int tid = threadIdx.x;
    int qa = c * W_ + tid;

    float qv[DH_];
    const float* qp = Q + (size_t)(b * S_ + qa) * D_ + h * DH_;
#pragma unroll
    for (int d = 0; d < DH_; d += 4) {
        float4 t = *(const float4*)(qp + d);
        qv[d] = t.x * 0.125f; qv[d + 1] = t.y * 0.125f;
        qv[d + 2] = t.z * 0.125f; qv[d + 3] = t.w * 0.125f;
    }

    const float* Kb = K + (size_t)b * S_ * D_ + h * DH_;
    const float* Vb = V + (size_t)b * S_ * D_ + h * DH_;

    float m = -1e30f, l = 0.f;
    float out[DH_];
#pragma unroll
    for (int d = 0; d < DH_; ++d) out[d] = 0.f;

    // ---- 3 global keys (rows 0..2), straight from global mem (hot in cache) ----
#pragma unroll
    for (int g = 0; g < NG_; ++g) {
        float s = dot64(qv, Kb + (size_t)g * D_);
        if (s > m) {
            float f = __expf(m - s);
            l *= f;
#pragma unroll
            for (int d = 0; d < DH_; ++d) out[d] *= f;
            m = s;
        }
        float p = __expf(s - m);
        l += p;
        const float* vp = Vb + (size_t)g * D_;
#pragma unroll
        for (int d = 0; d < DH_; d += 4) {
            float4 t = *(const float4*)(vp + d);
            out[d] += p * t.x; out[d + 1] += p * t.y;
            out[d + 2] += p * t.z; out[d + 3] += p * t.w;
        }
    }

    // ---- sliding window via LDS tiles ----
    int klo = qa - W_; if (klo < NG_) klo = NG_;
    int khi = qa + W_; if (khi > S_ - 1) khi = S_ - 1;
    int kstart = c * W_ - W_; if (kstart < NG_) kstart = NG_;
    int kend = c * W_ + 2 * W_ - 1; if (kend > S_ - 1) kend = S_ - 1;

    for (int kt = kstart; kt <= kend; kt += TK_) {
        int cnt = kend - kt + 1; if (cnt > TK_) cnt = TK_;
        __syncthreads();
        // cooperative load: cnt rows x 16 float4 each, for K and V
        int nf4 = cnt * 16;
        for (int i = tid; i < nf4; i += 256) {
            int r = i >> 4;
            int c4 = (i & 15) << 2;
            size_t goff = (size_t)(kt + r) * D_ + c4;
            *(float4*)&Ks[r][c4] = *(const float4*)(Kb + goff);
            *(float4*)&Vs[r][c4] = *(const float4*)(Vb + goff);
        }
        __syncthreads();
        int lo = klo > kt ? klo : kt;
        int hi = khi < kt + cnt - 1 ? khi : kt + cnt - 1;
        for (int t = lo - kt; t <= hi - kt; ++t) {
            float s = 0.f;
#pragma unroll
            for (int d = 0; d < DH_; d += 4) {
                float4 t4 = *(const float4*)&Ks[t][d];
                s += qv[d] * t4.x + qv[d + 1] * t4.y + qv[d + 2] * t4.z + qv[d + 3] * t4.w;
            }
            if (s > m) {
                float f = __expf(m - s);
                l *= f;
#pragma unroll
                for (int d = 0; d < DH_; ++d) out[d] *= f;
                m = s;
            }
            float p = __expf(s - m);
            l += p;
#pragma unroll
            for (int d = 0; d < DH_; d += 4) {
                float4 t4 = *(const float4*)&Vs[t][d];
                out[d] += p * t4.x; out[d + 1] += p * t4.y;
                out[d + 2] += p * t4.z; out[d + 3] += p * t4.w;
            }
        }
    }

    float linv = 1.0f / l;
    float* op = O + (size_t)(b * S_ + qa) * D_ + h * DH_;
#pragma unroll
    for (int d = 0; d < DH_; d += 4) {
        float4 t;
        t.x = out[d] * linv; t.y = out[d + 1] * linv;
        t.z = out[d + 2] * linv; t.w = out[d + 3] * linv;
        *(float4*)(op + d) = t;
    }
}

// ---------------- global attention (3 queries attend to all S) ----------------
// grid (NG, H, B). qg compact (B*NG, D). out row index = b*rowStride + g.
__global__ __launch_bounds__(256) void global_attn_k(
    const float* __restrict__ qg, const float* __restrict__ KG,
    const float* __restrict__ VG, float* __restrict__ outp, int rowStride) {
    __shared__ float sc[S_];
    __shared__ float qs[DH_];
    __shared__ float red[256];
    int g = blockIdx.x, h = blockIdx.y, b = blockIdx.z;
    int tid = threadIdx.x;
    if (tid < DH_) qs[tid] = qg[(size_t)(b * NG_ + g) * D_ + h * DH_ + tid] * 0.125f;
    __syncthreads();
    float mloc = -1e30f;
    for (int s0 = tid; s0 < S_; s0 += 256) {
        const float* kp = KG + (size_t)(b * S_ + s0) * D_ + h * DH_;
        float acc = 0.f;
#pragma unroll
        for (int d = 0; d < DH_; d += 4) {
            float4 t = *(const float4*)(kp + d);
            acc += qs[d] * t.x + qs[d + 1] * t.y + qs[d + 2] * t.z + qs[d + 3] * t.w;
        }
        sc[s0] = acc;
        mloc = fmaxf(mloc, acc);
    }
    float m = block_max(mloc, red);
    float lsum = 0.f;
    for (int s0 = tid; s0 < S_; s0 += 256) {
        float e = __expf(sc[s0] - m);
        sc[s0] = e;
        lsum += e;
    }
    float l = block_sum(lsum, red);
    if (tid < DH_) {
        float linv = 1.0f / l;
        const float* vp = VG + (size_t)(b * S_) * D_ + h * DH_ + tid;
        float a0 = 0.f, a1 = 0.f, a2 = 0.f, a3 = 0.f;
        for (int s0 = 0; s0 < S_; s0 += 4) {
            a0 += sc[s0 + 0] * vp[(size_t)(s0 + 0) * D_];
            a1 += sc[s0 + 1] * vp[(size_t)(s0 + 1) * D_];
            a2 += sc[s0 + 2] * vp[(size_t)(s0 + 2) * D_];
            a3 += sc[s0 + 3] * vp[(size_t)(s0 + 3) * D_];
        }
        outp[(size_t)(b * rowStride + g) * D_ + h * DH_ + tid] = (a0 + a1 + a2 + a3) * linv;
    }
}

// ---------------- elementwise exact GELU ----------------
__global__ void gelu_k(float* __restrict__ x, int n) {
    int i = blockIdx.x * blockDim.x + threadIdx.x;
    int stride = gridDim.x * blockDim.x;
    for (; i < n; i += stride) {
        float v = x[i];
        x[i] = 0.5f * v * (1.0f + erff(v * 0.70710678118654752f));
    }
}

// ---------------- gather the 6 global-token rows ----------------
__global__ void gather6_k(const float* __restrict__ X, float* __restrict__ xg) {
    int r = blockIdx.x;  // b*NG + g
    int b = r / NG_, g = r % NG_;
    for (int c = threadIdx.x; c < D_; c += blockDim.x)
        xg[(size_t)r * D_ + c] = X[(size_t)(b * S_ + g) * D_ + c];
}

// ---------------- classifier heads ----------------
__global__ __launch_bounds__(256) void classifier_k(
    const float* __restrict__ x26, const float* __restrict__ cw,
    const float* __restrict__ cb, float* __restrict__ out) {
    __shared__ float red[256];
    int tid = threadIdx.x;
    for (int i = 0; i < 3; ++i) {
        for (int b = 0; b < B_; ++b) {
            const float* xr = x26 + (size_t)(b * NG_ + i) * D_;
            const float* wr = cw + (size_t)i * D_;
            float p = 0.f;
            for (int c = tid; c < D_; c += 256) p += xr[c] * wr[c];
            float dotv = block_sum(p, red);
            if (tid == 0) out[i * B_ + b] = 1.0f / (1.0f + __expf(-(dotv + cb[i])));
        }
    }
    if (tid == 0) { out[6] = 1.0f; out[7] = 1.0f; }
}

// ---------------- host launcher ----------------
extern "C" void kernel_launch(void* const* d_in, const int* in_sizes, int n_in,
                              void* d_out, int out_size, void* d_ws, size_t ws_size,
                              hipStream_t stream) {
    const int*   src     = (const int*)d_in[0];
    const float* word_emb = (const float*)d_in[3];
    const float* pos_emb  = (const float*)d_in[4];
    const float* emb_ln   = (const float*)d_in[5];
    const float* attn_w   = (const float*)d_in[6];
    const float* attn_b   = (const float*)d_in[7];
    const float* ln_p     = (const float*)d_in[8];
    const float* ffn_w1   = (const float*)d_in[9];
    const float* ffn_b1   = (const float*)d_in[10];
    const float* ffn_w2   = (const float*)d_in[11];
    const float* ffn_b2   = (const float*)d_in[12];
    const float* cls_w    = (const float*)d_in[13];
    const float* cls_b    = (const float*)d_in[14];
    float* out = (float*)d_out;

    const size_t NT = (size_t)B_ * S_ * D_;  // 6291456
    float* X  = (float*)d_ws;
    float* P1 = X + NT;   // Q / KG / ffn2-out
    float* P2 = P1 + NT;  // K / VG
    float* P3 = P2 + NT;  // V / attn-proj
    float* P4 = P3 + NT;  // attnout / xa
    float* HC = P4 + NT;  // ffn hidden chunk (2048 x 3072 == NT)
    float* SB = HC + NT;  // small buffers
    float* xg  = SB;            // 6 x 768
    float* qg6 = xg + 6 * D_;   // 6 x 768
    float* og6 = qg6 + 6 * D_;  // 6 x 768
    float* pr6 = og6 + 6 * D_;  // 6 x 768
    float* xa6 = pr6 + 6 * D_;  // 6 x 768
    float* h6  = xa6 + 6 * D_;  // 6 x 3072
    float* f6  = h6 + 6 * FF_;  // 6 x 768
    float* x26 = f6 + 6 * D_;   // 6 x 768

    const int M = B_ * S_;  // 8192
    dim3 blk(256);

    auto aw = [&](int l, int i) { return attn_w + ((size_t)(l * 7 + i)) * D_ * D_; };
    auto ab = [&](int l, int i) { return attn_b + (size_t)(l * 7 + i) * D_; };
    auto lnp = [&](int l, int i) { return ln_p + (size_t)(l * 4 + i) * D_; };

    // ---- embedding + LN ----
    embed_ln_k<<<M, blk, 0, stream>>>(src, word_emb, pos_emb, emb_ln, emb_ln + D_, X);

    // ================= layer 0 (full) =================
    gemm_bias_k<<<dim3(D_ / 128, M / 128), blk, 0, stream>>>(X, aw(0, 0), ab(0, 0), P1, M, D_, D_);
    gemm_bias_k<<<dim3(D_ / 128, M / 128), blk, 0, stream>>>(X, aw(0, 1), ab(0, 1), P2, M, D_, D_);
    gemm_bias_k<<<dim3(D_ / 128, M / 128), blk, 0, stream>>>(X, aw(0, 2), ab(0, 2), P3, M, D_, D_);
    local_attn_k<<<dim3(NC_, H_, B_), blk, 0, stream>>>(P1, P2, P3, P4);
    // global path (overwrites rows 0..2 of P4)
    gemm_bias_k<<<dim3(D_ / 128, M / 128), blk, 0, stream>>>(X, aw(0, 4), ab(0, 4), P1, M, D_, D_);
    gemm_bias_k<<<dim3(D_ / 128, M / 128), blk, 0, stream>>>(X, aw(0, 5), ab(0, 5), P2, M, D_, D_);
    gather6_k<<<B_ * NG_, blk, 0, stream>>>(X, xg);
    gemm_bias_k<<<dim3(D_ / 128, 1), blk, 0, stream>>>(xg, aw(0, 3), ab(0, 3), qg6, B_ * NG_, D_, D_);
    global_attn_k<<<dim3(NG_, H_, B_), blk, 0, stream>>>(qg6, P1, P2, P4, S_);
    // output projection + LN
    gemm_bias_k<<<dim3(D_ / 128, M / 128), blk, 0, stream>>>(P4, aw(0, 6), ab(0, 6), P3, M, D_, D_);
    residual_ln_k<<<M, blk, 0, stream>>>(X, P3, lnp(0, 0), lnp(0, 1), P4);  // xa -> P4
    // FFN in 4 row-chunks of 2048
    for (int ch = 0; ch < 4; ++ch) {
        const float* xac = P4 + (size_t)ch * 2048 * D_;
        gemm_bias_k<<<dim3(FF_ / 128, 2048 / 128), blk, 0, stream>>>(xac, ffn_w1, ffn_b1, HC, 2048, FF_, D_);
        gelu_k<<<4096, blk, 0, stream>>>(HC, 2048 * FF_);
        gemm_bias_k<<<dim3(D_ / 128, 2048 / 128), blk, 0, stream>>>(HC, ffn_w2, ffn_b2, P1 + (size_t)ch * 2048 * D_, 2048, D_, FF_);
    }
    residual_ln_k<<<M, blk, 0, stream>>>(P4, P1, lnp(0, 2), lnp(0, 3), X);  // x1 -> X

    // ================= layer 1 (pruned: only global path feeds the classifier) ====
    const float* w1l = ffn_w1 + (size_t)1 * D_ * FF_;
    const float* b1l = ffn_b1 + (size_t)1 * FF_;
    const float* w2l = ffn_w2 + (size_t)1 * FF_ * D_;
    const float* b2l = ffn_b2 + (size_t)1 * D_;
    gemm_bias_k<<<dim3(D_ / 128, M / 128), blk, 0, stream>>>(X, aw(1, 4), ab(1, 4), P1, M, D_, D_);
    gemm_bias_k<<<dim3(D_ / 128, M / 128), blk, 0, stream>>>(X, aw(1, 5), ab(1, 5), P2, M, D_, D_);
    gather6_k<<<B_ * NG_, blk, 0, stream>>>(X, xg);
    gemm_bias_k<<<dim3(D_ / 128, 1), blk, 0, stream>>>(xg, aw(1, 3), ab(1, 3), qg6, B_ * NG_, D_, D_);
    global_attn_k<<<dim3(NG_, H_, B_), blk, 0, stream>>>(qg6, P1, P2, og6, NG_);
    gemm_bias_k<<<dim3(D_ / 128, 1), blk, 0, stream>>>(og6, aw(1, 6), ab(1, 6), pr6, B_ * NG_, D_, D_);
    residual_ln_k<<<B_ * NG_, blk, 0, stream>>>(xg, pr6, lnp(1, 0), lnp(1, 1), xa6);
    gemm_bias_k<<<dim3(FF_ / 128, 1), blk, 0, stream>>>(xa6, w1l, b1l, h6, B_ * NG_, FF_, D_);
    gelu_k<<<72, blk, 0, stream>>>(h6, B_ * NG_ * FF_);
    gemm_bias_k<<<dim3(D_ / 128, 1), blk, 0, stream>>>(h6, w2l, b2l, f6, B_ * NG_, D_, FF_);
    residual_ln_k<<<B_ * NG_, blk, 0, stream>>>(xa6, f6, lnp(1, 2), lnp(1, 3), x26);
    classifier_k<<<1, blk, 0, stream>>>(x26, cls_w, cls_b, out);
}

// Round 3
// 2311.802 us; speedup vs baseline: 5.1409x; 2.4865x over previous
//
#include <hip/hip_runtime.h>
#include <hip/hip_bf16.h>
#include <math.h>

// ---------------- constants (problem shapes) ----------------
#define B_    2
#define SSRC_ 4093
#define D_    768
#define H_    12
#define DH_   64
#define FF_   3072
#define NG_   3
#define W_    256
#define S_    4096
#define NC_   16
#define TK_   120   // key-tile size for local attention

typedef __attribute__((ext_vector_type(8))) short frag_ab;   // 8 bf16 (4 VGPRs)
typedef __attribute__((ext_vector_type(4))) float f32x4;     // 4 fp32 acc

// ---------------- helpers ----------------
__device__ __forceinline__ float bflo(unsigned int w) {
    union { float f; unsigned int i; } c; c.i = w << 16; return c.f;
}
__device__ __forceinline__ float bfhi(unsigned int w) {
    union { float f; unsigned int i; } c; c.i = w & 0xffff0000u; return c.f;
}
__device__ __forceinline__ void unp8(uint4 t, float* o) {
    o[0] = bflo(t.x); o[1] = bfhi(t.x); o[2] = bflo(t.y); o[3] = bfhi(t.y);
    o[4] = bflo(t.z); o[5] = bfhi(t.z); o[6] = bflo(t.w); o[7] = bfhi(t.w);
}

__device__ __forceinline__ float block_sum(float v, float* red) {
    int tid = threadIdx.x;
    red[tid] = v;
    __syncthreads();
#pragma unroll
    for (int off = 128; off >= 1; off >>= 1) {
        if (tid < off) red[tid] += red[tid + off];
        __syncthreads();
    }
    float r = red[0];
    __syncthreads();
    return r;
}

__device__ __forceinline__ float block_max(float v, float* red) {
    int tid = threadIdx.x;
    red[tid] = v;
    __syncthreads();
#pragma unroll
    for (int off = 128; off >= 1; off >>= 1) {
        if (tid < off) red[tid] = fmaxf(red[tid], red[tid + off]);
        __syncthreads();
    }
    float r = red[0];
    __syncthreads();
    return r;
}

__device__ __forceinline__ void storeO(float* p, float v) { *p = v; }
__device__ __forceinline__ void storeO(__hip_bfloat16* p, float v) { *p = __float2bfloat16(v); }

// ---------------- embedding + LN (writes f32 X and bf16 Xb) ----------------
__global__ __launch_bounds__(256) void embed_ln_k(
    const int* __restrict__ src, const float* __restrict__ we,
    const float* __restrict__ pe, const float* __restrict__ gam,
    const float* __restrict__ bet, float* __restrict__ X,
    __hip_bfloat16* __restrict__ Xb) {
    __shared__ float red[256];
    int row = blockIdx.x;
    int b = row >> 12;
    int s = row & (S_ - 1);
    int tid = threadIdx.x;
    int id = (s < NG_) ? (50261 + s) : src[b * SSRC_ + (s - NG_)];
    const float* wr = we + (size_t)id * D_;
    const float* pr = pe + (size_t)s * D_;
    float v[3];
    float lsum = 0.f;
#pragma unroll
    for (int j = 0; j < 3; ++j) {
        int c = tid + j * 256;
        v[j] = wr[c] + pr[c];
        lsum += v[j];
    }
    float mu = block_sum(lsum, red) * (1.0f / 768.0f);
    float ls2 = 0.f;
#pragma unroll
    for (int j = 0; j < 3; ++j) { float d = v[j] - mu; ls2 += d * d; }
    float var = block_sum(ls2, red) * (1.0f / 768.0f);
    float rs = rsqrtf(var + 1e-5f);
    float* xr = X + (size_t)row * D_;
    __hip_bfloat16* xbr = Xb + (size_t)row * D_;
#pragma unroll
    for (int j = 0; j < 3; ++j) {
        int c = tid + j * 256;
        float o = (v[j] - mu) * rs * gam[c] + bet[c];
        xr[c] = o;
        xbr[c] = __float2bfloat16(o);
    }
}

// ---------------- residual + LN : out = LN(x + y), optional bf16 mirror ----------------
__global__ __launch_bounds__(256) void residual_ln_k(
    const float* __restrict__ x, const float* __restrict__ y,
    const float* __restrict__ gam, const float* __restrict__ bet,
    float* __restrict__ out, __hip_bfloat16* __restrict__ outb) {
    __shared__ float red[256];
    int row = blockIdx.x;
    int tid = threadIdx.x;
    const float* xr = x + (size_t)row * D_;
    const float* yr = y + (size_t)row * D_;
    float v[3];
    float lsum = 0.f;
#pragma unroll
    for (int j = 0; j < 3; ++j) {
        int c = tid + j * 256;
        v[j] = xr[c] + yr[c];
        lsum += v[j];
    }
    float mu = block_sum(lsum, red) * (1.0f / 768.0f);
    float ls2 = 0.f;
#pragma unroll
    for (int j = 0; j < 3; ++j) { float d = v[j] - mu; ls2 += d * d; }
    float var = block_sum(ls2, red) * (1.0f / 768.0f);
    float rs = rsqrtf(var + 1e-5f);
    float* orow = out + (size_t)row * D_;
    __hip_bfloat16* obr = outb ? outb + (size_t)row * D_ : nullptr;
#pragma unroll
    for (int j = 0; j < 3; ++j) {
        int c = tid + j * 256;
        float o = (v[j] - mu) * rs * gam[c] + bet[c];
        orow[c] = o;
        if (obr) obr[c] = __float2bfloat16(o);
    }
}

// ---------------- transpose-convert: W[K,N] f32 -> WT[N,K] bf16 ----------------
__global__ __launch_bounds__(256) void convt_k(
    const float* __restrict__ W, __hip_bfloat16* __restrict__ WT, int K, int N) {
    __shared__ float tile[32][33];
    int bx = blockIdx.x, by = blockIdx.y;  // bx over N/32, by over K/32
    int tx = threadIdx.x & 31, ty = threadIdx.x >> 5;
#pragma unroll
    for (int i = 0; i < 32; i += 8)
        tile[ty + i][tx] = W[(size_t)(by * 32 + ty + i) * N + bx * 32 + tx];
    __syncthreads();
#pragma unroll
    for (int i = 0; i < 32; i += 8)
        WT[(size_t)(bx * 32 + ty + i) * K + by * 32 + tx] = __float2bfloat16(tile[tx][ty + i]);
}

// ---------------- MFMA GEMM: C[M,N] = A[M,K]bf16 @ BT[N,K]bf16^T + bias ----------------
// EPI: 0 = f32 out, 1 = bf16 out, 2 = bf16 gelu(out)
// M % 128 == 0, N % 128 == 0, K % 32 == 0
template <int EPI>
__global__ __launch_bounds__(256) void mfma_gemm_k(
    const __hip_bfloat16* __restrict__ A, const __hip_bfloat16* __restrict__ BT,
    const float* __restrict__ bias, void* __restrict__ Cout,
    int M, int N, int K) {
    __shared__ __align__(16) __hip_bfloat16 As[4096];  // 128 rows x 32 k
    __shared__ __align__(16) __hip_bfloat16 Bs[4096];  // 128 cols x 32 k
    int tid = threadIdx.x;
    int lane = tid & 63;
    int w = tid >> 6, wr = w >> 1, wc = w & 1;
    int brow = blockIdx.y * 128, bcol = blockIdx.x * 128;
    int r0 = tid >> 2, k0 = (tid & 3) * 8;
    const __hip_bfloat16* Ag0 = A + (size_t)(brow + r0) * K + k0;
    const __hip_bfloat16* Ag1 = Ag0 + (size_t)64 * K;
    const __hip_bfloat16* Bg0 = BT + (size_t)(bcol + r0) * K + k0;
    const __hip_bfloat16* Bg1 = Bg0 + (size_t)64 * K;

    f32x4 acc[4][4];
#pragma unroll
    for (int m = 0; m < 4; ++m)
#pragma unroll
        for (int n = 0; n < 4; ++n) acc[m][n] = (f32x4){0.f, 0.f, 0.f, 0.f};

    int l15 = lane & 15, kb = lane >> 4;
    int aoff = (wr * 64 + l15) * 32 + kb * 8;
    int boff = (wc * 64 + l15) * 32 + kb * 8;

    // prefetch tile 0 into regs
    uint4 pa0 = *(const uint4*)Ag0, pa1 = *(const uint4*)Ag1;
    uint4 pb0 = *(const uint4*)Bg0, pb1 = *(const uint4*)Bg1;

    for (int kt = 0; kt < K; kt += 32) {
        *(uint4*)&As[(size_t)tid * 8] = pa0;
        *(uint4*)&As[(size_t)tid * 8 + 2048] = pa1;
        *(uint4*)&Bs[(size_t)tid * 8] = pb0;
        *(uint4*)&Bs[(size_t)tid * 8 + 2048] = pb1;
        __syncthreads();
        if (kt + 32 < K) {  // issue next-tile loads early; consumed next iter
            pa0 = *(const uint4*)(Ag0 + kt + 32);
            pa1 = *(const uint4*)(Ag1 + kt + 32);
            pb0 = *(const uint4*)(Bg0 + kt + 32);
            pb1 = *(const uint4*)(Bg1 + kt + 32);
        }
        frag_ab af[4], bf[4];
#pragma unroll
        for (int m = 0; m < 4; ++m) af[m] = *(const frag_ab*)&As[aoff + m * 512];
#pragma unroll
        for (int n = 0; n < 4; ++n) bf[n] = *(const frag_ab*)&Bs[boff + n * 512];
#pragma unroll
        for (int m = 0; m < 4; ++m)
#pragma unroll
            for (int n = 0; n < 4; ++n)
                acc[m][n] = __builtin_amdgcn_mfma_f32_16x16x32_bf16(af[m], bf[n], acc[m][n], 0, 0, 0);
        __syncthreads();
    }

    // epilogue: C row = brow + wr*64 + m*16 + (lane>>4)*4 + r ; col = bcol + wc*64 + n*16 + (lane&15)
#pragma unroll
    for (int m = 0; m < 4; ++m) {
        int rowb = brow + wr * 64 + m * 16 + (lane >> 4) * 4;
#pragma unroll
        for (int n = 0; n < 4; ++n) {
            int col = bcol + wc * 64 + n * 16 + l15;
            float bv = bias[col];
#pragma unroll
            for (int r = 0; r < 4; ++r) {
                float v = acc[m][n][r] + bv;
                size_t idx = (size_t)(rowb + r) * N + col;
                if (EPI == 0) {
                    ((float*)Cout)[idx] = v;
                } else if (EPI == 1) {
                    ((__hip_bfloat16*)Cout)[idx] = __float2bfloat16(v);
                } else {
                    float g = 0.5f * v * (1.0f + erff(v * 0.70710678118654752f));
                    ((__hip_bfloat16*)Cout)[idx] = __float2bfloat16(g);
                }
            }
        }
    }
}

// ---------------- f32 tiled GEMM for tiny-M cases ----------------
__global__ __launch_bounds__(256) void gemm_bias_k(
    const float* __restrict__ A, const float* __restrict__ Wm,
    const float* __restrict__ bias, float* __restrict__ C,
    int M, int N, int K) {
    __shared__ float As[16][128];
    __shared__ float Bs[16][128];
    int tid = threadIdx.x;
    int bx = blockIdx.x, by = blockIdx.y;
    int tx = tid & 15, ty = tid >> 4;
    float acc[8][8];
#pragma unroll
    for (int i = 0; i < 8; ++i)
#pragma unroll
        for (int j = 0; j < 8; ++j) acc[i][j] = 0.f;

    for (int kt = 0; kt < K; kt += 16) {
#pragma unroll
        for (int i = 0; i < 2; ++i) {
            int f4 = tid + i * 256;
            int m = f4 >> 2;
            int ks = (f4 & 3) * 4;
            int gr = by * 128 + m;
            float4 va = make_float4(0.f, 0.f, 0.f, 0.f);
            if (gr < M) va = *(const float4*)(A + (size_t)gr * K + kt + ks);
            As[ks + 0][m] = va.x;
            As[ks + 1][m] = va.y;
            As[ks + 2][m] = va.z;
            As[ks + 3][m] = va.w;
            int r = f4 >> 5;
            int c4 = (f4 & 31) * 4;
            float4 vb = *(const float4*)(Wm + (size_t)(kt + r) * N + bx * 128 + c4);
            *(float4*)&Bs[r][c4] = vb;
        }
        __syncthreads();
#pragma unroll
        for (int kk = 0; kk < 16; ++kk) {
            float a[8], bb[8];
            *(float4*)&a[0] = *(const float4*)&As[kk][ty * 8];
            *(float4*)&a[4] = *(const float4*)&As[kk][ty * 8 + 4];
            *(float4*)&bb[0] = *(const float4*)&Bs[kk][tx * 8];
            *(float4*)&bb[4] = *(const float4*)&Bs[kk][tx * 8 + 4];
#pragma unroll
            for (int i = 0; i < 8; ++i)
#pragma unroll
                for (int j = 0; j < 8; ++j) acc[i][j] += a[i] * bb[j];
        }
        __syncthreads();
    }
#pragma unroll
    for (int i = 0; i < 8; ++i) {
        int row = by * 128 + ty * 8 + i;
        if (row < M) {
#pragma unroll
            for (int j = 0; j < 8; j += 4) {
                int col = bx * 128 + tx * 8 + j;
                float4 o;
                o.x = acc[i][j + 0] + bias[col + 0];
                o.y = acc[i][j + 1] + bias[col + 1];
                o.z = acc[i][j + 2] + bias[col + 2];
                o.w = acc[i][j + 3] + bias[col + 3];
                *(float4*)(C + (size_t)row * N + col) = o;
            }
        }
    }
}

// ---------------- sliding-window local attention (bf16 in/out, LDS flash) ----------------
__global__ __launch_bounds__(256) void local_attn_k(
    const __hip_bfloat16* __restrict__ Q, const __hip_bfloat16* __restrict__ K,
    const __hip_bfloat16* __restrict__ V, __hip_bfloat16* __restrict__ O) {
    __shared__ __align__(16) __hip_bfloat16 Ks[TK_][DH_];
    __shared__ __align__(16) __hip_bfloat16 Vs[TK_][DH_];
    int c = blockIdx.x, h = blockIdx.y, b = blockIdx.z;
    int tid = threadIdx.x;
    int qa = c * W_ + tid;

    float qv[DH_];
    const __hip_bfloat16* qp = Q + (size_t)(b * S_ + qa) * D_ + h * DH_;
#pragma unroll
    for (int c8 = 0; c8 < 8; ++c8) {
        uint4 t = *(const uint4*)(qp + c8 * 8);
        float f[8]; unp8(t, f);
#pragma unroll
        for (int j = 0; j < 8; ++j) qv[c8 * 8 + j] = f[j] * 0.125f;
    }

    const __hip_bfloat16* Kb = K + (size_t)b * S_ * D_ + h * DH_;
    const __hip_bfloat16* Vb = V + (size_t)b * S_ * D_ + h * DH_;

    float m = -1e30f, l = 0.f;
    float out[DH_];
#pragma unroll
    for (int d = 0; d < DH_; ++d) out[d] = 0.f;

    // ---- 3 global keys (rows 0..2) ----
#pragma unroll
    for (int g = 0; g < NG_; ++g) {
        const __hip_bfloat16* kp = Kb + (size_t)g * D_;
        float s = 0.f;
#pragma unroll
        for (int c8 = 0; c8 < 8; ++c8) {
            uint4 t = *(const uint4*)(kp + c8 * 8);
            float f[8]; unp8(t, f);
#pragma unroll
            for (int j = 0; j < 8; ++j) s += qv[c8 * 8 + j] * f[j];
        }
        if (s > m) {
            float fs = __expf(m - s);
            l *= fs;
#pragma unroll
            for (int d = 0; d < DH_; ++d) out[d] *= fs;
            m = s;
        }
        float p = __expf(s - m);
        l += p;
        const __hip_bfloat16* vp = Vb + (size_t)g * D_;
#pragma unroll
        for (int c8 = 0; c8 < 8; ++c8) {
            uint4 t = *(const uint4*)(vp + c8 * 8);
            float f[8]; unp8(t, f);
#pragma unroll
            for (int j = 0; j < 8; ++j) out[c8 * 8 + j] += p * f[j];
        }
    }

    // ---- sliding window via LDS tiles ----
    int klo = qa - W_; if (klo < NG_) klo = NG_;
    int khi = qa + W_; if (khi > S_ - 1) khi = S_ - 1;
    int kstart = c * W_ - W_; if (kstart < NG_) kstart = NG_;
    int kend = c * W_ + 2 * W_ - 1; if (kend > S_ - 1) kend = S_ - 1;

    for (int kt = kstart; kt <= kend; kt += TK_) {
        int cnt = kend - kt + 1; if (cnt > TK_) cnt = TK_;
        __syncthreads();
        int nch = cnt * 8;  // 16B chunks per array
        for (int i = tid; i < nch; i += 256) {
            int r = i >> 3;
            int c8 = (i & 7) * 8;
            size_t goff = (size_t)(kt + r) * D_ + c8;
            *(uint4*)&Ks[r][c8] = *(const uint4*)(Kb + goff);
            *(uint4*)&Vs[r][c8] = *(const uint4*)(Vb + goff);
        }
        __syncthreads();
        int lo = klo > kt ? klo : kt;
        int hi = khi < kt + cnt - 1 ? khi : kt + cnt - 1;
        for (int t = lo - kt; t <= hi - kt; ++t) {
            float s = 0.f;
#pragma unroll
            for (int c8 = 0; c8 < 8; ++c8) {
                uint4 u = *(const uint4*)&Ks[t][c8 * 8];
                float f[8]; unp8(u, f);
#pragma unroll
                for (int j = 0; j < 8; ++j) s += qv[c8 * 8 + j] * f[j];
            }
            if (s > m) {
                float fs = __expf(m - s);
                l *= fs;
#pragma unroll
                for (int d = 0; d < DH_; ++d) out[d] *= fs;
                m = s;
            }
            float p = __expf(s - m);
            l += p;
#pragma unroll
            for (int c8 = 0; c8 < 8; ++c8) {
                uint4 u = *(const uint4*)&Vs[t][c8 * 8];
                float f[8]; unp8(u, f);
#pragma unroll
                for (int j = 0; j < 8; ++j) out[c8 * 8 + j] += p * f[j];
            }
        }
    }

    float linv = 1.0f / l;
    __hip_bfloat16* op = O + (size_t)(b * S_ + qa) * D_ + h * DH_;
#pragma unroll
    for (int c8 = 0; c8 < 8; ++c8) {
        __hip_bfloat16 ob[8];
#pragma unroll
        for (int j = 0; j < 8; ++j) ob[j] = __float2bfloat16(out[c8 * 8 + j] * linv);
        *(uint4*)(op + c8 * 8) = *(uint4*)ob;
    }
}

// ---------------- global attention (3 queries attend to all S), bf16 K/V ----------------
template <typename TO>
__global__ __launch_bounds__(256) void global_attn_k(
    const float* __restrict__ qg, const __hip_bfloat16* __restrict__ KG,
    const __hip_bfloat16* __restrict__ VG, TO* __restrict__ outp, int rowStride) {
    __shared__ float sc[S_];
    __shared__ float qs[DH_];
    __shared__ float red[256];
    int g = blockIdx.x, h = blockIdx.y, b = blockIdx.z;
    int tid = threadIdx.x;
    if (tid < DH_) qs[tid] = qg[(size_t)(b * NG_ + g) * D_ + h * DH_ + tid] * 0.125f;
    __syncthreads();
    float qr[DH_];
#pragma unroll
    for (int d = 0; d < DH_; ++d) qr[d] = qs[d];
    float mloc = -1e30f;
    for (int s0 = tid; s0 < S_; s0 += 256) {
        const __hip_bfloat16* kp = KG + (size_t)(b * S_ + s0) * D_ + h * DH_;
        float acc = 0.f;
#pragma unroll
        for (int c8 = 0; c8 < 8; ++c8) {
            uint4 t = *(const uint4*)(kp + c8 * 8);
            float f[8]; unp8(t, f);
#pragma unroll
            for (int j = 0; j < 8; ++j) acc += qr[c8 * 8 + j] * f[j];
        }
        sc[s0] = acc;
        mloc = fmaxf(mloc, acc);
    }
    float m = block_max(mloc, red);
    float lsum = 0.f;
    for (int s0 = tid; s0 < S_; s0 += 256) {
        float e = __expf(sc[s0] - m);
        sc[s0] = e;
        lsum += e;
    }
    float l = block_sum(lsum, red);
    if (tid < DH_) {
        float linv = 1.0f / l;
        const unsigned short* vp = (const unsigned short*)(VG + (size_t)b * S_ * D_ + h * DH_ + tid);
        float a0 = 0.f, a1 = 0.f, a2 = 0.f, a3 = 0.f;
        for (int s0 = 0; s0 < S_; s0 += 4) {
            a0 += sc[s0 + 0] * bflo((unsigned int)vp[(size_t)(s0 + 0) * D_]);
            a1 += sc[s0 + 1] * bflo((unsigned int)vp[(size_t)(s0 + 1) * D_]);
            a2 += sc[s0 + 2] * bflo((unsigned int)vp[(size_t)(s0 + 2) * D_]);
            a3 += sc[s0 + 3] * bflo((unsigned int)vp[(size_t)(s0 + 3) * D_]);
        }
        storeO(&outp[(size_t)(b * rowStride + g) * D_ + h * DH_ + tid], (a0 + a1 + a2 + a3) * linv);
    }
}

// ---------------- elementwise exact GELU (layer-1 tiny FFN only) ----------------
__global__ void gelu_k(float* __restrict__ x, int n) {
    int i = blockIdx.x * blockDim.x + threadIdx.x;
    int stride = gridDim.x * blockDim.x;
    for (; i < n; i += stride) {
        float v = x[i];
        x[i] = 0.5f * v * (1.0f + erff(v * 0.70710678118654752f));
    }
}

// ---------------- gather the 6 global-token rows ----------------
__global__ void gather6_k(const float* __restrict__ X, float* __restrict__ xg) {
    int r = blockIdx.x;
    int b = r / NG_, g = r % NG_;
    for (int c = threadIdx.x; c < D_; c += blockDim.x)
        xg[(size_t)r * D_ + c] = X[(size_t)(b * S_ + g) * D_ + c];
}

// ---------------- classifier heads ----------------
__global__ __launch_bounds__(256) void classifier_k(
    const float* __restrict__ x26, const float* __restrict__ cw,
    const float* __restrict__ cb, float* __restrict__ out) {
    __shared__ float red[256];
    int tid = threadIdx.x;
    for (int i = 0; i < 3; ++i) {
        for (int b = 0; b < B_; ++b) {
            const float* xr = x26 + (size_t)(b * NG_ + i) * D_;
            const float* wr = cw + (size_t)i * D_;
            float p = 0.f;
            for (int c = tid; c < D_; c += 256) p += xr[c] * wr[c];
            float dotv = block_sum(p, red);
            if (tid == 0) out[i * B_ + b] = 1.0f / (1.0f + __expf(-(dotv + cb[i])));
        }
    }
    if (tid == 0) { out[6] = 1.0f; out[7] = 1.0f; }
}

// ---------------- host launcher ----------------
extern "C" void kernel_launch(void* const* d_in, const int* in_sizes, int n_in,
                              void* d_out, int out_size, void* d_ws, size_t ws_size,
                              hipStream_t stream) {
    const int*   src      = (const int*)d_in[0];
    const float* word_emb = (const float*)d_in[3];
    const float* pos_emb  = (const float*)d_in[4];
    const float* emb_ln   = (const float*)d_in[5];
    const float* attn_w   = (const float*)d_in[6];
    const float* attn_b   = (const float*)d_in[7];
    const float* ln_p     = (const float*)d_in[8];
    const float* ffn_w1   = (const float*)d_in[9];
    const float* ffn_b1   = (const float*)d_in[10];
    const float* ffn_w2   = (const float*)d_in[11];
    const float* ffn_b2   = (const float*)d_in[12];
    const float* cls_w    = (const float*)d_in[13];
    const float* cls_b    = (const float*)d_in[14];
    float* out = (float*)d_out;

    const size_t NT = (size_t)B_ * S_ * D_;  // 6291456 (elements)
    float* base = (float*)d_ws;
    float* X  = base;                                         // NT f32
    float* P4 = base + NT;                                    // NT f32
    __hip_bfloat16* Xb = (__hip_bfloat16*)(base + 2 * NT);    // NT bf16
    __hip_bfloat16* Qb = (__hip_bfloat16*)(base + 5 * NT / 2);
    __hip_bfloat16* Kb = (__hip_bfloat16*)(base + 3 * NT);
    __hip_bfloat16* Vb = (__hip_bfloat16*)(base + 7 * NT / 2);
    __hip_bfloat16* AOb = (__hip_bfloat16*)(base + 4 * NT);   // pool: NT floats = 2NT bf16
    __hip_bfloat16* HCb = AOb;                                 // FFN hidden chunk (4096x3072 bf16), reuses pool
    __hip_bfloat16* wq  = (__hip_bfloat16*)(base + 5 * NT);
    __hip_bfloat16* wk  = wq + 589824;
    __hip_bfloat16* wv  = wk + 589824;
    __hip_bfloat16* wg1 = wv + 589824;
    __hip_bfloat16* wg2 = wg1 + 589824;
    __hip_bfloat16* wo  = wg2 + 589824;
    __hip_bfloat16* wf1 = wo + 589824;    // 3072x768
    __hip_bfloat16* wf2 = wf1 + 2359296;  // 768x3072
    float* SM  = base + 5 * NT + 4128768 / 1;  // smalls (wf2 end = 8257536 elems = 4128768 floats)
    float* xg  = SM;
    float* qg6 = xg + 6 * D_;
    float* og6 = qg6 + 6 * D_;
    float* pr6 = og6 + 6 * D_;
    float* xa6 = pr6 + 6 * D_;
    float* h6  = xa6 + 6 * D_;
    float* f6  = h6 + 6 * FF_;
    float* x26 = f6 + 6 * D_;

    const int M = B_ * S_;  // 8192
    dim3 blk(256);

    auto aw = [&](int l, int i) { return attn_w + ((size_t)(l * 7 + i)) * D_ * D_; };
    auto ab = [&](int l, int i) { return attn_b + (size_t)(l * 7 + i) * D_; };
    auto lnp = [&](int l, int i) { return ln_p + (size_t)(l * 4 + i) * D_; };

    // ---- embedding + LN ----
    embed_ln_k<<<M, blk, 0, stream>>>(src, word_emb, pos_emb, emb_ln, emb_ln + D_, X, Xb);

    // ================= layer 0 =================
    convt_k<<<dim3(24, 24), blk, 0, stream>>>(aw(0, 0), wq, D_, D_);
    convt_k<<<dim3(24, 24), blk, 0, stream>>>(aw(0, 1), wk, D_, D_);
    convt_k<<<dim3(24, 24), blk, 0, stream>>>(aw(0, 2), wv, D_, D_);
    mfma_gemm_k<1><<<dim3(6, 64), blk, 0, stream>>>(Xb, wq, ab(0, 0), Qb, M, D_, D_);
    mfma_gemm_k<1><<<dim3(6, 64), blk, 0, stream>>>(Xb, wk, ab(0, 1), Kb, M, D_, D_);
    mfma_gemm_k<1><<<dim3(6, 64), blk, 0, stream>>>(Xb, wv, ab(0, 2), Vb, M, D_, D_);
    local_attn_k<<<dim3(NC_, H_, B_), blk, 0, stream>>>(Qb, Kb, Vb, AOb);
    // global path (KG->Qb slot, VG->Kb slot; both free after local attn)
    convt_k<<<dim3(24, 24), blk, 0, stream>>>(aw(0, 4), wg1, D_, D_);
    convt_k<<<dim3(24, 24), blk, 0, stream>>>(aw(0, 5), wg2, D_, D_);
    mfma_gemm_k<1><<<dim3(6, 64), blk, 0, stream>>>(Xb, wg1, ab(0, 4), Qb, M, D_, D_);
    mfma_gemm_k<1><<<dim3(6, 64), blk, 0, stream>>>(Xb, wg2, ab(0, 5), Kb, M, D_, D_);
    gather6_k<<<B_ * NG_, blk, 0, stream>>>(X, xg);
    gemm_bias_k<<<dim3(6, 1), blk, 0, stream>>>(xg, aw(0, 3), ab(0, 3), qg6, B_ * NG_, D_, D_);
    global_attn_k<__hip_bfloat16><<<dim3(NG_, H_, B_), blk, 0, stream>>>(qg6, Qb, Kb, AOb, S_);
    // output projection (f32 out) + LN
    convt_k<<<dim3(24, 24), blk, 0, stream>>>(aw(0, 6), wo, D_, D_);
    mfma_gemm_k<0><<<dim3(6, 64), blk, 0, stream>>>(AOb, wo, ab(0, 6), P4, M, D_, D_);
    residual_ln_k<<<M, blk, 0, stream>>>(X, P4, lnp(0, 0), lnp(0, 1), P4, Xb);  // xa -> P4/Xb
    // FFN (fused bias+GELU+bf16 in FFN1 epilogue), 2 chunks of 4096 rows
    convt_k<<<dim3(96, 24), blk, 0, stream>>>(ffn_w1, wf1, D_, FF_);
    convt_k<<<dim3(24, 96), blk, 0, stream>>>(ffn_w2, wf2, FF_, D_);
    for (int ch = 0; ch < 2; ++ch) {
        mfma_gemm_k<2><<<dim3(24, 32), blk, 0, stream>>>(Xb + (size_t)ch * 4096 * D_, wf1, ffn_b1, HCb, 4096, FF_, D_);
        mfma_gemm_k<0><<<dim3(6, 32), blk, 0, stream>>>(HCb, wf2, ffn_b2, X + (size_t)ch * 4096 * D_, 4096, D_, FF_);
    }
    residual_ln_k<<<M, blk, 0, stream>>>(P4, X, lnp(0, 2), lnp(0, 3), X, Xb);  // x1 -> X/Xb

    // ================= layer 1 (pruned: only global path feeds classifier) ====
    convt_k<<<dim3(24, 24), blk, 0, stream>>>(aw(1, 4), wg1, D_, D_);
    convt_k<<<dim3(24, 24), blk, 0, stream>>>(aw(1, 5), wg2, D_, D_);
    mfma_gemm_k<1><<<dim3(6, 64), blk, 0, stream>>>(Xb, wg1, ab(1, 4), Qb, M, D_, D_);
    mfma_gemm_k<1><<<dim3(6, 64), blk, 0, stream>>>(Xb, wg2, ab(1, 5), Kb, M, D_, D_);
    gather6_k<<<B_ * NG_, blk, 0, stream>>>(X, xg);
    gemm_bias_k<<<dim3(6, 1), blk, 0, stream>>>(xg, aw(1, 3), ab(1, 3), qg6, B_ * NG_, D_, D_);
    global_attn_k<float><<<dim3(NG_, H_, B_), blk, 0, stream>>>(qg6, Qb, Kb, og6, NG_);
    gemm_bias_k<<<dim3(6, 1), blk, 0, stream>>>(og6, aw(1, 6), ab(1, 6), pr6, B_ * NG_, D_, D_);
    residual_ln_k<<<B_ * NG_, blk, 0, stream>>>(xg, pr6, lnp(1, 0), lnp(1, 1), xa6, nullptr);
    gemm_bias_k<<<dim3(24, 1), blk, 0, stream>>>(xa6, ffn_w1 + (size_t)D_ * FF_, ffn_b1 + FF_, h6, B_ * NG_, FF_, D_);
    gelu_k<<<72, blk, 0, stream>>>(h6, B_ * NG_ * FF_);
    gemm_bias_k<<<dim3(6, 1), blk, 0, stream>>>(h6, ffn_w2 + (size_t)FF_ * D_, ffn_b2 + D_, f6, B_ * NG_, D_, FF_);
    residual_ln_k<<<B_ * NG_, blk, 0, stream>>>(xa6, f6, lnp(1, 2), lnp(1, 3), x26, nullptr);
    classifier_k<<<1, blk, 0, stream>>>(x26, cls_w, cls_b, out);
}

// Round 4
// 1719.846 us; speedup vs baseline: 6.9103x; 1.3442x over previous
//
#include <hip/hip_runtime.h>
#include <hip/hip_bf16.h>
#include <math.h>

// ---------------- constants (problem shapes) ----------------
#define B_    2
#define SSRC_ 4093
#define D_    768
#define H_    12
#define DH_   64
#define FF_   3072
#define NG_   3
#define W_    256
#define S_    4096
#define NC_   16

typedef __attribute__((ext_vector_type(8))) short frag_ab;   // 8 bf16 (4 VGPRs)
typedef __attribute__((ext_vector_type(4))) float f32x4;     // 4 fp32 acc

// ---------------- helpers ----------------
__device__ __forceinline__ float bflo(unsigned int w) {
    union { float f; unsigned int i; } c; c.i = w << 16; return c.f;
}
__device__ __forceinline__ float bfhi(unsigned int w) {
    union { float f; unsigned int i; } c; c.i = w & 0xffff0000u; return c.f;
}
__device__ __forceinline__ void unp8(uint4 t, float* o) {
    o[0] = bflo(t.x); o[1] = bfhi(t.x); o[2] = bflo(t.y); o[3] = bfhi(t.y);
    o[4] = bflo(t.z); o[5] = bfhi(t.z); o[6] = bflo(t.w); o[7] = bfhi(t.w);
}
__device__ __forceinline__ unsigned short f2bfu(float x) {
    __hip_bfloat16 h = __float2bfloat16(x);
    return *reinterpret_cast<unsigned short*>(&h);
}

__device__ __forceinline__ float block_sum(float v, float* red) {
    int tid = threadIdx.x;
    red[tid] = v;
    __syncthreads();
#pragma unroll
    for (int off = 128; off >= 1; off >>= 1) {
        if (tid < off) red[tid] += red[tid + off];
        __syncthreads();
    }
    float r = red[0];
    __syncthreads();
    return r;
}

__device__ __forceinline__ float block_max(float v, float* red) {
    int tid = threadIdx.x;
    red[tid] = v;
    __syncthreads();
#pragma unroll
    for (int off = 128; off >= 1; off >>= 1) {
        if (tid < off) red[tid] = fmaxf(red[tid], red[tid + off]);
        __syncthreads();
    }
    float r = red[0];
    __syncthreads();
    return r;
}

__device__ __forceinline__ void storeO(float* p, float v) { *p = v; }
__device__ __forceinline__ void storeO(__hip_bfloat16* p, float v) { *p = __float2bfloat16(v); }

// ---------------- embedding + LN (writes f32 X and bf16 Xb) ----------------
__global__ __launch_bounds__(256) void embed_ln_k(
    const int* __restrict__ src, const float* __restrict__ we,
    const float* __restrict__ pe, const float* __restrict__ gam,
    const float* __restrict__ bet, float* __restrict__ X,
    __hip_bfloat16* __restrict__ Xb) {
    __shared__ float red[256];
    int row = blockIdx.x;
    int b = row >> 12;
    int s = row & (S_ - 1);
    int tid = threadIdx.x;
    int id = (s < NG_) ? (50261 + s) : src[b * SSRC_ + (s - NG_)];
    const float* wr = we + (size_t)id * D_;
    const float* pr = pe + (size_t)s * D_;
    float v[3];
    float lsum = 0.f;
#pragma unroll
    for (int j = 0; j < 3; ++j) {
        int c = tid + j * 256;
        v[j] = wr[c] + pr[c];
        lsum += v[j];
    }
    float mu = block_sum(lsum, red) * (1.0f / 768.0f);
    float ls2 = 0.f;
#pragma unroll
    for (int j = 0; j < 3; ++j) { float d = v[j] - mu; ls2 += d * d; }
    float var = block_sum(ls2, red) * (1.0f / 768.0f);
    float rs = rsqrtf(var + 1e-5f);
    float* xr = X + (size_t)row * D_;
    __hip_bfloat16* xbr = Xb + (size_t)row * D_;
#pragma unroll
    for (int j = 0; j < 3; ++j) {
        int c = tid + j * 256;
        float o = (v[j] - mu) * rs * gam[c] + bet[c];
        xr[c] = o;
        xbr[c] = __float2bfloat16(o);
    }
}

// ---------------- residual + LN : out = LN(x + y), optional bf16 mirror ----------------
__global__ __launch_bounds__(256) void residual_ln_k(
    const float* __restrict__ x, const float* __restrict__ y,
    const float* __restrict__ gam, const float* __restrict__ bet,
    float* __restrict__ out, __hip_bfloat16* __restrict__ outb) {
    __shared__ float red[256];
    int row = blockIdx.x;
    int tid = threadIdx.x;
    const float* xr = x + (size_t)row * D_;
    const float* yr = y + (size_t)row * D_;
    float v[3];
    float lsum = 0.f;
#pragma unroll
    for (int j = 0; j < 3; ++j) {
        int c = tid + j * 256;
        v[j] = xr[c] + yr[c];
        lsum += v[j];
    }
    float mu = block_sum(lsum, red) * (1.0f / 768.0f);
    float ls2 = 0.f;
#pragma unroll
    for (int j = 0; j < 3; ++j) { float d = v[j] - mu; ls2 += d * d; }
    float var = block_sum(ls2, red) * (1.0f / 768.0f);
    float rs = rsqrtf(var + 1e-5f);
    float* orow = out + (size_t)row * D_;
    __hip_bfloat16* obr = outb ? outb + (size_t)row * D_ : nullptr;
#pragma unroll
    for (int j = 0; j < 3; ++j) {
        int c = tid + j * 256;
        float o = (v[j] - mu) * rs * gam[c] + bet[c];
        orow[c] = o;
        if (obr) obr[c] = __float2bfloat16(o);
    }
}

// ---------------- transpose-convert: W[K,N] f32 -> WT[N,K] bf16 ----------------
__global__ __launch_bounds__(256) void convt_k(
    const float* __restrict__ W, __hip_bfloat16* __restrict__ WT, int K, int N) {
    __shared__ float tile[32][33];
    int bx = blockIdx.x, by = blockIdx.y;
    int tx = threadIdx.x & 31, ty = threadIdx.x >> 5;
#pragma unroll
    for (int i = 0; i < 32; i += 8)
        tile[ty + i][tx] = W[(size_t)(by * 32 + ty + i) * N + bx * 32 + tx];
    __syncthreads();
#pragma unroll
    for (int i = 0; i < 32; i += 8)
        WT[(size_t)(bx * 32 + ty + i) * K + by * 32 + tx] = __float2bfloat16(tile[tx][ty + i]);
}

// ---------------- MFMA GEMM: C[M,N] = A[M,K]bf16 @ BT[N,K]bf16^T + bias ----------------
template <int EPI>
__global__ __launch_bounds__(256) void mfma_gemm_k(
    const __hip_bfloat16* __restrict__ A, const __hip_bfloat16* __restrict__ BT,
    const float* __restrict__ bias, void* __restrict__ Cout,
    int M, int N, int K) {
    __shared__ __align__(16) __hip_bfloat16 As[4096];
    __shared__ __align__(16) __hip_bfloat16 Bs[4096];
    int tid = threadIdx.x;
    int lane = tid & 63;
    int w = tid >> 6, wr = w >> 1, wc = w & 1;
    int brow = blockIdx.y * 128, bcol = blockIdx.x * 128;
    int r0 = tid >> 2, k0 = (tid & 3) * 8;
    const __hip_bfloat16* Ag0 = A + (size_t)(brow + r0) * K + k0;
    const __hip_bfloat16* Ag1 = Ag0 + (size_t)64 * K;
    const __hip_bfloat16* Bg0 = BT + (size_t)(bcol + r0) * K + k0;
    const __hip_bfloat16* Bg1 = Bg0 + (size_t)64 * K;

    f32x4 acc[4][4];
#pragma unroll
    for (int m = 0; m < 4; ++m)
#pragma unroll
        for (int n = 0; n < 4; ++n) acc[m][n] = (f32x4){0.f, 0.f, 0.f, 0.f};

    int l15 = lane & 15, kb = lane >> 4;
    int aoff = (wr * 64 + l15) * 32 + kb * 8;
    int boff = (wc * 64 + l15) * 32 + kb * 8;

    uint4 pa0 = *(const uint4*)Ag0, pa1 = *(const uint4*)Ag1;
    uint4 pb0 = *(const uint4*)Bg0, pb1 = *(const uint4*)Bg1;

    for (int kt = 0; kt < K; kt += 32) {
        *(uint4*)&As[(size_t)tid * 8] = pa0;
        *(uint4*)&As[(size_t)tid * 8 + 2048] = pa1;
        *(uint4*)&Bs[(size_t)tid * 8] = pb0;
        *(uint4*)&Bs[(size_t)tid * 8 + 2048] = pb1;
        __syncthreads();
        if (kt + 32 < K) {
            pa0 = *(const uint4*)(Ag0 + kt + 32);
            pa1 = *(const uint4*)(Ag1 + kt + 32);
            pb0 = *(const uint4*)(Bg0 + kt + 32);
            pb1 = *(const uint4*)(Bg1 + kt + 32);
        }
        frag_ab af[4], bf[4];
#pragma unroll
        for (int m = 0; m < 4; ++m) af[m] = *(const frag_ab*)&As[aoff + m * 512];
#pragma unroll
        for (int n = 0; n < 4; ++n) bf[n] = *(const frag_ab*)&Bs[boff + n * 512];
#pragma unroll
        for (int m = 0; m < 4; ++m)
#pragma unroll
            for (int n = 0; n < 4; ++n)
                acc[m][n] = __builtin_amdgcn_mfma_f32_16x16x32_bf16(af[m], bf[n], acc[m][n], 0, 0, 0);
        __syncthreads();
    }

#pragma unroll
    for (int m = 0; m < 4; ++m) {
        int rowb = brow + wr * 64 + m * 16 + (lane >> 4) * 4;
#pragma unroll
        for (int n = 0; n < 4; ++n) {
            int col = bcol + wc * 64 + n * 16 + l15;
            float bv = bias[col];
#pragma unroll
            for (int r = 0; r < 4; ++r) {
                float v = acc[m][n][r] + bv;
                size_t idx = (size_t)(rowb + r) * N + col;
                if (EPI == 0) {
                    ((float*)Cout)[idx] = v;
                } else if (EPI == 1) {
                    ((__hip_bfloat16*)Cout)[idx] = __float2bfloat16(v);
                } else {
                    float g = 0.5f * v * (1.0f + erff(v * 0.70710678118654752f));
                    ((__hip_bfloat16*)Cout)[idx] = __float2bfloat16(g);
                }
            }
        }
    }
}

// ---------------- f32 tiled GEMM for tiny-M cases ----------------
__global__ __launch_bounds__(256) void gemm_bias_k(
    const float* __restrict__ A, const float* __restrict__ Wm,
    const float* __restrict__ bias, float* __restrict__ C,
    int M, int N, int K) {
    __shared__ float As[16][128];
    __shared__ float Bs[16][128];
    int tid = threadIdx.x;
    int bx = blockIdx.x, by = blockIdx.y;
    int tx = tid & 15, ty = tid >> 4;
    float acc[8][8];
#pragma unroll
    for (int i = 0; i < 8; ++i)
#pragma unroll
        for (int j = 0; j < 8; ++j) acc[i][j] = 0.f;

    for (int kt = 0; kt < K; kt += 16) {
#pragma unroll
        for (int i = 0; i < 2; ++i) {
            int f4 = tid + i * 256;
            int m = f4 >> 2;
            int ks = (f4 & 3) * 4;
            int gr = by * 128 + m;
            float4 va = make_float4(0.f, 0.f, 0.f, 0.f);
            if (gr < M) va = *(const float4*)(A + (size_t)gr * K + kt + ks);
            As[ks + 0][m] = va.x;
            As[ks + 1][m] = va.y;
            As[ks + 2][m] = va.z;
            As[ks + 3][m] = va.w;
            int r = f4 >> 5;
            int c4 = (f4 & 31) * 4;
            float4 vb = *(const float4*)(Wm + (size_t)(kt + r) * N + bx * 128 + c4);
            *(float4*)&Bs[r][c4] = vb;
        }
        __syncthreads();
#pragma unroll
        for (int kk = 0; kk < 16; ++kk) {
            float a[8], bb[8];
            *(float4*)&a[0] = *(const float4*)&As[kk][ty * 8];
            *(float4*)&a[4] = *(const float4*)&As[kk][ty * 8 + 4];
            *(float4*)&bb[0] = *(const float4*)&Bs[kk][tx * 8];
            *(float4*)&bb[4] = *(const float4*)&Bs[kk][tx * 8 + 4];
#pragma unroll
            for (int i = 0; i < 8; ++i)
#pragma unroll
                for (int j = 0; j < 8; ++j) acc[i][j] += a[i] * bb[j];
        }
        __syncthreads();
    }
#pragma unroll
    for (int i = 0; i < 8; ++i) {
        int row = by * 128 + ty * 8 + i;
        if (row < M) {
#pragma unroll
            for (int j = 0; j < 8; j += 4) {
                int col = bx * 128 + tx * 8 + j;
                float4 o;
                o.x = acc[i][j + 0] + bias[col + 0];
                o.y = acc[i][j + 1] + bias[col + 1];
                o.z = acc[i][j + 2] + bias[col + 2];
                o.w = acc[i][j + 3] + bias[col + 3];
                *(float4*)(C + (size_t)row * N + col) = o;
            }
        }
    }
}

// ---------------- MFMA sliding-window local attention ----------------
// grid (NC, H, B), 256 threads = 4 waves x 64 queries.
// Swapped QK^T (lane owns q = lane&15) + transposed PV (O^T keeps q ownership).
__global__ __launch_bounds__(256, 1) void local_attn_k(
    const __hip_bfloat16* __restrict__ Q, const __hip_bfloat16* __restrict__ K,
    const __hip_bfloat16* __restrict__ V, __hip_bfloat16* __restrict__ O) {
    __shared__ __align__(16) __hip_bfloat16 K_lds[64 * 72];
    __shared__ __align__(16) __hip_bfloat16 VT_lds[64 * 72];
    __shared__ __align__(16) __hip_bfloat16 P_lds[4][16 * 72];

    const int c = blockIdx.x, h = blockIdx.y, b = blockIdx.z;
    const int tid = threadIdx.x;
    const int lane = tid & 63;
    const int w = tid >> 6;
    const int l15 = lane & 15, g4 = lane >> 4;
    const int cbase = c * W_;

    // ---- Q fragments (B-operand): col q = l15, d = g4*8 + j + 32*s ----
    frag_ab qf[4][2];
#pragma unroll
    for (int qt = 0; qt < 4; ++qt) {
        int qa = cbase + w * 64 + qt * 16 + l15;
        const __hip_bfloat16* qp = Q + (size_t)(b * S_ + qa) * D_ + h * DH_ + g4 * 8;
        qf[qt][0] = *(const frag_ab*)qp;
        qf[qt][1] = *(const frag_ab*)(qp + 32);
    }

    f32x4 o[4][4];
#pragma unroll
    for (int qt = 0; qt < 4; ++qt)
#pragma unroll
        for (int dt = 0; dt < 4; ++dt) o[qt][dt] = (f32x4){0.f, 0.f, 0.f, 0.f};
    float mrun[4] = {-1e30f, -1e30f, -1e30f, -1e30f};
    float lrun[4] = {0.f, 0.f, 0.f, 0.f};

    int kw0 = cbase - W_; if (kw0 < 0) kw0 = 0;
    int kw1 = cbase + 2 * W_; if (kw1 > S_) kw1 = S_;
    int ntiles = (kw1 - kw0) >> 6;

    char* Pw = (char*)P_lds[w];

    for (int t = 0; t < ntiles; ++t) {
        int k0 = kw0 + t * 64;
        __syncthreads();
        // ---- stage K (row-major, pad 72) and V^T (XOR-swizzled) ----
        {
            const __hip_bfloat16* Kg = K + (size_t)(b * S_ + k0) * D_ + h * DH_;
            const __hip_bfloat16* Vg = V + (size_t)(b * S_ + k0) * D_ + h * DH_;
#pragma unroll
            for (int it = 0; it < 2; ++it) {
                int idx = tid + it * 256;
                int kk = idx >> 3, d0 = (idx & 7) * 8;
                uint4 kv = *(const uint4*)(Kg + (size_t)kk * D_ + d0);
                *(uint4*)&K_lds[kk * 72 + d0] = kv;
                uint4 vv = *(const uint4*)(Vg + (size_t)kk * D_ + d0);
                unsigned short vs[8];
                *(uint4*)vs = vv;
#pragma unroll
                for (int j = 0; j < 8; ++j) {
                    int dd = d0 + j;
                    int boff = dd * 144 + ((kk * 2) ^ (((dd >> 3) & 7) << 4));
                    *(unsigned short*)((char*)VT_lds + boff) = vs[j];
                }
            }
        }
        __syncthreads();

        // ---- K fragments (A-operand): row k = l15, d = g4*8 + j + 32*s ----
        frag_ab kf[4][2];
#pragma unroll
        for (int kt = 0; kt < 4; ++kt) {
            const char* kp = (const char*)K_lds + (kt * 16 + l15) * 144 + g4 * 16;
            kf[kt][0] = *(const frag_ab*)kp;
            kf[kt][1] = *(const frag_ab*)(kp + 64);
        }
        // ---- V^T fragments (A-operand): row d = dt*16 + l15, k = g4*8 + j + 32*s ----
        frag_ab vf[4][2];
#pragma unroll
        for (int dt = 0; dt < 4; ++dt) {
            int drow = dt * 16 + l15;
            int swz = ((drow >> 3) & 7) << 4;
            const char* vp = (const char*)VT_lds + drow * 144;
            vf[dt][0] = *(const frag_ab*)(vp + ((g4 * 16) ^ swz));
            vf[dt][1] = *(const frag_ab*)(vp + ((g4 * 16 + 64) ^ swz));
        }

#pragma unroll
        for (int qt = 0; qt < 4; ++qt) {
            // S^T tiles: [k=16 rows][q=16 cols]; lane: col q = l15, rows k = g4*4 + r
            f32x4 st[4];
#pragma unroll
            for (int kt = 0; kt < 4; ++kt) {
                f32x4 z = (f32x4){0.f, 0.f, 0.f, 0.f};
                z = __builtin_amdgcn_mfma_f32_16x16x32_bf16(kf[kt][0], qf[qt][0], z, 0, 0, 0);
                z = __builtin_amdgcn_mfma_f32_16x16x32_bf16(kf[kt][1], qf[qt][1], z, 0, 0, 0);
                st[kt] = z;
            }
            int qa = cbase + w * 64 + qt * 16 + l15;
            float sv[16];
            float mx = -1e30f;
#pragma unroll
            for (int kt = 0; kt < 4; ++kt)
#pragma unroll
                for (int r = 0; r < 4; ++r) {
                    int ka = k0 + kt * 16 + g4 * 4 + r;
                    float s = st[kt][r] * 0.125f;
                    bool bad = (ka < NG_) | (ka - qa > W_) | (qa - ka > W_);
                    s = bad ? -1e30f : s;
                    sv[kt * 4 + r] = s;
                    mx = fmaxf(mx, s);
                }
            mx = fmaxf(mx, __shfl_xor(mx, 16));
            mx = fmaxf(mx, __shfl_xor(mx, 32));
            float mnew = fmaxf(fmaxf(mrun[qt], mx), -60.0f);
            float fsc = __expf(mrun[qt] - mnew);
            mrun[qt] = mnew;
#pragma unroll
            for (int dt = 0; dt < 4; ++dt) o[qt][dt] *= fsc;
            float psum = 0.f;
            unsigned short pb[16];
#pragma unroll
            for (int i = 0; i < 16; ++i) {
                float p = __expf(sv[i] - mnew);
                psum += p;
                pb[i] = f2bfu(p);
            }
            psum += __shfl_xor(psum, 16);
            psum += __shfl_xor(psum, 32);
            lrun[qt] = lrun[qt] * fsc + psum;
            // write P row q = l15, cols k (pairs)
#pragma unroll
            for (int kt = 0; kt < 4; ++kt)
#pragma unroll
                for (int rp = 0; rp < 2; ++rp) {
                    unsigned vpk = (unsigned)pb[kt * 4 + rp * 2] | ((unsigned)pb[kt * 4 + rp * 2 + 1] << 16);
                    int kloc = kt * 16 + g4 * 4 + rp * 2;
                    *(unsigned*)(Pw + l15 * 144 + kloc * 2) = vpk;
                }
            // PV: O^T tile [d rows][q cols] — B-operand P: row q = l15, k consecutive
            frag_ab pf0 = *(const frag_ab*)(Pw + l15 * 144 + g4 * 16);
            frag_ab pf1 = *(const frag_ab*)(Pw + l15 * 144 + g4 * 16 + 64);
#pragma unroll
            for (int dt = 0; dt < 4; ++dt) {
                o[qt][dt] = __builtin_amdgcn_mfma_f32_16x16x32_bf16(vf[dt][0], pf0, o[qt][dt], 0, 0, 0);
                o[qt][dt] = __builtin_amdgcn_mfma_f32_16x16x32_bf16(vf[dt][1], pf1, o[qt][dt], 0, 0, 0);
            }
        }
    }

    // ---- 3 global keys (unmasked), scalar epilogue ----
    uint4 kgc[3][2];
    uint2 vgd[3][4];
#pragma unroll
    for (int gk = 0; gk < NG_; ++gk) {
        const __hip_bfloat16* kp = K + (size_t)(b * S_ + gk) * D_ + h * DH_ + g4 * 8;
        kgc[gk][0] = *(const uint4*)kp;
        kgc[gk][1] = *(const uint4*)(kp + 32);
        const __hip_bfloat16* vp = V + (size_t)(b * S_ + gk) * D_ + h * DH_ + g4 * 4;
#pragma unroll
        for (int dt = 0; dt < 4; ++dt)
            vgd[gk][dt] = *(const uint2*)(vp + dt * 16);
    }
#pragma unroll
    for (int qt = 0; qt < 4; ++qt) {
        float sg[3];
#pragma unroll
        for (int gk = 0; gk < NG_; ++gk) {
            float part = 0.f;
#pragma unroll
            for (int s = 0; s < 2; ++s) {
                uint4 qw = *(uint4*)&qf[qt][s];
                uint4 kw = kgc[gk][s];
                part += bflo(qw.x) * bflo(kw.x) + bfhi(qw.x) * bfhi(kw.x);
                part += bflo(qw.y) * bflo(kw.y) + bfhi(qw.y) * bfhi(kw.y);
                part += bflo(qw.z) * bflo(kw.z) + bfhi(qw.z) * bfhi(kw.z);
                part += bflo(qw.w) * bflo(kw.w) + bfhi(qw.w) * bfhi(kw.w);
            }
            part += __shfl_xor(part, 16);
            part += __shfl_xor(part, 32);
            sg[gk] = part * 0.125f;
        }
        float mx3 = fmaxf(fmaxf(sg[0], sg[1]), sg[2]);
        float mnew = fmaxf(fmaxf(mrun[qt], mx3), -60.0f);
        float fsc = __expf(mrun[qt] - mnew);
        mrun[qt] = mnew;
#pragma unroll
        for (int dt = 0; dt < 4; ++dt) o[qt][dt] *= fsc;
        float pg[3];
        float psum = 0.f;
#pragma unroll
        for (int gk = 0; gk < NG_; ++gk) { pg[gk] = __expf(sg[gk] - mnew); psum += pg[gk]; }
        lrun[qt] = lrun[qt] * fsc + psum;
#pragma unroll
        for (int dt = 0; dt < 4; ++dt) {
#pragma unroll
            for (int gk = 0; gk < NG_; ++gk) {
                uint2 vv = vgd[gk][dt];
                o[qt][dt][0] += pg[gk] * bflo(vv.x);
                o[qt][dt][1] += pg[gk] * bfhi(vv.x);
                o[qt][dt][2] += pg[gk] * bflo(vv.y);
                o[qt][dt][3] += pg[gk] * bfhi(vv.y);
            }
        }
    }

    // ---- normalize + store: lane owns q = l15; d = dt*16 + g4*4 + r ----
#pragma unroll
    for (int qt = 0; qt < 4; ++qt) {
        float linv = 1.0f / lrun[qt];
        int qa = cbase + w * 64 + qt * 16 + l15;
        __hip_bfloat16* orow = O + (size_t)(b * S_ + qa) * D_ + h * DH_;
#pragma unroll
        for (int dt = 0; dt < 4; ++dt) {
            unsigned short pk[4];
#pragma unroll
            for (int r = 0; r < 4; ++r) pk[r] = f2bfu(o[qt][dt][r] * linv);
            *(uint2*)(orow + dt * 16 + g4 * 4) = *(uint2*)pk;
        }
    }
}

// ---------------- global attention (3 queries attend to all S), bf16 K/V ----------------
template <typename TO>
__global__ __launch_bounds__(256) void global_attn_k(
    const float* __restrict__ qg, const __hip_bfloat16* __restrict__ KG,
    const __hip_bfloat16* __restrict__ VG, TO* __restrict__ outp, int rowStride) {
    __shared__ float sc[S_];
    __shared__ float qs[DH_];
    __shared__ float red[256];
    int g = blockIdx.x, h = blockIdx.y, b = blockIdx.z;
    int tid = threadIdx.x;
    if (tid < DH_) qs[tid] = qg[(size_t)(b * NG_ + g) * D_ + h * DH_ + tid] * 0.125f;
    __syncthreads();
    float qr[DH_];
#pragma unroll
    for (int d = 0; d < DH_; ++d) qr[d] = qs[d];
    float mloc = -1e30f;
    for (int s0 = tid; s0 < S_; s0 += 256) {
        const __hip_bfloat16* kp = KG + (size_t)(b * S_ + s0) * D_ + h * DH_;
        float acc = 0.f;
#pragma unroll
        for (int c8 = 0; c8 < 8; ++c8) {
            uint4 t = *(const uint4*)(kp + c8 * 8);
            float f[8]; unp8(t, f);
#pragma unroll
            for (int j = 0; j < 8; ++j) acc += qr[c8 * 8 + j] * f[j];
        }
        sc[s0] = acc;
        mloc = fmaxf(mloc, acc);
    }
    float m = block_max(mloc, red);
    float lsum = 0.f;
    for (int s0 = tid; s0 < S_; s0 += 256) {
        float e = __expf(sc[s0] - m);
        sc[s0] = e;
        lsum += e;
    }
    float l = block_sum(lsum, red);
    if (tid < DH_) {
        float linv = 1.0f / l;
        const unsigned short* vp = (const unsigned short*)(VG + (size_t)b * S_ * D_ + h * DH_ + tid);
        float a0 = 0.f, a1 = 0.f, a2 = 0.f, a3 = 0.f;
        for (int s0 = 0; s0 < S_; s0 += 4) {
            a0 += sc[s0 + 0] * bflo((unsigned int)vp[(size_t)(s0 + 0) * D_]);
            a1 += sc[s0 + 1] * bflo((unsigned int)vp[(size_t)(s0 + 1) * D_]);
            a2 += sc[s0 + 2] * bflo((unsigned int)vp[(size_t)(s0 + 2) * D_]);
            a3 += sc[s0 + 3] * bflo((unsigned int)vp[(size_t)(s0 + 3) * D_]);
        }
        storeO(&outp[(size_t)(b * rowStride + g) * D_ + h * DH_ + tid], (a0 + a1 + a2 + a3) * linv);
    }
}

// ---------------- elementwise exact GELU (layer-1 tiny FFN only) ----------------
__global__ void gelu_k(float* __restrict__ x, int n) {
    int i = blockIdx.x * blockDim.x + threadIdx.x;
    int stride = gridDim.x * blockDim.x;
    for (; i < n; i += stride) {
        float v = x[i];
        x[i] = 0.5f * v * (1.0f + erff(v * 0.70710678118654752f));
    }
}

// ---------------- gather the 6 global-token rows ----------------
__global__ void gather6_k(const float* __restrict__ X, float* __restrict__ xg) {
    int r = blockIdx.x;
    int b = r / NG_, g = r % NG_;
    for (int c = threadIdx.x; c < D_; c += blockDim.x)
        xg[(size_t)r * D_ + c] = X[(size_t)(b * S_ + g) * D_ + c];
}

// ---------------- classifier heads ----------------
__global__ __launch_bounds__(256) void classifier_k(
    const float* __restrict__ x26, const float* __restrict__ cw,
    const float* __restrict__ cb, float* __restrict__ out) {
    __shared__ float red[256];
    int tid = threadIdx.x;
    for (int i = 0; i < 3; ++i) {
        for (int b = 0; b < B_; ++b) {
            const float* xr = x26 + (size_t)(b * NG_ + i) * D_;
            const float* wr = cw + (size_t)i * D_;
            float p = 0.f;
            for (int c = tid; c < D_; c += 256) p += xr[c] * wr[c];
            float dotv = block_sum(p, red);
            if (tid == 0) out[i * B_ + b] = 1.0f / (1.0f + __expf(-(dotv + cb[i])));
        }
    }
    if (tid == 0) { out[6] = 1.0f; out[7] = 1.0f; }
}

// ---------------- host launcher ----------------
extern "C" void kernel_launch(void* const* d_in, const int* in_sizes, int n_in,
                              void* d_out, int out_size, void* d_ws, size_t ws_size,
                              hipStream_t stream) {
    const int*   src      = (const int*)d_in[0];
    const float* word_emb = (const float*)d_in[3];
    const float* pos_emb  = (const float*)d_in[4];
    const float* emb_ln   = (const float*)d_in[5];
    const float* attn_w   = (const float*)d_in[6];
    const float* attn_b   = (const float*)d_in[7];
    const float* ln_p     = (const float*)d_in[8];
    const float* ffn_w1   = (const float*)d_in[9];
    const float* ffn_b1   = (const float*)d_in[10];
    const float* ffn_w2   = (const float*)d_in[11];
    const float* ffn_b2   = (const float*)d_in[12];
    const float* cls_w    = (const float*)d_in[13];
    const float* cls_b    = (const float*)d_in[14];
    float* out = (float*)d_out;

    const size_t NT = (size_t)B_ * S_ * D_;  // 6291456 (elements)
    float* base = (float*)d_ws;
    float* X  = base;
    float* P4 = base + NT;
    __hip_bfloat16* Xb = (__hip_bfloat16*)(base + 2 * NT);
    __hip_bfloat16* Qb = (__hip_bfloat16*)(base + 5 * NT / 2);
    __hip_bfloat16* Kb = (__hip_bfloat16*)(base + 3 * NT);
    __hip_bfloat16* Vb = (__hip_bfloat16*)(base + 7 * NT / 2);
    __hip_bfloat16* AOb = (__hip_bfloat16*)(base + 4 * NT);
    __hip_bfloat16* HCb = AOb;
    __hip_bfloat16* wq  = (__hip_bfloat16*)(base + 5 * NT);
    __hip_bfloat16* wk  = wq + 589824;
    __hip_bfloat16* wv  = wk + 589824;
    __hip_bfloat16* wg1 = wv + 589824;
    __hip_bfloat16* wg2 = wg1 + 589824;
    __hip_bfloat16* wo  = wg2 + 589824;
    __hip_bfloat16* wf1 = wo + 589824;
    __hip_bfloat16* wf2 = wf1 + 2359296;
    float* SM  = base + 5 * NT + 4128768;
    float* xg  = SM;
    float* qg6 = xg + 6 * D_;
    float* og6 = qg6 + 6 * D_;
    float* pr6 = og6 + 6 * D_;
    float* xa6 = pr6 + 6 * D_;
    float* h6  = xa6 + 6 * D_;
    float* f6  = h6 + 6 * FF_;
    float* x26 = f6 + 6 * D_;

    const int M = B_ * S_;
    dim3 blk(256);

    auto aw = [&](int l, int i) { return attn_w + ((size_t)(l * 7 + i)) * D_ * D_; };
    auto ab = [&](int l, int i) { return attn_b + (size_t)(l * 7 + i) * D_; };
    auto lnp = [&](int l, int i) { return ln_p + (size_t)(l * 4 + i) * D_; };

    embed_ln_k<<<M, blk, 0, stream>>>(src, word_emb, pos_emb, emb_ln, emb_ln + D_, X, Xb);

    // ================= layer 0 =================
    convt_k<<<dim3(24, 24), blk, 0, stream>>>(aw(0, 0), wq, D_, D_);
    convt_k<<<dim3(24, 24), blk, 0, stream>>>(aw(0, 1), wk, D_, D_);
    convt_k<<<dim3(24, 24), blk, 0, stream>>>(aw(0, 2), wv, D_, D_);
    mfma_gemm_k<1><<<dim3(6, 64), blk, 0, stream>>>(Xb, wq, ab(0, 0), Qb, M, D_, D_);
    mfma_gemm_k<1><<<dim3(6, 64), blk, 0, stream>>>(Xb, wk, ab(0, 1), Kb, M, D_, D_);
    mfma_gemm_k<1><<<dim3(6, 64), blk, 0, stream>>>(Xb, wv, ab(0, 2), Vb, M, D_, D_);
    local_attn_k<<<dim3(NC_, H_, B_), blk, 0, stream>>>(Qb, Kb, Vb, AOb);
    convt_k<<<dim3(24, 24), blk, 0, stream>>>(aw(0, 4), wg1, D_, D_);
    convt_k<<<dim3(24, 24), blk, 0, stream>>>(aw(0, 5), wg2, D_, D_);
    mfma_gemm_k<1><<<dim3(6, 64), blk, 0, stream>>>(Xb, wg1, ab(0, 4), Qb, M, D_, D_);
    mfma_gemm_k<1><<<dim3(6, 64), blk, 0, stream>>>(Xb, wg2, ab(0, 5), Kb, M, D_, D_);
    gather6_k<<<B_ * NG_, blk, 0, stream>>>(X, xg);
    gemm_bias_k<<<dim3(6, 1), blk, 0, stream>>>(xg, aw(0, 3), ab(0, 3), qg6, B_ * NG_, D_, D_);
    global_attn_k<__hip_bfloat16><<<dim3(NG_, H_, B_), blk, 0, stream>>>(qg6, Qb, Kb, AOb, S_);
    convt_k<<<dim3(24, 24), blk, 0, stream>>>(aw(0, 6), wo, D_, D_);
    mfma_gemm_k<0><<<dim3(6, 64), blk, 0, stream>>>(AOb, wo, ab(0, 6), P4, M, D_, D_);
    residual_ln_k<<<M, blk, 0, stream>>>(X, P4, lnp(0, 0), lnp(0, 1), P4, Xb);
    convt_k<<<dim3(96, 24), blk, 0, stream>>>(ffn_w1, wf1, D_, FF_);
    convt_k<<<dim3(24, 96), blk, 0, stream>>>(ffn_w2, wf2, FF_, D_);
    for (int ch = 0; ch < 2; ++ch) {
        mfma_gemm_k<2><<<dim3(24, 32), blk, 0, stream>>>(Xb + (size_t)ch * 4096 * D_, wf1, ffn_b1, HCb, 4096, FF_, D_);
        mfma_gemm_k<0><<<dim3(6, 32), blk, 0, stream>>>(HCb, wf2, ffn_b2, X + (size_t)ch * 4096 * D_, 4096, D_, FF_);
    }
    residual_ln_k<<<M, blk, 0, stream>>>(P4, X, lnp(0, 2), lnp(0, 3), X, Xb);

    // ================= layer 1 (pruned) =================
    convt_k<<<dim3(24, 24), blk, 0, stream>>>(aw(1, 4), wg1, D_, D_);
    convt_k<<<dim3(24, 24), blk, 0, stream>>>(aw(1, 5), wg2, D_, D_);
    mfma_gemm_k<1><<<dim3(6, 64), blk, 0, stream>>>(Xb, wg1, ab(1, 4), Qb, M, D_, D_);
    mfma_gemm_k<1><<<dim3(6, 64), blk, 0, stream>>>(Xb, wg2, ab(1, 5), Kb, M, D_, D_);
    gather6_k<<<B_ * NG_, blk, 0, stream>>>(X, xg);
    gemm_bias_k<<<dim3(6, 1), blk, 0, stream>>>(xg, aw(1, 3), ab(1, 3), qg6, B_ * NG_, D_, D_);
    global_attn_k<float><<<dim3(NG_, H_, B_), blk, 0, stream>>>(qg6, Qb, Kb, og6, NG_);
    gemm_bias_k<<<dim3(6, 1), blk, 0, stream>>>(og6, aw(1, 6), ab(1, 6), pr6, B_ * NG_, D_, D_);
    residual_ln_k<<<B_ * NG_, blk, 0, stream>>>(xg, pr6, lnp(1, 0), lnp(1, 1), xa6, nullptr);
    gemm_bias_k<<<dim3(24, 1), blk, 0, stream>>>(xa6, ffn_w1 + (size_t)D_ * FF_, ffn_b1 + FF_, h6, B_ * NG_, FF_, D_);
    gelu_k<<<72, blk, 0, stream>>>(h6, B_ * NG_ * FF_);
    gemm_bias_k<<<dim3(6, 1), blk, 0, stream>>>(h6, ffn_w2 + (size_t)FF_ * D_, ffn_b2 + D_, f6, B_ * NG_, D_, FF_);
    residual_ln_k<<<B_ * NG_, blk, 0, stream>>>(xa6, f6, lnp(1, 2), lnp(1, 3), x26, nullptr);
    classifier_k<<<1, blk, 0, stream>>>(x26, cls_w, cls_b, out);
}

// Round 6
// 847.969 us; speedup vs baseline: 14.0154x; 2.0282x over previous
//
#include <hip/hip_runtime.h>
#include <hip/hip_bf16.h>
#include <math.h>

// ---------------- constants (problem shapes) ----------------
#define B_    2
#define SSRC_ 4093
#define D_    768
#define H_    12
#define DH_   64
#define FF_   3072
#define NG_   3
#define W_    256
#define S_    4096
#define NC_   16

typedef __attribute__((ext_vector_type(8))) short frag_ab;   // 8 bf16 (4 VGPRs)
typedef __attribute__((ext_vector_type(4))) float f32x4;     // 4 fp32 acc

// ---------------- helpers ----------------
__device__ __forceinline__ float bflo(unsigned int w) {
    union { float f; unsigned int i; } c; c.i = w << 16; return c.f;
}
__device__ __forceinline__ float bfhi(unsigned int w) {
    union { float f; unsigned int i; } c; c.i = w & 0xffff0000u; return c.f;
}
__device__ __forceinline__ void unp8(uint4 t, float* o) {
    o[0] = bflo(t.x); o[1] = bfhi(t.x); o[2] = bflo(t.y); o[3] = bfhi(t.y);
    o[4] = bflo(t.z); o[5] = bfhi(t.z); o[6] = bflo(t.w); o[7] = bfhi(t.w);
}
__device__ __forceinline__ unsigned short f2bfu(float x) {
    __hip_bfloat16 h = __float2bfloat16(x);
    return *reinterpret_cast<unsigned short*>(&h);
}

__device__ __forceinline__ float block_sum(float v, float* red) {
    int tid = threadIdx.x;
    red[tid] = v;
    __syncthreads();
#pragma unroll
    for (int off = 128; off >= 1; off >>= 1) {
        if (tid < off) red[tid] += red[tid + off];
        __syncthreads();
    }
    float r = red[0];
    __syncthreads();
    return r;
}

__device__ __forceinline__ float block_max(float v, float* red) {
    int tid = threadIdx.x;
    red[tid] = v;
    __syncthreads();
#pragma unroll
    for (int off = 128; off >= 1; off >>= 1) {
        if (tid < off) red[tid] = fmaxf(red[tid], red[tid + off]);
        __syncthreads();
    }
    float r = red[0];
    __syncthreads();
    return r;
}

__device__ __forceinline__ void storeO(float* p, float v) { *p = v; }
__device__ __forceinline__ void storeO(__hip_bfloat16* p, float v) { *p = __float2bfloat16(v); }

// ---------------- embedding + LN (writes f32 X and bf16 Xb) ----------------
__global__ __launch_bounds__(256) void embed_ln_k(
    const int* __restrict__ src, const float* __restrict__ we,
    const float* __restrict__ pe, const float* __restrict__ gam,
    const float* __restrict__ bet, float* __restrict__ X,
    __hip_bfloat16* __restrict__ Xb) {
    __shared__ float red[256];
    int row = blockIdx.x;
    int b = row >> 12;
    int s = row & (S_ - 1);
    int tid = threadIdx.x;
    int id = (s < NG_) ? (50261 + s) : src[b * SSRC_ + (s - NG_)];
    const float* wr = we + (size_t)id * D_;
    const float* pr = pe + (size_t)s * D_;
    float v[3];
    float lsum = 0.f;
#pragma unroll
    for (int j = 0; j < 3; ++j) {
        int c = tid + j * 256;
        v[j] = wr[c] + pr[c];
        lsum += v[j];
    }
    float mu = block_sum(lsum, red) * (1.0f / 768.0f);
    float ls2 = 0.f;
#pragma unroll
    for (int j = 0; j < 3; ++j) { float d = v[j] - mu; ls2 += d * d; }
    float var = block_sum(ls2, red) * (1.0f / 768.0f);
    float rs = rsqrtf(var + 1e-5f);
    float* xr = X + (size_t)row * D_;
    __hip_bfloat16* xbr = Xb + (size_t)row * D_;
#pragma unroll
    for (int j = 0; j < 3; ++j) {
        int c = tid + j * 256;
        float o = (v[j] - mu) * rs * gam[c] + bet[c];
        xr[c] = o;
        xbr[c] = __float2bfloat16(o);
    }
}

// ---------------- residual + LN : out = LN(x + y), optional bf16 mirror ----------------
__global__ __launch_bounds__(256) void residual_ln_k(
    const float* __restrict__ x, const float* __restrict__ y,
    const float* __restrict__ gam, const float* __restrict__ bet,
    float* __restrict__ out, __hip_bfloat16* __restrict__ outb) {
    __shared__ float red[256];
    int row = blockIdx.x;
    int tid = threadIdx.x;
    const float* xr = x + (size_t)row * D_;
    const float* yr = y + (size_t)row * D_;
    float v[3];
    float lsum = 0.f;
#pragma unroll
    for (int j = 0; j < 3; ++j) {
        int c = tid + j * 256;
        v[j] = xr[c] + yr[c];
        lsum += v[j];
    }
    float mu = block_sum(lsum, red) * (1.0f / 768.0f);
    float ls2 = 0.f;
#pragma unroll
    for (int j = 0; j < 3; ++j) { float d = v[j] - mu; ls2 += d * d; }
    float var = block_sum(ls2, red) * (1.0f / 768.0f);
    float rs = rsqrtf(var + 1e-5f);
    float* orow = out + (size_t)row * D_;
    __hip_bfloat16* obr = outb ? outb + (size_t)row * D_ : nullptr;
#pragma unroll
    for (int j = 0; j < 3; ++j) {
        int c = tid + j * 256;
        float o = (v[j] - mu) * rs * gam[c] + bet[c];
        orow[c] = o;
        if (obr) obr[c] = __float2bfloat16(o);
    }
}

// ---------------- transpose-convert: W[K,N] f32 -> WT[N,K] bf16 ----------------
__global__ __launch_bounds__(256) void convt_k(
    const float* __restrict__ W, __hip_bfloat16* __restrict__ WT, int K, int N) {
    __shared__ float tile[32][33];
    int bx = blockIdx.x, by = blockIdx.y;
    int tx = threadIdx.x & 31, ty = threadIdx.x >> 5;
#pragma unroll
    for (int i = 0; i < 32; i += 8)
        tile[ty + i][tx] = W[(size_t)(by * 32 + ty + i) * N + bx * 32 + tx];
    __syncthreads();
#pragma unroll
    for (int i = 0; i < 32; i += 8)
        WT[(size_t)(bx * 32 + ty + i) * K + by * 32 + tx] = __float2bfloat16(tile[tx][ty + i]);
}

// ---------------- MFMA GEMM: C[M,N] = A[M,K]bf16 @ BT[N,K]bf16^T + bias ----------------
template <int EPI>
__global__ __launch_bounds__(256) void mfma_gemm_k(
    const __hip_bfloat16* __restrict__ A, const __hip_bfloat16* __restrict__ BT,
    const float* __restrict__ bias, void* __restrict__ Cout,
    int M, int N, int K) {
    __shared__ __align__(16) __hip_bfloat16 As[4096];
    __shared__ __align__(16) __hip_bfloat16 Bs[4096];
    int tid = threadIdx.x;
    int lane = tid & 63;
    int w = tid >> 6, wr = w >> 1, wc = w & 1;
    int brow = blockIdx.y * 128, bcol = blockIdx.x * 128;
    int r0 = tid >> 2, k0 = (tid & 3) * 8;
    const __hip_bfloat16* Ag0 = A + (size_t)(brow + r0) * K + k0;
    const __hip_bfloat16* Ag1 = Ag0 + (size_t)64 * K;
    const __hip_bfloat16* Bg0 = BT + (size_t)(bcol + r0) * K + k0;
    const __hip_bfloat16* Bg1 = Bg0 + (size_t)64 * K;

    f32x4 acc[4][4];
#pragma unroll
    for (int m = 0; m < 4; ++m)
#pragma unroll
        for (int n = 0; n < 4; ++n) acc[m][n] = (f32x4){0.f, 0.f, 0.f, 0.f};

    int l15 = lane & 15, kb = lane >> 4;
    int aoff = (wr * 64 + l15) * 32 + kb * 8;
    int boff = (wc * 64 + l15) * 32 + kb * 8;

    uint4 pa0 = *(const uint4*)Ag0, pa1 = *(const uint4*)Ag1;
    uint4 pb0 = *(const uint4*)Bg0, pb1 = *(const uint4*)Bg1;

    for (int kt = 0; kt < K; kt += 32) {
        *(uint4*)&As[(size_t)tid * 8] = pa0;
        *(uint4*)&As[(size_t)tid * 8 + 2048] = pa1;
        *(uint4*)&Bs[(size_t)tid * 8] = pb0;
        *(uint4*)&Bs[(size_t)tid * 8 + 2048] = pb1;
        __syncthreads();
        if (kt + 32 < K) {
            pa0 = *(const uint4*)(Ag0 + kt + 32);
            pa1 = *(const uint4*)(Ag1 + kt + 32);
            pb0 = *(const uint4*)(Bg0 + kt + 32);
            pb1 = *(const uint4*)(Bg1 + kt + 32);
        }
        frag_ab af[4], bf[4];
#pragma unroll
        for (int m = 0; m < 4; ++m) af[m] = *(const frag_ab*)&As[aoff + m * 512];
#pragma unroll
        for (int n = 0; n < 4; ++n) bf[n] = *(const frag_ab*)&Bs[boff + n * 512];
#pragma unroll
        for (int m = 0; m < 4; ++m)
#pragma unroll
            for (int n = 0; n < 4; ++n)
                acc[m][n] = __builtin_amdgcn_mfma_f32_16x16x32_bf16(af[m], bf[n], acc[m][n], 0, 0, 0);
        __syncthreads();
    }

#pragma unroll
    for (int m = 0; m < 4; ++m) {
        int rowb = brow + wr * 64 + m * 16 + (lane >> 4) * 4;
#pragma unroll
        for (int n = 0; n < 4; ++n) {
            int col = bcol + wc * 64 + n * 16 + l15;
            float bv = bias[col];
#pragma unroll
            for (int r = 0; r < 4; ++r) {
                float v = acc[m][n][r] + bv;
                size_t idx = (size_t)(rowb + r) * N + col;
                if (EPI == 0) {
                    ((float*)Cout)[idx] = v;
                } else if (EPI == 1) {
                    ((__hip_bfloat16*)Cout)[idx] = __float2bfloat16(v);
                } else {
                    float g = 0.5f * v * (1.0f + erff(v * 0.70710678118654752f));
                    ((__hip_bfloat16*)Cout)[idx] = __float2bfloat16(g);
                }
            }
        }
    }
}

// ---------------- split-K skinny GEMM: M=6 rows ----------------
// partial[kb][m][col] = sum_{k in kb-th 64-block} A[m][k] * W[k][col]
// grid (N/64, K/64), 256 threads = 64 cols x 4 kgroups (16 k each)
__global__ __launch_bounds__(256) void skinny_gemm_k(
    const float* __restrict__ A, const float* __restrict__ W,
    float* __restrict__ partial, int N, int K) {
    __shared__ float Asl[6][64];
    __shared__ float red[4][6][64];
    int tid = threadIdx.x;
    int cl = tid & 63;          // col lane
    int kg = tid >> 6;          // k-group 0..3
    int col = blockIdx.x * 64 + cl;
    int k0 = blockIdx.y * 64;
    for (int i = tid; i < 6 * 64; i += 256)
        Asl[i >> 6][i & 63] = A[(size_t)(i >> 6) * K + k0 + (i & 63)];
    __syncthreads();
    float acc[6] = {0.f, 0.f, 0.f, 0.f, 0.f, 0.f};
#pragma unroll
    for (int kk = 0; kk < 16; ++kk) {
        int k = kg * 16 + kk;
        float wv = W[(size_t)(k0 + k) * N + col];
#pragma unroll
        for (int m = 0; m < 6; ++m) acc[m] += Asl[m][k] * wv;
    }
#pragma unroll
    for (int m = 0; m < 6; ++m) red[kg][m][cl] = acc[m];
    __syncthreads();
    // FIX (round 5 bug): 6*64 = 384 > 256 threads, must LOOP, not guard
    for (int i = tid; i < 6 * 64; i += 256) {
        int m = i >> 6, lane = i & 63;
        float s = red[0][m][lane] + red[1][m][lane] + red[2][m][lane] + red[3][m][lane];
        partial[(size_t)blockIdx.y * 6 * N + (size_t)m * N + blockIdx.x * 64 + lane] = s;
    }
}

// reduce over KS partials + bias (+ optional exact GELU); out[6][N] f32
__global__ __launch_bounds__(256) void skinny_reduce_k(
    const float* __restrict__ partial, const float* __restrict__ bias,
    float* __restrict__ outp, int N, int KS, int gelu) {
    int idx = blockIdx.x * 256 + threadIdx.x;
    if (idx >= 6 * N) return;
    int m = idx / N, col = idx - m * N;
    float s = bias[col];
    for (int kb = 0; kb < KS; ++kb)
        s += partial[(size_t)kb * 6 * N + (size_t)m * N + col];
    if (gelu) s = 0.5f * s * (1.0f + erff(s * 0.70710678118654752f));
    outp[(size_t)m * N + col] = s;
}

// ---------------- MFMA sliding-window local attention ----------------
// grid (NC, H, B), 256 threads = 4 waves x 64 queries.
__global__ __launch_bounds__(256, 1) void local_attn_k(
    const __hip_bfloat16* __restrict__ Q, const __hip_bfloat16* __restrict__ K,
    const __hip_bfloat16* __restrict__ V, __hip_bfloat16* __restrict__ O) {
    __shared__ __align__(16) __hip_bfloat16 K_lds[64 * 72];
    __shared__ __align__(16) __hip_bfloat16 VT_lds[64 * 72];
    __shared__ __align__(16) __hip_bfloat16 P_lds[4][16 * 72];

    const int c = blockIdx.x, h = blockIdx.y, b = blockIdx.z;
    const int tid = threadIdx.x;
    const int lane = tid & 63;
    const int w = tid >> 6;
    const int l15 = lane & 15, g4 = lane >> 4;
    const int cbase = c * W_;

    frag_ab qf[4][2];
#pragma unroll
    for (int qt = 0; qt < 4; ++qt) {
        int qa = cbase + w * 64 + qt * 16 + l15;
        const __hip_bfloat16* qp = Q + (size_t)(b * S_ + qa) * D_ + h * DH_ + g4 * 8;
        qf[qt][0] = *(const frag_ab*)qp;
        qf[qt][1] = *(const frag_ab*)(qp + 32);
    }

    f32x4 o[4][4];
#pragma unroll
    for (int qt = 0; qt < 4; ++qt)
#pragma unroll
        for (int dt = 0; dt < 4; ++dt) o[qt][dt] = (f32x4){0.f, 0.f, 0.f, 0.f};
    float mrun[4] = {-1e30f, -1e30f, -1e30f, -1e30f};
    float lrun[4] = {0.f, 0.f, 0.f, 0.f};

    int kw0 = cbase - W_; if (kw0 < 0) kw0 = 0;
    int kw1 = cbase + 2 * W_; if (kw1 > S_) kw1 = S_;
    int ntiles = (kw1 - kw0) >> 6;

    char* Pw = (char*)P_lds[w];

    for (int t = 0; t < ntiles; ++t) {
        int k0 = kw0 + t * 64;
        __syncthreads();
        {
            const __hip_bfloat16* Kg = K + (size_t)(b * S_ + k0) * D_ + h * DH_;
            const __hip_bfloat16* Vg = V + (size_t)(b * S_ + k0) * D_ + h * DH_;
#pragma unroll
            for (int it = 0; it < 2; ++it) {
                int idx = tid + it * 256;
                int kk = idx >> 3, d0 = (idx & 7) * 8;
                uint4 kv = *(const uint4*)(Kg + (size_t)kk * D_ + d0);
                *(uint4*)&K_lds[kk * 72 + d0] = kv;
                uint4 vv = *(const uint4*)(Vg + (size_t)kk * D_ + d0);
                unsigned short vs[8];
                *(uint4*)vs = vv;
#pragma unroll
                for (int j = 0; j < 8; ++j) {
                    int dd = d0 + j;
                    int boff = dd * 144 + ((kk * 2) ^ (((dd >> 3) & 7) << 4));
                    *(unsigned short*)((char*)VT_lds + boff) = vs[j];
                }
            }
        }
        __syncthreads();

        frag_ab kf[4][2];
#pragma unroll
        for (int kt = 0; kt < 4; ++kt) {
            const char* kp = (const char*)K_lds + (kt * 16 + l15) * 144 + g4 * 16;
            kf[kt][0] = *(const frag_ab*)kp;
            kf[kt][1] = *(const frag_ab*)(kp + 64);
        }
        frag_ab vf[4][2];
#pragma unroll
        for (int dt = 0; dt < 4; ++dt) {
            int drow = dt * 16 + l15;
            int swz = ((drow >> 3) & 7) << 4;
            const char* vp = (const char*)VT_lds + drow * 144;
            vf[dt][0] = *(const frag_ab*)(vp + ((g4 * 16) ^ swz));
            vf[dt][1] = *(const frag_ab*)(vp + ((g4 * 16 + 64) ^ swz));
        }

#pragma unroll
        for (int qt = 0; qt < 4; ++qt) {
            f32x4 st[4];
#pragma unroll
            for (int kt = 0; kt < 4; ++kt) {
                f32x4 z = (f32x4){0.f, 0.f, 0.f, 0.f};
                z = __builtin_amdgcn_mfma_f32_16x16x32_bf16(kf[kt][0], qf[qt][0], z, 0, 0, 0);
                z = __builtin_amdgcn_mfma_f32_16x16x32_bf16(kf[kt][1], qf[qt][1], z, 0, 0, 0);
                st[kt] = z;
            }
            int qa = cbase + w * 64 + qt * 16 + l15;
            float sv[16];
            float mx = -1e30f;
#pragma unroll
            for (int kt = 0; kt < 4; ++kt)
#pragma unroll
                for (int r = 0; r < 4; ++r) {
                    int ka = k0 + kt * 16 + g4 * 4 + r;
                    float s = st[kt][r] * 0.125f;
                    bool bad = (ka < NG_) | (ka - qa > W_) | (qa - ka > W_);
                    s = bad ? -1e30f : s;
                    sv[kt * 4 + r] = s;
                    mx = fmaxf(mx, s);
                }
            mx = fmaxf(mx, __shfl_xor(mx, 16));
            mx = fmaxf(mx, __shfl_xor(mx, 32));
            float mnew = fmaxf(fmaxf(mrun[qt], mx), -60.0f);
            float fsc = __expf(mrun[qt] - mnew);
            mrun[qt] = mnew;
#pragma unroll
            for (int dt = 0; dt < 4; ++dt) o[qt][dt] *= fsc;
            float psum = 0.f;
            unsigned short pb[16];
#pragma unroll
            for (int i = 0; i < 16; ++i) {
                float p = __expf(sv[i] - mnew);
                psum += p;
                pb[i] = f2bfu(p);
            }
            psum += __shfl_xor(psum, 16);
            psum += __shfl_xor(psum, 32);
            lrun[qt] = lrun[qt] * fsc + psum;
#pragma unroll
            for (int kt = 0; kt < 4; ++kt)
#pragma unroll
                for (int rp = 0; rp < 2; ++rp) {
                    unsigned vpk = (unsigned)pb[kt * 4 + rp * 2] | ((unsigned)pb[kt * 4 + rp * 2 + 1] << 16);
                    int kloc = kt * 16 + g4 * 4 + rp * 2;
                    *(unsigned*)(Pw + l15 * 144 + kloc * 2) = vpk;
                }
            frag_ab pf0 = *(const frag_ab*)(Pw + l15 * 144 + g4 * 16);
            frag_ab pf1 = *(const frag_ab*)(Pw + l15 * 144 + g4 * 16 + 64);
#pragma unroll
            for (int dt = 0; dt < 4; ++dt) {
                o[qt][dt] = __builtin_amdgcn_mfma_f32_16x16x32_bf16(vf[dt][0], pf0, o[qt][dt], 0, 0, 0);
                o[qt][dt] = __builtin_amdgcn_mfma_f32_16x16x32_bf16(vf[dt][1], pf1, o[qt][dt], 0, 0, 0);
            }
        }
    }

    // ---- 3 global keys (unmasked), scalar epilogue ----
    uint4 kgc[3][2];
    uint2 vgd[3][4];
#pragma unroll
    for (int gk = 0; gk < NG_; ++gk) {
        const __hip_bfloat16* kp = K + (size_t)(b * S_ + gk) * D_ + h * DH_ + g4 * 8;
        kgc[gk][0] = *(const uint4*)kp;
        kgc[gk][1] = *(const uint4*)(kp + 32);
        const __hip_bfloat16* vp = V + (size_t)(b * S_ + gk) * D_ + h * DH_ + g4 * 4;
#pragma unroll
        for (int dt = 0; dt < 4; ++dt)
            vgd[gk][dt] = *(const uint2*)(vp + dt * 16);
    }
#pragma unroll
    for (int qt = 0; qt < 4; ++qt) {
        float sg[3];
#pragma unroll
        for (int gk = 0; gk < NG_; ++gk) {
            float part = 0.f;
#pragma unroll
            for (int s = 0; s < 2; ++s) {
                uint4 qw = *(uint4*)&qf[qt][s];
                uint4 kw = kgc[gk][s];
                part += bflo(qw.x) * bflo(kw.x) + bfhi(qw.x) * bfhi(kw.x);
                part += bflo(qw.y) * bflo(kw.y) + bfhi(qw.y) * bfhi(kw.y);
                part += bflo(qw.z) * bflo(kw.z) + bfhi(qw.z) * bfhi(kw.z);
                part += bflo(qw.w) * bflo(kw.w) + bfhi(qw.w) * bfhi(kw.w);
            }
            part += __shfl_xor(part, 16);
            part += __shfl_xor(part, 32);
            sg[gk] = part * 0.125f;
        }
        float mx3 = fmaxf(fmaxf(sg[0], sg[1]), sg[2]);
        float mnew = fmaxf(fmaxf(mrun[qt], mx3), -60.0f);
        float fsc = __expf(mrun[qt] - mnew);
        mrun[qt] = mnew;
#pragma unroll
        for (int dt = 0; dt < 4; ++dt) o[qt][dt] *= fsc;
        float pg[3];
        float psum = 0.f;
#pragma unroll
        for (int gk = 0; gk < NG_; ++gk) { pg[gk] = __expf(sg[gk] - mnew); psum += pg[gk]; }
        lrun[qt] = lrun[qt] * fsc + psum;
#pragma unroll
        for (int dt = 0; dt < 4; ++dt) {
#pragma unroll
            for (int gk = 0; gk < NG_; ++gk) {
                uint2 vv = vgd[gk][dt];
                o[qt][dt][0] += pg[gk] * bflo(vv.x);
                o[qt][dt][1] += pg[gk] * bfhi(vv.x);
                o[qt][dt][2] += pg[gk] * bflo(vv.y);
                o[qt][dt][3] += pg[gk] * bfhi(vv.y);
            }
        }
    }

#pragma unroll
    for (int qt = 0; qt < 4; ++qt) {
        float linv = 1.0f / lrun[qt];
        int qa = cbase + w * 64 + qt * 16 + l15;
        __hip_bfloat16* orow = O + (size_t)(b * S_ + qa) * D_ + h * DH_;
#pragma unroll
        for (int dt = 0; dt < 4; ++dt) {
            unsigned short pk[4];
#pragma unroll
            for (int r = 0; r < 4; ++r) pk[r] = f2bfu(o[qt][dt][r] * linv);
            *(uint2*)(orow + dt * 16 + g4 * 4) = *(uint2*)pk;
        }
    }
}

// ---------------- global attention (3 queries attend to all S), bf16 K/V ----------------
template <typename TO>
__global__ __launch_bounds__(256) void global_attn_k(
    const float* __restrict__ qg, const __hip_bfloat16* __restrict__ KG,
    const __hip_bfloat16* __restrict__ VG, TO* __restrict__ outp, int rowStride) {
    __shared__ float sc[S_];
    __shared__ float qs[DH_];
    __shared__ float red[256];
    int g = blockIdx.x, h = blockIdx.y, b = blockIdx.z;
    int tid = threadIdx.x;
    if (tid < DH_) qs[tid] = qg[(size_t)(b * NG_ + g) * D_ + h * DH_ + tid] * 0.125f;
    __syncthreads();
    float qr[DH_];
#pragma unroll
    for (int d = 0; d < DH_; ++d) qr[d] = qs[d];
    float mloc = -1e30f;
    for (int s0 = tid; s0 < S_; s0 += 256) {
        const __hip_bfloat16* kp = KG + (size_t)(b * S_ + s0) * D_ + h * DH_;
        float acc = 0.f;
#pragma unroll
        for (int c8 = 0; c8 < 8; ++c8) {
            uint4 t = *(const uint4*)(kp + c8 * 8);
            float f[8]; unp8(t, f);
#pragma unroll
            for (int j = 0; j < 8; ++j) acc += qr[c8 * 8 + j] * f[j];
        }
        sc[s0] = acc;
        mloc = fmaxf(mloc, acc);
    }
    float m = block_max(mloc, red);
    float lsum = 0.f;
    for (int s0 = tid; s0 < S_; s0 += 256) {
        float e = __expf(sc[s0] - m);
        sc[s0] = e;
        lsum += e;
    }
    float l = block_sum(lsum, red);
    if (tid < DH_) {
        float linv = 1.0f / l;
        const unsigned short* vp = (const unsigned short*)(VG + (size_t)b * S_ * D_ + h * DH_ + tid);
        float a0 = 0.f, a1 = 0.f, a2 = 0.f, a3 = 0.f;
        for (int s0 = 0; s0 < S_; s0 += 4) {
            a0 += sc[s0 + 0] * bflo((unsigned int)vp[(size_t)(s0 + 0) * D_]);
            a1 += sc[s0 + 1] * bflo((unsigned int)vp[(size_t)(s0 + 1) * D_]);
            a2 += sc[s0 + 2] * bflo((unsigned int)vp[(size_t)(s0 + 2) * D_]);
            a3 += sc[s0 + 3] * bflo((unsigned int)vp[(size_t)(s0 + 3) * D_]);
        }
        storeO(&outp[(size_t)(b * rowStride + g) * D_ + h * DH_ + tid], (a0 + a1 + a2 + a3) * linv);
    }
}

// ---------------- gather the 6 global-token rows ----------------
__global__ void gather6_k(const float* __restrict__ X, float* __restrict__ xg) {
    int r = blockIdx.x;
    int b = r / NG_, g = r % NG_;
    for (int c = threadIdx.x; c < D_; c += blockDim.x)
        xg[(size_t)r * D_ + c] = X[(size_t)(b * S_ + g) * D_ + c];
}

// ---------------- classifier heads ----------------
__global__ __launch_bounds__(256) void classifier_k(
    const float* __restrict__ x26, const float* __restrict__ cw,
    const float* __restrict__ cb, float* __restrict__ out) {
    __shared__ float red[256];
    int tid = threadIdx.x;
    for (int i = 0; i < 3; ++i) {
        for (int b = 0; b < B_; ++b) {
            const float* xr = x26 + (size_t)(b * NG_ + i) * D_;
            const float* wr = cw + (size_t)i * D_;
            float p = 0.f;
            for (int c = tid; c < D_; c += 256) p += xr[c] * wr[c];
            float dotv = block_sum(p, red);
            if (tid == 0) out[i * B_ + b] = 1.0f / (1.0f + __expf(-(dotv + cb[i])));
        }
    }
    if (tid == 0) { out[6] = 1.0f; out[7] = 1.0f; }
}

// ---------------- host launcher ----------------
extern "C" void kernel_launch(void* const* d_in, const int* in_sizes, int n_in,
                              void* d_out, int out_size, void* d_ws, size_t ws_size,
                              hipStream_t stream) {
    const int*   src      = (const int*)d_in[0];
    const float* word_emb = (const float*)d_in[3];
    const float* pos_emb  = (const float*)d_in[4];
    const float* emb_ln   = (const float*)d_in[5];
    const float* attn_w   = (const float*)d_in[6];
    const float* attn_b   = (const float*)d_in[7];
    const float* ln_p     = (const float*)d_in[8];
    const float* ffn_w1   = (const float*)d_in[9];
    const float* ffn_b1   = (const float*)d_in[10];
    const float* ffn_w2   = (const float*)d_in[11];
    const float* ffn_b2   = (const float*)d_in[12];
    const float* cls_w    = (const float*)d_in[13];
    const float* cls_b    = (const float*)d_in[14];
    float* out = (float*)d_out;

    const size_t NT = (size_t)B_ * S_ * D_;  // 6291456 (elements)
    float* base = (float*)d_ws;
    float* X  = base;
    float* P4 = base + NT;
    __hip_bfloat16* Xb = (__hip_bfloat16*)(base + 2 * NT);
    __hip_bfloat16* Qb = (__hip_bfloat16*)(base + 5 * NT / 2);
    __hip_bfloat16* Kb = (__hip_bfloat16*)(base + 3 * NT);
    __hip_bfloat16* Vb = (__hip_bfloat16*)(base + 7 * NT / 2);
    __hip_bfloat16* AOb = (__hip_bfloat16*)(base + 4 * NT);
    __hip_bfloat16* HCb = AOb;
    __hip_bfloat16* wq  = (__hip_bfloat16*)(base + 5 * NT);
    __hip_bfloat16* wk  = wq + 589824;
    __hip_bfloat16* wv  = wk + 589824;
    __hip_bfloat16* wg1 = wv + 589824;
    __hip_bfloat16* wg2 = wg1 + 589824;
    __hip_bfloat16* wo  = wg2 + 589824;
    __hip_bfloat16* wf1 = wo + 589824;
    __hip_bfloat16* wf2 = wf1 + 2359296;
    float* SM  = base + 5 * NT + 4128768;
    float* xg  = SM;
    float* qg6 = xg + 6 * D_;
    float* og6 = qg6 + 6 * D_;
    float* pr6 = og6 + 6 * D_;
    float* xa6 = pr6 + 6 * D_;
    float* h6  = xa6 + 6 * D_;
    float* f6  = h6 + 6 * FF_;
    float* x26 = f6 + 6 * D_;
    float* part = x26 + 6 * D_;  // split-K partials (max 48*6*768 = 221184 f32)

    const int M = B_ * S_;
    dim3 blk(256);

    auto aw = [&](int l, int i) { return attn_w + ((size_t)(l * 7 + i)) * D_ * D_; };
    auto ab = [&](int l, int i) { return attn_b + (size_t)(l * 7 + i) * D_; };
    auto lnp = [&](int l, int i) { return ln_p + (size_t)(l * 4 + i) * D_; };

    // skinny GEMM helper: out6[6][N] = A6[6][K] @ W[K][N] + bias (optional gelu)
    auto skinny = [&](const float* A6, const float* Wm, const float* bias,
                      float* out6, int N, int K, int gelu) {
        skinny_gemm_k<<<dim3(N / 64, K / 64), blk, 0, stream>>>(A6, Wm, part, N, K);
        skinny_reduce_k<<<dim3((6 * N + 255) / 256), blk, 0, stream>>>(part, bias, out6, N, K / 64, gelu);
    };

    embed_ln_k<<<M, blk, 0, stream>>>(src, word_emb, pos_emb, emb_ln, emb_ln + D_, X, Xb);

    // ================= layer 0 =================
    convt_k<<<dim3(24, 24), blk, 0, stream>>>(aw(0, 0), wq, D_, D_);
    convt_k<<<dim3(24, 24), blk, 0, stream>>>(aw(0, 1), wk, D_, D_);
    convt_k<<<dim3(24, 24), blk, 0, stream>>>(aw(0, 2), wv, D_, D_);
    mfma_gemm_k<1><<<dim3(6, 64), blk, 0, stream>>>(Xb, wq, ab(0, 0), Qb, M, D_, D_);
    mfma_gemm_k<1><<<dim3(6, 64), blk, 0, stream>>>(Xb, wk, ab(0, 1), Kb, M, D_, D_);
    mfma_gemm_k<1><<<dim3(6, 64), blk, 0, stream>>>(Xb, wv, ab(0, 2), Vb, M, D_, D_);
    local_attn_k<<<dim3(NC_, H_, B_), blk, 0, stream>>>(Qb, Kb, Vb, AOb);
    convt_k<<<dim3(24, 24), blk, 0, stream>>>(aw(0, 4), wg1, D_, D_);
    convt_k<<<dim3(24, 24), blk, 0, stream>>>(aw(0, 5), wg2, D_, D_);
    mfma_gemm_k<1><<<dim3(6, 64), blk, 0, stream>>>(Xb, wg1, ab(0, 4), Qb, M, D_, D_);
    mfma_gemm_k<1><<<dim3(6, 64), blk, 0, stream>>>(Xb, wg2, ab(0, 5), Kb, M, D_, D_);
    gather6_k<<<B_ * NG_, blk, 0, stream>>>(X, xg);
    skinny(xg, aw(0, 3), ab(0, 3), qg6, D_, D_, 0);
    global_attn_k<__hip_bfloat16><<<dim3(NG_, H_, B_), blk, 0, stream>>>(qg6, Qb, Kb, AOb, S_);
    convt_k<<<dim3(24, 24), blk, 0, stream>>>(aw(0, 6), wo, D_, D_);
    mfma_gemm_k<0><<<dim3(6, 64), blk, 0, stream>>>(AOb, wo, ab(0, 6), P4, M, D_, D_);
    residual_ln_k<<<M, blk, 0, stream>>>(X, P4, lnp(0, 0), lnp(0, 1), P4, Xb);
    convt_k<<<dim3(96, 24), blk, 0, stream>>>(ffn_w1, wf1, D_, FF_);
    convt_k<<<dim3(24, 96), blk, 0, stream>>>(ffn_w2, wf2, FF_, D_);
    for (int ch = 0; ch < 2; ++ch) {
        mfma_gemm_k<2><<<dim3(24, 32), blk, 0, stream>>>(Xb + (size_t)ch * 4096 * D_, wf1, ffn_b1, HCb, 4096, FF_, D_);
        mfma_gemm_k<0><<<dim3(6, 32), blk, 0, stream>>>(HCb, wf2, ffn_b2, X + (size_t)ch * 4096 * D_, 4096, D_, FF_);
    }
    residual_ln_k<<<M, blk, 0, stream>>>(P4, X, lnp(0, 2), lnp(0, 3), X, Xb);

    // ================= layer 1 (pruned) =================
    convt_k<<<dim3(24, 24), blk, 0, stream>>>(aw(1, 4), wg1, D_, D_);
    convt_k<<<dim3(24, 24), blk, 0, stream>>>(aw(1, 5), wg2, D_, D_);
    mfma_gemm_k<1><<<dim3(6, 64), blk, 0, stream>>>(Xb, wg1, ab(1, 4), Qb, M, D_, D_);
    mfma_gemm_k<1><<<dim3(6, 64), blk, 0, stream>>>(Xb, wg2, ab(1, 5), Kb, M, D_, D_);
    gather6_k<<<B_ * NG_, blk, 0, stream>>>(X, xg);
    skinny(xg, aw(1, 3), ab(1, 3), qg6, D_, D_, 0);
    global_attn_k<float><<<dim3(NG_, H_, B_), blk, 0, stream>>>(qg6, Qb, Kb, og6, NG_);
    skinny(og6, aw(1, 6), ab(1, 6), pr6, D_, D_, 0);
    residual_ln_k<<<B_ * NG_, blk, 0, stream>>>(xg, pr6, lnp(1, 0), lnp(1, 1), xa6, nullptr);
    skinny(xa6, ffn_w1 + (size_t)D_ * FF_, ffn_b1 + FF_, h6, FF_, D_, 1);
    skinny(h6, ffn_w2 + (size_t)FF_ * D_, ffn_b2 + D_, f6, D_, FF_, 0);
    residual_ln_k<<<B_ * NG_, blk, 0, stream>>>(xa6, f6, lnp(1, 2), lnp(1, 3), x26, nullptr);
    classifier_k<<<1, blk, 0, stream>>>(x26, cls_w, cls_b, out);
}

// Round 7
// 635.373 us; speedup vs baseline: 18.7050x; 1.3346x over previous
//
#include <hip/hip_runtime.h>
#include <hip/hip_bf16.h>
#include <math.h>

// ---------------- constants (problem shapes) ----------------
#define B_    2
#define SSRC_ 4093
#define D_    768
#define H_    12
#define DH_   64
#define FF_   3072
#define NG_   3
#define W_    256
#define S_    4096
#define NC_   16
#define NSPLIT_ 16   // global-attention S-splits (S/NSPLIT = 256 keys per block)

typedef __attribute__((ext_vector_type(8))) short frag_ab;   // 8 bf16 (4 VGPRs)
typedef __attribute__((ext_vector_type(4))) float f32x4;     // 4 fp32 acc

// ---------------- helpers ----------------
__device__ __forceinline__ float bflo(unsigned int w) {
    union { float f; unsigned int i; } c; c.i = w << 16; return c.f;
}
__device__ __forceinline__ float bfhi(unsigned int w) {
    union { float f; unsigned int i; } c; c.i = w & 0xffff0000u; return c.f;
}
__device__ __forceinline__ void unp8(uint4 t, float* o) {
    o[0] = bflo(t.x); o[1] = bfhi(t.x); o[2] = bflo(t.y); o[3] = bfhi(t.y);
    o[4] = bflo(t.z); o[5] = bfhi(t.z); o[6] = bflo(t.w); o[7] = bfhi(t.w);
}
__device__ __forceinline__ unsigned short f2bfu(float x) {
    __hip_bfloat16 h = __float2bfloat16(x);
    return *reinterpret_cast<unsigned short*>(&h);
}

__device__ __forceinline__ float block_sum(float v, float* red) {
    int tid = threadIdx.x;
    red[tid] = v;
    __syncthreads();
#pragma unroll
    for (int off = 128; off >= 1; off >>= 1) {
        if (tid < off) red[tid] += red[tid + off];
        __syncthreads();
    }
    float r = red[0];
    __syncthreads();
    return r;
}

__device__ __forceinline__ float block_max(float v, float* red) {
    int tid = threadIdx.x;
    red[tid] = v;
    __syncthreads();
#pragma unroll
    for (int off = 128; off >= 1; off >>= 1) {
        if (tid < off) red[tid] = fmaxf(red[tid], red[tid + off]);
        __syncthreads();
    }
    float r = red[0];
    __syncthreads();
    return r;
}

__device__ __forceinline__ void storeO(float* p, float v) { *p = v; }
__device__ __forceinline__ void storeO(__hip_bfloat16* p, float v) { *p = __float2bfloat16(v); }

// ---------------- embedding + LN (writes f32 X and bf16 Xb) ----------------
__global__ __launch_bounds__(256) void embed_ln_k(
    const int* __restrict__ src, const float* __restrict__ we,
    const float* __restrict__ pe, const float* __restrict__ gam,
    const float* __restrict__ bet, float* __restrict__ X,
    __hip_bfloat16* __restrict__ Xb) {
    __shared__ float red[256];
    int row = blockIdx.x;
    int b = row >> 12;
    int s = row & (S_ - 1);
    int tid = threadIdx.x;
    int id = (s < NG_) ? (50261 + s) : src[b * SSRC_ + (s - NG_)];
    const float* wr = we + (size_t)id * D_;
    const float* pr = pe + (size_t)s * D_;
    float v[3];
    float lsum = 0.f;
#pragma unroll
    for (int j = 0; j < 3; ++j) {
        int c = tid + j * 256;
        v[j] = wr[c] + pr[c];
        lsum += v[j];
    }
    float mu = block_sum(lsum, red) * (1.0f / 768.0f);
    float ls2 = 0.f;
#pragma unroll
    for (int j = 0; j < 3; ++j) { float d = v[j] - mu; ls2 += d * d; }
    float var = block_sum(ls2, red) * (1.0f / 768.0f);
    float rs = rsqrtf(var + 1e-5f);
    float* xr = X + (size_t)row * D_;
    __hip_bfloat16* xbr = Xb + (size_t)row * D_;
#pragma unroll
    for (int j = 0; j < 3; ++j) {
        int c = tid + j * 256;
        float o = (v[j] - mu) * rs * gam[c] + bet[c];
        xr[c] = o;
        xbr[c] = __float2bfloat16(o);
    }
}

// ---------------- residual + LN : out = LN(x + y), optional bf16 mirror ----------------
__global__ __launch_bounds__(256) void residual_ln_k(
    const float* __restrict__ x, const float* __restrict__ y,
    const float* __restrict__ gam, const float* __restrict__ bet,
    float* __restrict__ out, __hip_bfloat16* __restrict__ outb) {
    __shared__ float red[256];
    int row = blockIdx.x;
    int tid = threadIdx.x;
    const float* xr = x + (size_t)row * D_;
    const float* yr = y + (size_t)row * D_;
    float v[3];
    float lsum = 0.f;
#pragma unroll
    for (int j = 0; j < 3; ++j) {
        int c = tid + j * 256;
        v[j] = xr[c] + yr[c];
        lsum += v[j];
    }
    float mu = block_sum(lsum, red) * (1.0f / 768.0f);
    float ls2 = 0.f;
#pragma unroll
    for (int j = 0; j < 3; ++j) { float d = v[j] - mu; ls2 += d * d; }
    float var = block_sum(ls2, red) * (1.0f / 768.0f);
    float rs = rsqrtf(var + 1e-5f);
    float* orow = out + (size_t)row * D_;
    __hip_bfloat16* obr = outb ? outb + (size_t)row * D_ : nullptr;
#pragma unroll
    for (int j = 0; j < 3; ++j) {
        int c = tid + j * 256;
        float o = (v[j] - mu) * rs * gam[c] + bet[c];
        orow[c] = o;
        if (obr) obr[c] = __float2bfloat16(o);
    }
}

// ---------------- transpose-convert: W[K,N] f32 -> WT[N,K] bf16 ----------------
__global__ __launch_bounds__(256) void convt_k(
    const float* __restrict__ W, __hip_bfloat16* __restrict__ WT, int K, int N) {
    __shared__ float tile[32][33];
    int bx = blockIdx.x, by = blockIdx.y;
    int tx = threadIdx.x & 31, ty = threadIdx.x >> 5;
#pragma unroll
    for (int i = 0; i < 32; i += 8)
        tile[ty + i][tx] = W[(size_t)(by * 32 + ty + i) * N + bx * 32 + tx];
    __syncthreads();
#pragma unroll
    for (int i = 0; i < 32; i += 8)
        WT[(size_t)(bx * 32 + ty + i) * K + by * 32 + tx] = __float2bfloat16(tile[tx][ty + i]);
}

// ---------------- MFMA GEMM: C[M,N] = A[M,K]bf16 @ BT[N,K]bf16^T + bias ----------------
template <int EPI>
__global__ __launch_bounds__(256) void mfma_gemm_k(
    const __hip_bfloat16* __restrict__ A, const __hip_bfloat16* __restrict__ BT,
    const float* __restrict__ bias, void* __restrict__ Cout,
    int M, int N, int K) {
    __shared__ __align__(16) __hip_bfloat16 As[4096];
    __shared__ __align__(16) __hip_bfloat16 Bs[4096];
    int tid = threadIdx.x;
    int lane = tid & 63;
    int w = tid >> 6, wr = w >> 1, wc = w & 1;
    int brow = blockIdx.y * 128, bcol = blockIdx.x * 128;
    int r0 = tid >> 2, k0 = (tid & 3) * 8;
    const __hip_bfloat16* Ag0 = A + (size_t)(brow + r0) * K + k0;
    const __hip_bfloat16* Ag1 = Ag0 + (size_t)64 * K;
    const __hip_bfloat16* Bg0 = BT + (size_t)(bcol + r0) * K + k0;
    const __hip_bfloat16* Bg1 = Bg0 + (size_t)64 * K;

    f32x4 acc[4][4];
#pragma unroll
    for (int m = 0; m < 4; ++m)
#pragma unroll
        for (int n = 0; n < 4; ++n) acc[m][n] = (f32x4){0.f, 0.f, 0.f, 0.f};

    int l15 = lane & 15, kb = lane >> 4;
    int aoff = (wr * 64 + l15) * 32 + kb * 8;
    int boff = (wc * 64 + l15) * 32 + kb * 8;

    uint4 pa0 = *(const uint4*)Ag0, pa1 = *(const uint4*)Ag1;
    uint4 pb0 = *(const uint4*)Bg0, pb1 = *(const uint4*)Bg1;

    for (int kt = 0; kt < K; kt += 32) {
        *(uint4*)&As[(size_t)tid * 8] = pa0;
        *(uint4*)&As[(size_t)tid * 8 + 2048] = pa1;
        *(uint4*)&Bs[(size_t)tid * 8] = pb0;
        *(uint4*)&Bs[(size_t)tid * 8 + 2048] = pb1;
        __syncthreads();
        if (kt + 32 < K) {
            pa0 = *(const uint4*)(Ag0 + kt + 32);
            pa1 = *(const uint4*)(Ag1 + kt + 32);
            pb0 = *(const uint4*)(Bg0 + kt + 32);
            pb1 = *(const uint4*)(Bg1 + kt + 32);
        }
        frag_ab af[4], bf[4];
#pragma unroll
        for (int m = 0; m < 4; ++m) af[m] = *(const frag_ab*)&As[aoff + m * 512];
#pragma unroll
        for (int n = 0; n < 4; ++n) bf[n] = *(const frag_ab*)&Bs[boff + n * 512];
#pragma unroll
        for (int m = 0; m < 4; ++m)
#pragma unroll
            for (int n = 0; n < 4; ++n)
                acc[m][n] = __builtin_amdgcn_mfma_f32_16x16x32_bf16(af[m], bf[n], acc[m][n], 0, 0, 0);
        __syncthreads();
    }

#pragma unroll
    for (int m = 0; m < 4; ++m) {
        int rowb = brow + wr * 64 + m * 16 + (lane >> 4) * 4;
#pragma unroll
        for (int n = 0; n < 4; ++n) {
            int col = bcol + wc * 64 + n * 16 + l15;
            float bv = bias[col];
#pragma unroll
            for (int r = 0; r < 4; ++r) {
                float v = acc[m][n][r] + bv;
                size_t idx = (size_t)(rowb + r) * N + col;
                if (EPI == 0) {
                    ((float*)Cout)[idx] = v;
                } else if (EPI == 1) {
                    ((__hip_bfloat16*)Cout)[idx] = __float2bfloat16(v);
                } else {
                    float g = 0.5f * v * (1.0f + erff(v * 0.70710678118654752f));
                    ((__hip_bfloat16*)Cout)[idx] = __float2bfloat16(g);
                }
            }
        }
    }
}

// ---------------- split-K skinny GEMM: M=6 rows ----------------
__global__ __launch_bounds__(256) void skinny_gemm_k(
    const float* __restrict__ A, const float* __restrict__ W,
    float* __restrict__ partial, int N, int K) {
    __shared__ float Asl[6][64];
    __shared__ float red[4][6][64];
    int tid = threadIdx.x;
    int cl = tid & 63;
    int kg = tid >> 6;
    int col = blockIdx.x * 64 + cl;
    int k0 = blockIdx.y * 64;
    for (int i = tid; i < 6 * 64; i += 256)
        Asl[i >> 6][i & 63] = A[(size_t)(i >> 6) * K + k0 + (i & 63)];
    __syncthreads();
    float acc[6] = {0.f, 0.f, 0.f, 0.f, 0.f, 0.f};
#pragma unroll
    for (int kk = 0; kk < 16; ++kk) {
        int k = kg * 16 + kk;
        float wv = W[(size_t)(k0 + k) * N + col];
#pragma unroll
        for (int m = 0; m < 6; ++m) acc[m] += Asl[m][k] * wv;
    }
#pragma unroll
    for (int m = 0; m < 6; ++m) red[kg][m][cl] = acc[m];
    __syncthreads();
    for (int i = tid; i < 6 * 64; i += 256) {
        int m = i >> 6, lane = i & 63;
        float s = red[0][m][lane] + red[1][m][lane] + red[2][m][lane] + red[3][m][lane];
        partial[(size_t)blockIdx.y * 6 * N + (size_t)m * N + blockIdx.x * 64 + lane] = s;
    }
}

__global__ __launch_bounds__(256) void skinny_reduce_k(
    const float* __restrict__ partial, const float* __restrict__ bias,
    float* __restrict__ outp, int N, int KS, int gelu) {
    int idx = blockIdx.x * 256 + threadIdx.x;
    if (idx >= 6 * N) return;
    int m = idx / N, col = idx - m * N;
    float s = bias[col];
    for (int kb = 0; kb < KS; ++kb)
        s += partial[(size_t)kb * 6 * N + (size_t)m * N + col];
    if (gelu) s = 0.5f * s * (1.0f + erff(s * 0.70710678118654752f));
    outp[(size_t)m * N + col] = s;
}

// ---------------- MFMA sliding-window local attention ----------------
__global__ __launch_bounds__(256, 1) void local_attn_k(
    const __hip_bfloat16* __restrict__ Q, const __hip_bfloat16* __restrict__ K,
    const __hip_bfloat16* __restrict__ V, __hip_bfloat16* __restrict__ O) {
    __shared__ __align__(16) __hip_bfloat16 K_lds[64 * 72];
    __shared__ __align__(16) __hip_bfloat16 VT_lds[64 * 72];
    __shared__ __align__(16) __hip_bfloat16 P_lds[4][16 * 72];

    const int c = blockIdx.x, h = blockIdx.y, b = blockIdx.z;
    const int tid = threadIdx.x;
    const int lane = tid & 63;
    const int w = tid >> 6;
    const int l15 = lane & 15, g4 = lane >> 4;
    const int cbase = c * W_;

    frag_ab qf[4][2];
#pragma unroll
    for (int qt = 0; qt < 4; ++qt) {
        int qa = cbase + w * 64 + qt * 16 + l15;
        const __hip_bfloat16* qp = Q + (size_t)(b * S_ + qa) * D_ + h * DH_ + g4 * 8;
        qf[qt][0] = *(const frag_ab*)qp;
        qf[qt][1] = *(const frag_ab*)(qp + 32);
    }

    f32x4 o[4][4];
#pragma unroll
    for (int qt = 0; qt < 4; ++qt)
#pragma unroll
        for (int dt = 0; dt < 4; ++dt) o[qt][dt] = (f32x4){0.f, 0.f, 0.f, 0.f};
    float mrun[4] = {-1e30f, -1e30f, -1e30f, -1e30f};
    float lrun[4] = {0.f, 0.f, 0.f, 0.f};

    int kw0 = cbase - W_; if (kw0 < 0) kw0 = 0;
    int kw1 = cbase + 2 * W_; if (kw1 > S_) kw1 = S_;
    int ntiles = (kw1 - kw0) >> 6;

    char* Pw = (char*)P_lds[w];

    for (int t = 0; t < ntiles; ++t) {
        int k0 = kw0 + t * 64;
        __syncthreads();
        {
            const __hip_bfloat16* Kg = K + (size_t)(b * S_ + k0) * D_ + h * DH_;
            const __hip_bfloat16* Vg = V + (size_t)(b * S_ + k0) * D_ + h * DH_;
#pragma unroll
            for (int it = 0; it < 2; ++it) {
                int idx = tid + it * 256;
                int kk = idx >> 3, d0 = (idx & 7) * 8;
                uint4 kv = *(const uint4*)(Kg + (size_t)kk * D_ + d0);
                *(uint4*)&K_lds[kk * 72 + d0] = kv;
                uint4 vv = *(const uint4*)(Vg + (size_t)kk * D_ + d0);
                unsigned short vs[8];
                *(uint4*)vs = vv;
#pragma unroll
                for (int j = 0; j < 8; ++j) {
                    int dd = d0 + j;
                    int boff = dd * 144 + ((kk * 2) ^ (((dd >> 3) & 7) << 4));
                    *(unsigned short*)((char*)VT_lds + boff) = vs[j];
                }
            }
        }
        __syncthreads();

        frag_ab kf[4][2];
#pragma unroll
        for (int kt = 0; kt < 4; ++kt) {
            const char* kp = (const char*)K_lds + (kt * 16 + l15) * 144 + g4 * 16;
            kf[kt][0] = *(const frag_ab*)kp;
            kf[kt][1] = *(const frag_ab*)(kp + 64);
        }
        frag_ab vf[4][2];
#pragma unroll
        for (int dt = 0; dt < 4; ++dt) {
            int drow = dt * 16 + l15;
            int swz = ((drow >> 3) & 7) << 4;
            const char* vp = (const char*)VT_lds + drow * 144;
            vf[dt][0] = *(const frag_ab*)(vp + ((g4 * 16) ^ swz));
            vf[dt][1] = *(const frag_ab*)(vp + ((g4 * 16 + 64) ^ swz));
        }

#pragma unroll
        for (int qt = 0; qt < 4; ++qt) {
            f32x4 st[4];
#pragma unroll
            for (int kt = 0; kt < 4; ++kt) {
                f32x4 z = (f32x4){0.f, 0.f, 0.f, 0.f};
                z = __builtin_amdgcn_mfma_f32_16x16x32_bf16(kf[kt][0], qf[qt][0], z, 0, 0, 0);
                z = __builtin_amdgcn_mfma_f32_16x16x32_bf16(kf[kt][1], qf[qt][1], z, 0, 0, 0);
                st[kt] = z;
            }
            int qa = cbase + w * 64 + qt * 16 + l15;
            float sv[16];
            float mx = -1e30f;
#pragma unroll
            for (int kt = 0; kt < 4; ++kt)
#pragma unroll
                for (int r = 0; r < 4; ++r) {
                    int ka = k0 + kt * 16 + g4 * 4 + r;
                    float s = st[kt][r] * 0.125f;
                    bool bad = (ka < NG_) | (ka - qa > W_) | (qa - ka > W_);
                    s = bad ? -1e30f : s;
                    sv[kt * 4 + r] = s;
                    mx = fmaxf(mx, s);
                }
            mx = fmaxf(mx, __shfl_xor(mx, 16));
            mx = fmaxf(mx, __shfl_xor(mx, 32));
            float mnew = fmaxf(fmaxf(mrun[qt], mx), -60.0f);
            float fsc = __expf(mrun[qt] - mnew);
            mrun[qt] = mnew;
#pragma unroll
            for (int dt = 0; dt < 4; ++dt) o[qt][dt] *= fsc;
            float psum = 0.f;
            unsigned short pb[16];
#pragma unroll
            for (int i = 0; i < 16; ++i) {
                float p = __expf(sv[i] - mnew);
                psum += p;
                pb[i] = f2bfu(p);
            }
            psum += __shfl_xor(psum, 16);
            psum += __shfl_xor(psum, 32);
            lrun[qt] = lrun[qt] * fsc + psum;
#pragma unroll
            for (int kt = 0; kt < 4; ++kt)
#pragma unroll
                for (int rp = 0; rp < 2; ++rp) {
                    unsigned vpk = (unsigned)pb[kt * 4 + rp * 2] | ((unsigned)pb[kt * 4 + rp * 2 + 1] << 16);
                    int kloc = kt * 16 + g4 * 4 + rp * 2;
                    *(unsigned*)(Pw + l15 * 144 + kloc * 2) = vpk;
                }
            frag_ab pf0 = *(const frag_ab*)(Pw + l15 * 144 + g4 * 16);
            frag_ab pf1 = *(const frag_ab*)(Pw + l15 * 144 + g4 * 16 + 64);
#pragma unroll
            for (int dt = 0; dt < 4; ++dt) {
                o[qt][dt] = __builtin_amdgcn_mfma_f32_16x16x32_bf16(vf[dt][0], pf0, o[qt][dt], 0, 0, 0);
                o[qt][dt] = __builtin_amdgcn_mfma_f32_16x16x32_bf16(vf[dt][1], pf1, o[qt][dt], 0, 0, 0);
            }
        }
    }

    // ---- 3 global keys (unmasked), scalar epilogue ----
    uint4 kgc[3][2];
    uint2 vgd[3][4];
#pragma unroll
    for (int gk = 0; gk < NG_; ++gk) {
        const __hip_bfloat16* kp = K + (size_t)(b * S_ + gk) * D_ + h * DH_ + g4 * 8;
        kgc[gk][0] = *(const uint4*)kp;
        kgc[gk][1] = *(const uint4*)(kp + 32);
        const __hip_bfloat16* vp = V + (size_t)(b * S_ + gk) * D_ + h * DH_ + g4 * 4;
#pragma unroll
        for (int dt = 0; dt < 4; ++dt)
            vgd[gk][dt] = *(const uint2*)(vp + dt * 16);
    }
#pragma unroll
    for (int qt = 0; qt < 4; ++qt) {
        float sg[3];
#pragma unroll
        for (int gk = 0; gk < NG_; ++gk) {
            float part = 0.f;
#pragma unroll
            for (int s = 0; s < 2; ++s) {
                uint4 qw = *(uint4*)&qf[qt][s];
                uint4 kw = kgc[gk][s];
                part += bflo(qw.x) * bflo(kw.x) + bfhi(qw.x) * bfhi(kw.x);
                part += bflo(qw.y) * bflo(kw.y) + bfhi(qw.y) * bfhi(kw.y);
                part += bflo(qw.z) * bflo(kw.z) + bfhi(qw.z) * bfhi(kw.z);
                part += bflo(qw.w) * bflo(kw.w) + bfhi(qw.w) * bfhi(kw.w);
            }
            part += __shfl_xor(part, 16);
            part += __shfl_xor(part, 32);
            sg[gk] = part * 0.125f;
        }
        float mx3 = fmaxf(fmaxf(sg[0], sg[1]), sg[2]);
        float mnew = fmaxf(fmaxf(mrun[qt], mx3), -60.0f);
        float fsc = __expf(mrun[qt] - mnew);
        mrun[qt] = mnew;
#pragma unroll
        for (int dt = 0; dt < 4; ++dt) o[qt][dt] *= fsc;
        float pg[3];
        float psum = 0.f;
#pragma unroll
        for (int gk = 0; gk < NG_; ++gk) { pg[gk] = __expf(sg[gk] - mnew); psum += pg[gk]; }
        lrun[qt] = lrun[qt] * fsc + psum;
#pragma unroll
        for (int dt = 0; dt < 4; ++dt) {
#pragma unroll
            for (int gk = 0; gk < NG_; ++gk) {
                uint2 vv = vgd[gk][dt];
                o[qt][dt][0] += pg[gk] * bflo(vv.x);
                o[qt][dt][1] += pg[gk] * bfhi(vv.x);
                o[qt][dt][2] += pg[gk] * bflo(vv.y);
                o[qt][dt][3] += pg[gk] * bfhi(vv.y);
            }
        }
    }

#pragma unroll
    for (int qt = 0; qt < 4; ++qt) {
        float linv = 1.0f / lrun[qt];
        int qa = cbase + w * 64 + qt * 16 + l15;
        __hip_bfloat16* orow = O + (size_t)(b * S_ + qa) * D_ + h * DH_;
#pragma unroll
        for (int dt = 0; dt < 4; ++dt) {
            unsigned short pk[4];
#pragma unroll
            for (int r = 0; r < 4; ++r) pk[r] = f2bfu(o[qt][dt][r] * linv);
            *(uint2*)(orow + dt * 16 + g4 * 4) = *(uint2*)pk;
        }
    }
}

// ---------------- global attention, split-S flash decode ----------------
// grid (NSPLIT_, NG*H, B), 256 threads. Each block: 256 keys.
// gpart layout: [(b*NG+g)*H+h][NSPLIT][66] = {m, l, o[64]}
__global__ __launch_bounds__(256) void gattn_part_k(
    const float* __restrict__ qg, const __hip_bfloat16* __restrict__ KG,
    const __hip_bfloat16* __restrict__ VG, float* __restrict__ gpart) {
    __shared__ float sc[256];
    __shared__ float qs[DH_];
    __shared__ float red[256];
    __shared__ float rv[16][64];
    int split = blockIdx.x;
    int gh = blockIdx.y;
    int g = gh / H_, h = gh - g * H_;
    int b = blockIdx.z;
    int tid = threadIdx.x;
    if (tid < DH_) qs[tid] = qg[(size_t)(b * NG_ + g) * D_ + h * DH_ + tid] * 0.125f;
    __syncthreads();
    int s0 = split * (S_ / NSPLIT_);
    // ---- QK^T: one key per thread ----
    float acc = 0.f;
    {
        const __hip_bfloat16* kp = KG + (size_t)(b * S_ + s0 + tid) * D_ + h * DH_;
#pragma unroll
        for (int c8 = 0; c8 < 8; ++c8) {
            uint4 t = *(const uint4*)(kp + c8 * 8);
            float f[8]; unp8(t, f);
#pragma unroll
            for (int j = 0; j < 8; ++j) acc += qs[c8 * 8 + j] * f[j];
        }
    }
    float m = block_max(acc, red);
    float e = __expf(acc - m);
    sc[tid] = e;
    float l = block_sum(e, red);
    // ---- PV: 16 s-groups x 16 d-quads ----
    int sgq = tid >> 4, dq = (tid & 15) * 4;
    float a0 = 0.f, a1 = 0.f, a2 = 0.f, a3 = 0.f;
    const __hip_bfloat16* vbase = VG + (size_t)(b * S_ + s0 + sgq * 16) * D_ + h * DH_ + dq;
#pragma unroll
    for (int i = 0; i < 16; ++i) {
        float p = sc[sgq * 16 + i];
        uint2 vv = *(const uint2*)(vbase + (size_t)i * D_);
        a0 += p * bflo(vv.x); a1 += p * bfhi(vv.x);
        a2 += p * bflo(vv.y); a3 += p * bfhi(vv.y);
    }
    rv[sgq][dq] = a0; rv[sgq][dq + 1] = a1; rv[sgq][dq + 2] = a2; rv[sgq][dq + 3] = a3;
    __syncthreads();
    float* op = gpart + ((size_t)((b * NG_ + g) * H_ + h) * NSPLIT_ + split) * 66;
    if (tid == 0) { op[0] = m; op[1] = l; }
    if (tid < DH_) {
        float s = 0.f;
#pragma unroll
        for (int j = 0; j < 16; ++j) s += rv[j][tid];
        op[2 + tid] = s;
    }
}

// combine NSPLIT partials; grid (NG, H, B), 64 threads
template <typename TO>
__global__ __launch_bounds__(64) void gattn_comb_k(
    const float* __restrict__ gpart, TO* __restrict__ outp, int rowStride) {
    int g = blockIdx.x, h = blockIdx.y, b = blockIdx.z;
    int tid = threadIdx.x;
    const float* base = gpart + (size_t)((b * NG_ + g) * H_ + h) * NSPLIT_ * 66;
    float M = -1e30f;
#pragma unroll
    for (int p = 0; p < NSPLIT_; ++p) M = fmaxf(M, base[p * 66]);
    float l = 0.f, o = 0.f;
#pragma unroll
    for (int p = 0; p < NSPLIT_; ++p) {
        float wgt = __expf(base[p * 66] - M);
        l += wgt * base[p * 66 + 1];
        o += wgt * base[p * 66 + 2 + tid];
    }
    storeO(&outp[(size_t)(b * rowStride + g) * D_ + h * DH_ + tid], o / l);
}

// ---------------- gather the 6 global-token rows ----------------
__global__ void gather6_k(const float* __restrict__ X, float* __restrict__ xg) {
    int r = blockIdx.x;
    int b = r / NG_, g = r % NG_;
    for (int c = threadIdx.x; c < D_; c += blockDim.x)
        xg[(size_t)r * D_ + c] = X[(size_t)(b * S_ + g) * D_ + c];
}

// ---------------- classifier heads ----------------
__global__ __launch_bounds__(256) void classifier_k(
    const float* __restrict__ x26, const float* __restrict__ cw,
    const float* __restrict__ cb, float* __restrict__ out) {
    __shared__ float red[256];
    int tid = threadIdx.x;
    for (int i = 0; i < 3; ++i) {
        for (int b = 0; b < B_; ++b) {
            const float* xr = x26 + (size_t)(b * NG_ + i) * D_;
            const float* wr = cw + (size_t)i * D_;
            float p = 0.f;
            for (int c = tid; c < D_; c += 256) p += xr[c] * wr[c];
            float dotv = block_sum(p, red);
            if (tid == 0) out[i * B_ + b] = 1.0f / (1.0f + __expf(-(dotv + cb[i])));
        }
    }
    if (tid == 0) { out[6] = 1.0f; out[7] = 1.0f; }
}

// ---------------- host launcher ----------------
extern "C" void kernel_launch(void* const* d_in, const int* in_sizes, int n_in,
                              void* d_out, int out_size, void* d_ws, size_t ws_size,
                              hipStream_t stream) {
    const int*   src      = (const int*)d_in[0];
    const float* word_emb = (const float*)d_in[3];
    const float* pos_emb  = (const float*)d_in[4];
    const float* emb_ln   = (const float*)d_in[5];
    const float* attn_w   = (const float*)d_in[6];
    const float* attn_b   = (const float*)d_in[7];
    const float* ln_p     = (const float*)d_in[8];
    const float* ffn_w1   = (const float*)d_in[9];
    const float* ffn_b1   = (const float*)d_in[10];
    const float* ffn_w2   = (const float*)d_in[11];
    const float* ffn_b2   = (const float*)d_in[12];
    const float* cls_w    = (const float*)d_in[13];
    const float* cls_b    = (const float*)d_in[14];
    float* out = (float*)d_out;

    const size_t NT = (size_t)B_ * S_ * D_;  // 6291456 (elements)
    float* base = (float*)d_ws;
    float* X  = base;
    float* P4 = base + NT;
    __hip_bfloat16* Xb = (__hip_bfloat16*)(base + 2 * NT);
    __hip_bfloat16* Qb = (__hip_bfloat16*)(base + 5 * NT / 2);
    __hip_bfloat16* Kb = (__hip_bfloat16*)(base + 3 * NT);
    __hip_bfloat16* Vb = (__hip_bfloat16*)(base + 7 * NT / 2);
    __hip_bfloat16* AOb = (__hip_bfloat16*)(base + 4 * NT);
    __hip_bfloat16* HCb = AOb;
    __hip_bfloat16* wq  = (__hip_bfloat16*)(base + 5 * NT);
    __hip_bfloat16* wk  = wq + 589824;
    __hip_bfloat16* wv  = wk + 589824;
    __hip_bfloat16* wg1 = wv + 589824;
    __hip_bfloat16* wg2 = wg1 + 589824;
    __hip_bfloat16* wo  = wg2 + 589824;
    __hip_bfloat16* wf1 = wo + 589824;
    __hip_bfloat16* wf2 = wf1 + 2359296;
    float* SM  = base + 5 * NT + 4128768;
    float* xg  = SM;
    float* qg6 = xg + 6 * D_;
    float* og6 = qg6 + 6 * D_;
    float* pr6 = og6 + 6 * D_;
    float* xa6 = pr6 + 6 * D_;
    float* h6  = xa6 + 6 * D_;
    float* f6  = h6 + 6 * FF_;
    float* x26 = f6 + 6 * D_;
    float* part = x26 + 6 * D_;  // split-K partials (max 48*6*768 = 221184 f32)
    float* gpart = part;         // aliased: never live at the same time (72*16*66 = 76032 f32)

    const int M = B_ * S_;
    dim3 blk(256);

    auto aw = [&](int l, int i) { return attn_w + ((size_t)(l * 7 + i)) * D_ * D_; };
    auto ab = [&](int l, int i) { return attn_b + (size_t)(l * 7 + i) * D_; };
    auto lnp = [&](int l, int i) { return ln_p + (size_t)(l * 4 + i) * D_; };

    auto skinny = [&](const float* A6, const float* Wm, const float* bias,
                      float* out6, int N, int K, int gelu) {
        skinny_gemm_k<<<dim3(N / 64, K / 64), blk, 0, stream>>>(A6, Wm, part, N, K);
        skinny_reduce_k<<<dim3((6 * N + 255) / 256), blk, 0, stream>>>(part, bias, out6, N, K / 64, gelu);
    };

    embed_ln_k<<<M, blk, 0, stream>>>(src, word_emb, pos_emb, emb_ln, emb_ln + D_, X, Xb);

    // ================= layer 0 =================
    convt_k<<<dim3(24, 24), blk, 0, stream>>>(aw(0, 0), wq, D_, D_);
    convt_k<<<dim3(24, 24), blk, 0, stream>>>(aw(0, 1), wk, D_, D_);
    convt_k<<<dim3(24, 24), blk, 0, stream>>>(aw(0, 2), wv, D_, D_);
    mfma_gemm_k<1><<<dim3(6, 64), blk, 0, stream>>>(Xb, wq, ab(0, 0), Qb, M, D_, D_);
    mfma_gemm_k<1><<<dim3(6, 64), blk, 0, stream>>>(Xb, wk, ab(0, 1), Kb, M, D_, D_);
    mfma_gemm_k<1><<<dim3(6, 64), blk, 0, stream>>>(Xb, wv, ab(0, 2), Vb, M, D_, D_);
    local_attn_k<<<dim3(NC_, H_, B_), blk, 0, stream>>>(Qb, Kb, Vb, AOb);
    convt_k<<<dim3(24, 24), blk, 0, stream>>>(aw(0, 4), wg1, D_, D_);
    convt_k<<<dim3(24, 24), blk, 0, stream>>>(aw(0, 5), wg2, D_, D_);
    mfma_gemm_k<1><<<dim3(6, 64), blk, 0, stream>>>(Xb, wg1, ab(0, 4), Qb, M, D_, D_);
    mfma_gemm_k<1><<<dim3(6, 64), blk, 0, stream>>>(Xb, wg2, ab(0, 5), Kb, M, D_, D_);
    gather6_k<<<B_ * NG_, blk, 0, stream>>>(X, xg);
    skinny(xg, aw(0, 3), ab(0, 3), qg6, D_, D_, 0);
    gattn_part_k<<<dim3(NSPLIT_, NG_ * H_, B_), blk, 0, stream>>>(qg6, Qb, Kb, gpart);
    gattn_comb_k<__hip_bfloat16><<<dim3(NG_, H_, B_), dim3(64), 0, stream>>>(gpart, AOb, S_);
    convt_k<<<dim3(24, 24), blk, 0, stream>>>(aw(0, 6), wo, D_, D_);
    mfma_gemm_k<0><<<dim3(6, 64), blk, 0, stream>>>(AOb, wo, ab(0, 6), P4, M, D_, D_);
    residual_ln_k<<<M, blk, 0, stream>>>(X, P4, lnp(0, 0), lnp(0, 1), P4, Xb);
    convt_k<<<dim3(96, 24), blk, 0, stream>>>(ffn_w1, wf1, D_, FF_);
    convt_k<<<dim3(24, 96), blk, 0, stream>>>(ffn_w2, wf2, FF_, D_);
    for (int ch = 0; ch < 2; ++ch) {
        mfma_gemm_k<2><<<dim3(24, 32), blk, 0, stream>>>(Xb + (size_t)ch * 4096 * D_, wf1, ffn_b1, HCb, 4096, FF_, D_);
        mfma_gemm_k<0><<<dim3(6, 32), blk, 0, stream>>>(HCb, wf2, ffn_b2, X + (size_t)ch * 4096 * D_, 4096, D_, FF_);
    }
    residual_ln_k<<<M, blk, 0, stream>>>(P4, X, lnp(0, 2), lnp(0, 3), X, Xb);

    // ================= layer 1 (pruned) =================
    convt_k<<<dim3(24, 24), blk, 0, stream>>>(aw(1, 4), wg1, D_, D_);
    convt_k<<<dim3(24, 24), blk, 0, stream>>>(aw(1, 5), wg2, D_, D_);
    mfma_gemm_k<1><<<dim3(6, 64), blk, 0, stream>>>(Xb, wg1, ab(1, 4), Qb, M, D_, D_);
    mfma_gemm_k<1><<<dim3(6, 64), blk, 0, stream>>>(Xb, wg2, ab(1, 5), Kb, M, D_, D_);
    gather6_k<<<B_ * NG_, blk, 0, stream>>>(X, xg);
    skinny(xg, aw(1, 3), ab(1, 3), qg6, D_, D_, 0);
    gattn_part_k<<<dim3(NSPLIT_, NG_ * H_, B_), blk, 0, stream>>>(qg6, Qb, Kb, gpart);
    gattn_comb_k<float><<<dim3(NG_, H_, B_), dim3(64), 0, stream>>>(gpart, og6, NG_);
    skinny(og6, aw(1, 6), ab(1, 6), pr6, D_, D_, 0);
    residual_ln_k<<<B_ * NG_, blk, 0, stream>>>(xg, pr6, lnp(1, 0), lnp(1, 1), xa6, nullptr);
    skinny(xa6, ffn_w1 + (size_t)D_ * FF_, ffn_b1 + FF_, h6, FF_, D_, 1);
    skinny(h6, ffn_w2 + (size_t)FF_ * D_, ffn_b2 + D_, f6, D_, FF_, 0);
    residual_ln_k<<<B_ * NG_, blk, 0, stream>>>(xa6, f6, lnp(1, 2), lnp(1, 3), x26, nullptr);
    classifier_k<<<1, blk, 0, stream>>>(x26, cls_w, cls_b, out);
}

// Round 8
// 631.172 us; speedup vs baseline: 18.8295x; 1.0067x over previous
//
#include <hip/hip_runtime.h>
#include <hip/hip_bf16.h>
#include <math.h>

// ---------------- constants (problem shapes) ----------------
#define B_    2
#define SSRC_ 4093
#define D_    768
#define H_    12
#define DH_   64
#define FF_   3072
#define NG_   3
#define W_    256
#define S_    4096
#define NC_   16
#define NSPLIT_ 16

typedef __attribute__((ext_vector_type(8))) short frag_ab;   // 8 bf16 (4 VGPRs)
typedef __attribute__((ext_vector_type(4))) float f32x4;     // 4 fp32 acc

// async global->LDS, 16B per lane (linear dest: base + lane*16)
#define GL16(gp, lp) __builtin_amdgcn_global_load_lds( \
    (const __attribute__((address_space(1))) void*)(gp), \
    (__attribute__((address_space(3))) void*)(lp), 16, 0, 0)

// ---------------- helpers ----------------
__device__ __forceinline__ float bflo(unsigned int w) {
    union { float f; unsigned int i; } c; c.i = w << 16; return c.f;
}
__device__ __forceinline__ float bfhi(unsigned int w) {
    union { float f; unsigned int i; } c; c.i = w & 0xffff0000u; return c.f;
}
__device__ __forceinline__ void unp8(uint4 t, float* o) {
    o[0] = bflo(t.x); o[1] = bfhi(t.x); o[2] = bflo(t.y); o[3] = bfhi(t.y);
    o[4] = bflo(t.z); o[5] = bfhi(t.z); o[6] = bflo(t.w); o[7] = bfhi(t.w);
}
__device__ __forceinline__ unsigned short f2bfu(float x) {
    __hip_bfloat16 h = __float2bfloat16(x);
    return *reinterpret_cast<unsigned short*>(&h);
}

__device__ __forceinline__ float block_sum(float v, float* red) {
    int tid = threadIdx.x;
    red[tid] = v;
    __syncthreads();
#pragma unroll
    for (int off = 128; off >= 1; off >>= 1) {
        if (tid < off) red[tid] += red[tid + off];
        __syncthreads();
    }
    float r = red[0];
    __syncthreads();
    return r;
}

__device__ __forceinline__ float block_max(float v, float* red) {
    int tid = threadIdx.x;
    red[tid] = v;
    __syncthreads();
#pragma unroll
    for (int off = 128; off >= 1; off >>= 1) {
        if (tid < off) red[tid] = fmaxf(red[tid], red[tid + off]);
        __syncthreads();
    }
    float r = red[0];
    __syncthreads();
    return r;
}

__device__ __forceinline__ void storeO(float* p, float v) { *p = v; }
__device__ __forceinline__ void storeO(__hip_bfloat16* p, float v) { *p = __float2bfloat16(v); }

// ---------------- embedding + LN (writes f32 X and bf16 Xb) ----------------
__global__ __launch_bounds__(256) void embed_ln_k(
    const int* __restrict__ src, const float* __restrict__ we,
    const float* __restrict__ pe, const float* __restrict__ gam,
    const float* __restrict__ bet, float* __restrict__ X,
    __hip_bfloat16* __restrict__ Xb) {
    __shared__ float red[256];
    int row = blockIdx.x;
    int b = row >> 12;
    int s = row & (S_ - 1);
    int tid = threadIdx.x;
    int id = (s < NG_) ? (50261 + s) : src[b * SSRC_ + (s - NG_)];
    const float* wr = we + (size_t)id * D_;
    const float* pr = pe + (size_t)s * D_;
    float v[3];
    float lsum = 0.f;
#pragma unroll
    for (int j = 0; j < 3; ++j) {
        int c = tid + j * 256;
        v[j] = wr[c] + pr[c];
        lsum += v[j];
    }
    float mu = block_sum(lsum, red) * (1.0f / 768.0f);
    float ls2 = 0.f;
#pragma unroll
    for (int j = 0; j < 3; ++j) { float d = v[j] - mu; ls2 += d * d; }
    float var = block_sum(ls2, red) * (1.0f / 768.0f);
    float rs = rsqrtf(var + 1e-5f);
    float* xr = X + (size_t)row * D_;
    __hip_bfloat16* xbr = Xb + (size_t)row * D_;
#pragma unroll
    for (int j = 0; j < 3; ++j) {
        int c = tid + j * 256;
        float o = (v[j] - mu) * rs * gam[c] + bet[c];
        xr[c] = o;
        xbr[c] = __float2bfloat16(o);
    }
}

// ---------------- residual + LN : out = LN(x + y), optional bf16 mirror ----------------
__global__ __launch_bounds__(256) void residual_ln_k(
    const float* __restrict__ x, const float* __restrict__ y,
    const float* __restrict__ gam, const float* __restrict__ bet,
    float* __restrict__ out, __hip_bfloat16* __restrict__ outb) {
    __shared__ float red[256];
    int row = blockIdx.x;
    int tid = threadIdx.x;
    const float* xr = x + (size_t)row * D_;
    const float* yr = y + (size_t)row * D_;
    float v[3];
    float lsum = 0.f;
#pragma unroll
    for (int j = 0; j < 3; ++j) {
        int c = tid + j * 256;
        v[j] = xr[c] + yr[c];
        lsum += v[j];
    }
    float mu = block_sum(lsum, red) * (1.0f / 768.0f);
    float ls2 = 0.f;
#pragma unroll
    for (int j = 0; j < 3; ++j) { float d = v[j] - mu; ls2 += d * d; }
    float var = block_sum(ls2, red) * (1.0f / 768.0f);
    float rs = rsqrtf(var + 1e-5f);
    float* orow = out + (size_t)row * D_;
    __hip_bfloat16* obr = outb ? outb + (size_t)row * D_ : nullptr;
#pragma unroll
    for (int j = 0; j < 3; ++j) {
        int c = tid + j * 256;
        float o = (v[j] - mu) * rs * gam[c] + bet[c];
        orow[c] = o;
        if (obr) obr[c] = __float2bfloat16(o);
    }
}

// ---------------- transpose-convert: nmat x (W[K,N] f32 -> WT[N,K] bf16) ----------------
__global__ __launch_bounds__(256) void convt_k(
    const float* __restrict__ W, __hip_bfloat16* __restrict__ WT,
    int K, int N, int npb /* = N/32 */) {
    __shared__ float tile[32][33];
    int mat = blockIdx.x / npb;
    int bx = blockIdx.x - mat * npb;
    int by = blockIdx.y;
    const float* Wm = W + (size_t)mat * K * N;
    __hip_bfloat16* WTm = WT + (size_t)mat * N * K;
    int tx = threadIdx.x & 31, ty = threadIdx.x >> 5;
#pragma unroll
    for (int i = 0; i < 32; i += 8)
        tile[ty + i][tx] = Wm[(size_t)(by * 32 + ty + i) * N + bx * 32 + tx];
    __syncthreads();
#pragma unroll
    for (int i = 0; i < 32; i += 8)
        WTm[(size_t)(bx * 32 + ty + i) * K + by * 32 + tx] = __float2bfloat16(tile[tx][ty + i]);
}

// ---------------- MFMA GEMM (global_load_lds staged, m97 structure) ----------------
// C[M,N] = A[M,K]bf16 @ BT[N,K]^T + bias
// EPI: 0 = f32 out, 1 = bf16 out, 2 = bf16 gelu(out)
// SPLIT: 1 => output column c goes to matrix c/768 (stride matstride elems), col c%768
template <int EPI, int SPLIT>
__global__ __launch_bounds__(256) void mfma_gemm_k(
    const __hip_bfloat16* __restrict__ A, const __hip_bfloat16* __restrict__ BT,
    const float* __restrict__ bias, void* __restrict__ Cout,
    int M, int N, int K, size_t matstride) {
    __shared__ __align__(16) __hip_bfloat16 As[4096];  // 128 rows x 32 k
    __shared__ __align__(16) __hip_bfloat16 Bs[4096];  // 128 cols x 32 k
    int tid = threadIdx.x;
    int lane = tid & 63;
    int w = tid >> 6, wr = w >> 1, wc = w & 1;
    int brow = blockIdx.y * 128, bcol = blockIdx.x * 128;
    int r0 = tid >> 2, k0 = (tid & 3) * 8;
    const __hip_bfloat16* Ag0 = A + (size_t)(brow + r0) * K + k0;
    const __hip_bfloat16* Ag1 = Ag0 + (size_t)64 * K;
    const __hip_bfloat16* Bg0 = BT + (size_t)(bcol + r0) * K + k0;
    const __hip_bfloat16* Bg1 = Bg0 + (size_t)64 * K;
    __hip_bfloat16* lA0 = &As[tid * 8];
    __hip_bfloat16* lA1 = &As[tid * 8 + 2048];
    __hip_bfloat16* lB0 = &Bs[tid * 8];
    __hip_bfloat16* lB1 = &Bs[tid * 8 + 2048];

    f32x4 acc[4][4];
#pragma unroll
    for (int m = 0; m < 4; ++m)
#pragma unroll
        for (int n = 0; n < 4; ++n) acc[m][n] = (f32x4){0.f, 0.f, 0.f, 0.f};

    int l15 = lane & 15, kb = lane >> 4;
    int aoff = (wr * 64 + l15) * 32 + kb * 8;
    int boff = (wc * 64 + l15) * 32 + kb * 8;

    for (int kt = 0; kt < K; kt += 32) {
        GL16(Ag0 + kt, lA0);
        GL16(Ag1 + kt, lA1);
        GL16(Bg0 + kt, lB0);
        GL16(Bg1 + kt, lB1);
        __syncthreads();   // drains vmcnt before barrier -> LDS tiles ready
        frag_ab af[4], bf[4];
#pragma unroll
        for (int m = 0; m < 4; ++m) af[m] = *(const frag_ab*)&As[aoff + m * 512];
#pragma unroll
        for (int n = 0; n < 4; ++n) bf[n] = *(const frag_ab*)&Bs[boff + n * 512];
#pragma unroll
        for (int m = 0; m < 4; ++m)
#pragma unroll
            for (int n = 0; n < 4; ++n)
                acc[m][n] = __builtin_amdgcn_mfma_f32_16x16x32_bf16(af[m], bf[n], acc[m][n], 0, 0, 0);
        __syncthreads();   // protect LDS from next iteration's loads
    }

#pragma unroll
    for (int m = 0; m < 4; ++m) {
        int rowb = brow + wr * 64 + m * 16 + (lane >> 4) * 4;
#pragma unroll
        for (int n = 0; n < 4; ++n) {
            int col = bcol + wc * 64 + n * 16 + l15;
            float bv = bias[col];
#pragma unroll
            for (int r = 0; r < 4; ++r) {
                float v = acc[m][n][r] + bv;
                size_t idx;
                if (SPLIT) {
                    int mat = col / 768;
                    idx = (size_t)mat * matstride + (size_t)(rowb + r) * 768 + (col - mat * 768);
                } else {
                    idx = (size_t)(rowb + r) * N + col;
                }
                if (EPI == 0) {
                    ((float*)Cout)[idx] = v;
                } else if (EPI == 1) {
                    ((__hip_bfloat16*)Cout)[idx] = __float2bfloat16(v);
                } else {
                    float g = 0.5f * v * (1.0f + erff(v * 0.70710678118654752f));
                    ((__hip_bfloat16*)Cout)[idx] = __float2bfloat16(g);
                }
            }
        }
    }
}

// ---------------- split-K skinny GEMM: M=6 rows ----------------
__global__ __launch_bounds__(256) void skinny_gemm_k(
    const float* __restrict__ A, const float* __restrict__ W,
    float* __restrict__ partial, int N, int K) {
    __shared__ float Asl[6][64];
    __shared__ float red[4][6][64];
    int tid = threadIdx.x;
    int cl = tid & 63;
    int kg = tid >> 6;
    int col = blockIdx.x * 64 + cl;
    int k0 = blockIdx.y * 64;
    for (int i = tid; i < 6 * 64; i += 256)
        Asl[i >> 6][i & 63] = A[(size_t)(i >> 6) * K + k0 + (i & 63)];
    __syncthreads();
    float acc[6] = {0.f, 0.f, 0.f, 0.f, 0.f, 0.f};
#pragma unroll
    for (int kk = 0; kk < 16; ++kk) {
        int k = kg * 16 + kk;
        float wv = W[(size_t)(k0 + k) * N + col];
#pragma unroll
        for (int m = 0; m < 6; ++m) acc[m] += Asl[m][k] * wv;
    }
#pragma unroll
    for (int m = 0; m < 6; ++m) red[kg][m][cl] = acc[m];
    __syncthreads();
    for (int i = tid; i < 6 * 64; i += 256) {
        int m = i >> 6, lane = i & 63;
        float s = red[0][m][lane] + red[1][m][lane] + red[2][m][lane] + red[3][m][lane];
        partial[(size_t)blockIdx.y * 6 * N + (size_t)m * N + blockIdx.x * 64 + lane] = s;
    }
}

__global__ __launch_bounds__(256) void skinny_reduce_k(
    const float* __restrict__ partial, const float* __restrict__ bias,
    float* __restrict__ outp, int N, int KS, int gelu) {
    int idx = blockIdx.x * 256 + threadIdx.x;
    if (idx >= 6 * N) return;
    int m = idx / N, col = idx - m * N;
    float s = bias[col];
    for (int kb = 0; kb < KS; ++kb)
        s += partial[(size_t)kb * 6 * N + (size_t)m * N + col];
    if (gelu) s = 0.5f * s * (1.0f + erff(s * 0.70710678118654752f));
    outp[(size_t)m * N + col] = s;
}

// ---------------- MFMA sliding-window local attention ----------------
__global__ __launch_bounds__(256, 1) void local_attn_k(
    const __hip_bfloat16* __restrict__ Q, const __hip_bfloat16* __restrict__ K,
    const __hip_bfloat16* __restrict__ V, __hip_bfloat16* __restrict__ O) {
    __shared__ __align__(16) __hip_bfloat16 K_lds[64 * 72];
    __shared__ __align__(16) __hip_bfloat16 VT_lds[64 * 72];
    __shared__ __align__(16) __hip_bfloat16 P_lds[4][16 * 72];

    const int c = blockIdx.x, h = blockIdx.y, b = blockIdx.z;
    const int tid = threadIdx.x;
    const int lane = tid & 63;
    const int w = tid >> 6;
    const int l15 = lane & 15, g4 = lane >> 4;
    const int cbase = c * W_;

    frag_ab qf[4][2];
#pragma unroll
    for (int qt = 0; qt < 4; ++qt) {
        int qa = cbase + w * 64 + qt * 16 + l15;
        const __hip_bfloat16* qp = Q + (size_t)(b * S_ + qa) * D_ + h * DH_ + g4 * 8;
        qf[qt][0] = *(const frag_ab*)qp;
        qf[qt][1] = *(const frag_ab*)(qp + 32);
    }

    f32x4 o[4][4];
#pragma unroll
    for (int qt = 0; qt < 4; ++qt)
#pragma unroll
        for (int dt = 0; dt < 4; ++dt) o[qt][dt] = (f32x4){0.f, 0.f, 0.f, 0.f};
    float mrun[4] = {-1e30f, -1e30f, -1e30f, -1e30f};
    float lrun[4] = {0.f, 0.f, 0.f, 0.f};

    int kw0 = cbase - W_; if (kw0 < 0) kw0 = 0;
    int kw1 = cbase + 2 * W_; if (kw1 > S_) kw1 = S_;
    int ntiles = (kw1 - kw0) >> 6;

    char* Pw = (char*)P_lds[w];

    for (int t = 0; t < ntiles; ++t) {
        int k0 = kw0 + t * 64;
        __syncthreads();
        {
            const __hip_bfloat16* Kg = K + (size_t)(b * S_ + k0) * D_ + h * DH_;
            const __hip_bfloat16* Vg = V + (size_t)(b * S_ + k0) * D_ + h * DH_;
#pragma unroll
            for (int it = 0; it < 2; ++it) {
                int idx = tid + it * 256;
                int kk = idx >> 3, d0 = (idx & 7) * 8;
                uint4 kv = *(const uint4*)(Kg + (size_t)kk * D_ + d0);
                *(uint4*)&K_lds[kk * 72 + d0] = kv;
                uint4 vv = *(const uint4*)(Vg + (size_t)kk * D_ + d0);
                unsigned short vs[8];
                *(uint4*)vs = vv;
#pragma unroll
                for (int j = 0; j < 8; ++j) {
                    int dd = d0 + j;
                    int boff = dd * 144 + ((kk * 2) ^ (((dd >> 3) & 7) << 4));
                    *(unsigned short*)((char*)VT_lds + boff) = vs[j];
                }
            }
        }
        __syncthreads();

        frag_ab kf[4][2];
#pragma unroll
        for (int kt = 0; kt < 4; ++kt) {
            const char* kp = (const char*)K_lds + (kt * 16 + l15) * 144 + g4 * 16;
            kf[kt][0] = *(const frag_ab*)kp;
            kf[kt][1] = *(const frag_ab*)(kp + 64);
        }
        frag_ab vf[4][2];
#pragma unroll
        for (int dt = 0; dt < 4; ++dt) {
            int drow = dt * 16 + l15;
            int swz = ((drow >> 3) & 7) << 4;
            const char* vp = (const char*)VT_lds + drow * 144;
            vf[dt][0] = *(const frag_ab*)(vp + ((g4 * 16) ^ swz));
            vf[dt][1] = *(const frag_ab*)(vp + ((g4 * 16 + 64) ^ swz));
        }

#pragma unroll
        for (int qt = 0; qt < 4; ++qt) {
            f32x4 st[4];
#pragma unroll
            for (int kt = 0; kt < 4; ++kt) {
                f32x4 z = (f32x4){0.f, 0.f, 0.f, 0.f};
                z = __builtin_amdgcn_mfma_f32_16x16x32_bf16(kf[kt][0], qf[qt][0], z, 0, 0, 0);
                z = __builtin_amdgcn_mfma_f32_16x16x32_bf16(kf[kt][1], qf[qt][1], z, 0, 0, 0);
                st[kt] = z;
            }
            int qa = cbase + w * 64 + qt * 16 + l15;
            float sv[16];
            float mx = -1e30f;
#pragma unroll
            for (int kt = 0; kt < 4; ++kt)
#pragma unroll
                for (int r = 0; r < 4; ++r) {
                    int ka = k0 + kt * 16 + g4 * 4 + r;
                    float s = st[kt][r] * 0.125f;
                    bool bad = (ka < NG_) | (ka - qa > W_) | (qa - ka > W_);
                    s = bad ? -1e30f : s;
                    sv[kt * 4 + r] = s;
                    mx = fmaxf(mx, s);
                }
            mx = fmaxf(mx, __shfl_xor(mx, 16));
            mx = fmaxf(mx, __shfl_xor(mx, 32));
            float mnew = fmaxf(fmaxf(mrun[qt], mx), -60.0f);
            float fsc = __expf(mrun[qt] - mnew);
            mrun[qt] = mnew;
#pragma unroll
            for (int dt = 0; dt < 4; ++dt) o[qt][dt] *= fsc;
            float psum = 0.f;
            unsigned short pb[16];
#pragma unroll
            for (int i = 0; i < 16; ++i) {
                float p = __expf(sv[i] - mnew);
                psum += p;
                pb[i] = f2bfu(p);
            }
            psum += __shfl_xor(psum, 16);
            psum += __shfl_xor(psum, 32);
            lrun[qt] = lrun[qt] * fsc + psum;
#pragma unroll
            for (int kt = 0; kt < 4; ++kt)
#pragma unroll
                for (int rp = 0; rp < 2; ++rp) {
                    unsigned vpk = (unsigned)pb[kt * 4 + rp * 2] | ((unsigned)pb[kt * 4 + rp * 2 + 1] << 16);
                    int kloc = kt * 16 + g4 * 4 + rp * 2;
                    *(unsigned*)(Pw + l15 * 144 + kloc * 2) = vpk;
                }
            frag_ab pf0 = *(const frag_ab*)(Pw + l15 * 144 + g4 * 16);
            frag_ab pf1 = *(const frag_ab*)(Pw + l15 * 144 + g4 * 16 + 64);
#pragma unroll
            for (int dt = 0; dt < 4; ++dt) {
                o[qt][dt] = __builtin_amdgcn_mfma_f32_16x16x32_bf16(vf[dt][0], pf0, o[qt][dt], 0, 0, 0);
                o[qt][dt] = __builtin_amdgcn_mfma_f32_16x16x32_bf16(vf[dt][1], pf1, o[qt][dt], 0, 0, 0);
            }
        }
    }

    // ---- 3 global keys (unmasked), scalar epilogue ----
    uint4 kgc[3][2];
    uint2 vgd[3][4];
#pragma unroll
    for (int gk = 0; gk < NG_; ++gk) {
        const __hip_bfloat16* kp = K + (size_t)(b * S_ + gk) * D_ + h * DH_ + g4 * 8;
        kgc[gk][0] = *(const uint4*)kp;
        kgc[gk][1] = *(const uint4*)(kp + 32);
        const __hip_bfloat16* vp = V + (size_t)(b * S_ + gk) * D_ + h * DH_ + g4 * 4;
#pragma unroll
        for (int dt = 0; dt < 4; ++dt)
            vgd[gk][dt] = *(const uint2*)(vp + dt * 16);
    }
#pragma unroll
    for (int qt = 0; qt < 4; ++qt) {
        float sg[3];
#pragma unroll
        for (int gk = 0; gk < NG_; ++gk) {
            float part = 0.f;
#pragma unroll
            for (int s = 0; s < 2; ++s) {
                uint4 qw = *(uint4*)&qf[qt][s];
                uint4 kw = kgc[gk][s];
                part += bflo(qw.x) * bflo(kw.x) + bfhi(qw.x) * bfhi(kw.x);
                part += bflo(qw.y) * bflo(kw.y) + bfhi(qw.y) * bfhi(kw.y);
                part += bflo(qw.z) * bflo(kw.z) + bfhi(qw.z) * bfhi(kw.z);
                part += bflo(qw.w) * bflo(kw.w) + bfhi(qw.w) * bfhi(kw.w);
            }
            part += __shfl_xor(part, 16);
            part += __shfl_xor(part, 32);
            sg[gk] = part * 0.125f;
        }
        float mx3 = fmaxf(fmaxf(sg[0], sg[1]), sg[2]);
        float mnew = fmaxf(fmaxf(mrun[qt], mx3), -60.0f);
        float fsc = __expf(mrun[qt] - mnew);
        mrun[qt] = mnew;
#pragma unroll
        for (int dt = 0; dt < 4; ++dt) o[qt][dt] *= fsc;
        float pg[3];
        float psum = 0.f;
#pragma unroll
        for (int gk = 0; gk < NG_; ++gk) { pg[gk] = __expf(sg[gk] - mnew); psum += pg[gk]; }
        lrun[qt] = lrun[qt] * fsc + psum;
#pragma unroll
        for (int dt = 0; dt < 4; ++dt) {
#pragma unroll
            for (int gk = 0; gk < NG_; ++gk) {
                uint2 vv = vgd[gk][dt];
                o[qt][dt][0] += pg[gk] * bflo(vv.x);
                o[qt][dt][1] += pg[gk] * bfhi(vv.x);
                o[qt][dt][2] += pg[gk] * bflo(vv.y);
                o[qt][dt][3] += pg[gk] * bfhi(vv.y);
            }
        }
    }

#pragma unroll
    for (int qt = 0; qt < 4; ++qt) {
        float linv = 1.0f / lrun[qt];
        int qa = cbase + w * 64 + qt * 16 + l15;
        __hip_bfloat16* orow = O + (size_t)(b * S_ + qa) * D_ + h * DH_;
#pragma unroll
        for (int dt = 0; dt < 4; ++dt) {
            unsigned short pk[4];
#pragma unroll
            for (int r = 0; r < 4; ++r) pk[r] = f2bfu(o[qt][dt][r] * linv);
            *(uint2*)(orow + dt * 16 + g4 * 4) = *(uint2*)pk;
        }
    }
}

// ---------------- global attention, split-S flash decode ----------------
__global__ __launch_bounds__(256) void gattn_part_k(
    const float* __restrict__ qg, const __hip_bfloat16* __restrict__ KG,
    const __hip_bfloat16* __restrict__ VG, float* __restrict__ gpart) {
    __shared__ float sc[256];
    __shared__ float qs[DH_];
    __shared__ float red[256];
    __shared__ float rv[16][64];
    int split = blockIdx.x;
    int gh = blockIdx.y;
    int g = gh / H_, h = gh - g * H_;
    int b = blockIdx.z;
    int tid = threadIdx.x;
    if (tid < DH_) qs[tid] = qg[(size_t)(b * NG_ + g) * D_ + h * DH_ + tid] * 0.125f;
    __syncthreads();
    int s0 = split * (S_ / NSPLIT_);
    float acc = 0.f;
    {
        const __hip_bfloat16* kp = KG + (size_t)(b * S_ + s0 + tid) * D_ + h * DH_;
#pragma unroll
        for (int c8 = 0; c8 < 8; ++c8) {
            uint4 t = *(const uint4*)(kp + c8 * 8);
            float f[8]; unp8(t, f);
#pragma unroll
            for (int j = 0; j < 8; ++j) acc += qs[c8 * 8 + j] * f[j];
        }
    }
    float m = block_max(acc, red);
    float e = __expf(acc - m);
    sc[tid] = e;
    float l = block_sum(e, red);
    int sgq = tid >> 4, dq = (tid & 15) * 4;
    float a0 = 0.f, a1 = 0.f, a2 = 0.f, a3 = 0.f;
    const __hip_bfloat16* vbase = VG + (size_t)(b * S_ + s0 + sgq * 16) * D_ + h * DH_ + dq;
#pragma unroll
    for (int i = 0; i < 16; ++i) {
        float p = sc[sgq * 16 + i];
        uint2 vv = *(const uint2*)(vbase + (size_t)i * D_);
        a0 += p * bflo(vv.x); a1 += p * bfhi(vv.x);
        a2 += p * bflo(vv.y); a3 += p * bfhi(vv.y);
    }
    rv[sgq][dq] = a0; rv[sgq][dq + 1] = a1; rv[sgq][dq + 2] = a2; rv[sgq][dq + 3] = a3;
    __syncthreads();
    float* op = gpart + ((size_t)((b * NG_ + g) * H_ + h) * NSPLIT_ + split) * 66;
    if (tid == 0) { op[0] = m; op[1] = l; }
    if (tid < DH_) {
        float s = 0.f;
#pragma unroll
        for (int j = 0; j < 16; ++j) s += rv[j][tid];
        op[2 + tid] = s;
    }
}

template <typename TO>
__global__ __launch_bounds__(64) void gattn_comb_k(
    const float* __restrict__ gpart, TO* __restrict__ outp, int rowStride) {
    int g = blockIdx.x, h = blockIdx.y, b = blockIdx.z;
    int tid = threadIdx.x;
    const float* base = gpart + (size_t)((b * NG_ + g) * H_ + h) * NSPLIT_ * 66;
    float M = -1e30f;
#pragma unroll
    for (int p = 0; p < NSPLIT_; ++p) M = fmaxf(M, base[p * 66]);
    float l = 0.f, o = 0.f;
#pragma unroll
    for (int p = 0; p < NSPLIT_; ++p) {
        float wgt = __expf(base[p * 66] - M);
        l += wgt * base[p * 66 + 1];
        o += wgt * base[p * 66 + 2 + tid];
    }
    storeO(&outp[(size_t)(b * rowStride + g) * D_ + h * DH_ + tid], o / l);
}

// ---------------- gather the 6 global-token rows ----------------
__global__ void gather6_k(const float* __restrict__ X, float* __restrict__ xg) {
    int r = blockIdx.x;
    int b = r / NG_, g = r % NG_;
    for (int c = threadIdx.x; c < D_; c += blockDim.x)
        xg[(size_t)r * D_ + c] = X[(size_t)(b * S_ + g) * D_ + c];
}

// ---------------- classifier heads ----------------
__global__ __launch_bounds__(256) void classifier_k(
    const float* __restrict__ x26, const float* __restrict__ cw,
    const float* __restrict__ cb, float* __restrict__ out) {
    __shared__ float red[256];
    int tid = threadIdx.x;
    for (int i = 0; i < 3; ++i) {
        for (int b = 0; b < B_; ++b) {
            const float* xr = x26 + (size_t)(b * NG_ + i) * D_;
            const float* wr = cw + (size_t)i * D_;
            float p = 0.f;
            for (int c = tid; c < D_; c += 256) p += xr[c] * wr[c];
            float dotv = block_sum(p, red);
            if (tid == 0) out[i * B_ + b] = 1.0f / (1.0f + __expf(-(dotv + cb[i])));
        }
    }
    if (tid == 0) { out[6] = 1.0f; out[7] = 1.0f; }
}

// ---------------- host launcher ----------------
extern "C" void kernel_launch(void* const* d_in, const int* in_sizes, int n_in,
                              void* d_out, int out_size, void* d_ws, size_t ws_size,
                              hipStream_t stream) {
    const int*   src      = (const int*)d_in[0];
    const float* word_emb = (const float*)d_in[3];
    const float* pos_emb  = (const float*)d_in[4];
    const float* emb_ln   = (const float*)d_in[5];
    const float* attn_w   = (const float*)d_in[6];
    const float* attn_b   = (const float*)d_in[7];
    const float* ln_p     = (const float*)d_in[8];
    const float* ffn_w1   = (const float*)d_in[9];
    const float* ffn_b1   = (const float*)d_in[10];
    const float* ffn_w2   = (const float*)d_in[11];
    const float* ffn_b2   = (const float*)d_in[12];
    const float* cls_w    = (const float*)d_in[13];
    const float* cls_b    = (const float*)d_in[14];
    float* out = (float*)d_out;

    const size_t NT = (size_t)B_ * S_ * D_;  // 6291456 (elements)
    float* base = (float*)d_ws;
    float* X  = base;
    float* P4 = base + NT;
    __hip_bfloat16* Xb = (__hip_bfloat16*)(base + 2 * NT);
    __hip_bfloat16* Qb = (__hip_bfloat16*)(base + 5 * NT / 2);  // Qb,Kb,Vb contiguous (NT apart)
    __hip_bfloat16* Kb = (__hip_bfloat16*)(base + 3 * NT);
    __hip_bfloat16* Vb = (__hip_bfloat16*)(base + 7 * NT / 2);
    __hip_bfloat16* AOb = (__hip_bfloat16*)(base + 4 * NT);
    __hip_bfloat16* HCb = AOb;
    __hip_bfloat16* wq  = (__hip_bfloat16*)(base + 5 * NT);  // wq,wk,wv contiguous
    __hip_bfloat16* wg1 = wq + 3 * 589824;                   // wg1,wg2 contiguous
    __hip_bfloat16* wo  = wg1 + 2 * 589824;
    __hip_bfloat16* wf1 = wo + 589824;
    __hip_bfloat16* wf2 = wf1 + 2359296;
    float* SM  = base + 5 * NT + 4128768;
    float* xg  = SM;
    float* qg6 = xg + 6 * D_;
    float* og6 = qg6 + 6 * D_;
    float* pr6 = og6 + 6 * D_;
    float* xa6 = pr6 + 6 * D_;
    float* h6  = xa6 + 6 * D_;
    float* f6  = h6 + 6 * FF_;
    float* x26 = f6 + 6 * D_;
    float* part = x26 + 6 * D_;
    float* gpart = part;

    const int M = B_ * S_;
    dim3 blk(256);

    auto aw = [&](int l, int i) { return attn_w + ((size_t)(l * 7 + i)) * D_ * D_; };
    auto ab = [&](int l, int i) { return attn_b + (size_t)(l * 7 + i) * D_; };
    auto lnp = [&](int l, int i) { return ln_p + (size_t)(l * 4 + i) * D_; };

    auto skinny = [&](const float* A6, const float* Wm, const float* bias,
                      float* out6, int N, int K, int gelu) {
        skinny_gemm_k<<<dim3(N / 64, K / 64), blk, 0, stream>>>(A6, Wm, part, N, K);
        skinny_reduce_k<<<dim3((6 * N + 255) / 256), blk, 0, stream>>>(part, bias, out6, N, K / 64, gelu);
    };

    embed_ln_k<<<M, blk, 0, stream>>>(src, word_emb, pos_emb, emb_ln, emb_ln + D_, X, Xb);

    // ================= layer 0 =================
    // fused QKV: weights aw(0,0..2) contiguous -> wq; outputs Qb,Kb,Vb contiguous
    convt_k<<<dim3(24 * 3, 24), blk, 0, stream>>>(aw(0, 0), wq, D_, D_, 24);
    mfma_gemm_k<1, 1><<<dim3(2304 / 128, 64), blk, 0, stream>>>(Xb, wq, ab(0, 0), Qb, M, 2304, D_, NT);
    local_attn_k<<<dim3(NC_, H_, B_), blk, 0, stream>>>(Qb, Kb, Vb, AOb);
    // fused global K/V projections: aw(0,4..5) -> wg1; outputs Qb(KG),Kb(VG)
    convt_k<<<dim3(24 * 2, 24), blk, 0, stream>>>(aw(0, 4), wg1, D_, D_, 24);
    mfma_gemm_k<1, 1><<<dim3(1536 / 128, 64), blk, 0, stream>>>(Xb, wg1, ab(0, 4), Qb, M, 1536, D_, NT);
    gather6_k<<<B_ * NG_, blk, 0, stream>>>(X, xg);
    skinny(xg, aw(0, 3), ab(0, 3), qg6, D_, D_, 0);
    gattn_part_k<<<dim3(NSPLIT_, NG_ * H_, B_), blk, 0, stream>>>(qg6, Qb, Kb, gpart);
    gattn_comb_k<__hip_bfloat16><<<dim3(NG_, H_, B_), dim3(64), 0, stream>>>(gpart, AOb, S_);
    convt_k<<<dim3(24, 24), blk, 0, stream>>>(aw(0, 6), wo, D_, D_, 24);
    mfma_gemm_k<0, 0><<<dim3(6, 64), blk, 0, stream>>>(AOb, wo, ab(0, 6), P4, M, D_, D_, 0);
    residual_ln_k<<<M, blk, 0, stream>>>(X, P4, lnp(0, 0), lnp(0, 1), P4, Xb);
    convt_k<<<dim3(96, 24), blk, 0, stream>>>(ffn_w1, wf1, D_, FF_, 96);
    convt_k<<<dim3(24, 96), blk, 0, stream>>>(ffn_w2, wf2, FF_, D_, 24);
    for (int ch = 0; ch < 2; ++ch) {
        mfma_gemm_k<2, 0><<<dim3(24, 32), blk, 0, stream>>>(Xb + (size_t)ch * 4096 * D_, wf1, ffn_b1, HCb, 4096, FF_, D_, 0);
        mfma_gemm_k<0, 0><<<dim3(6, 32), blk, 0, stream>>>(HCb, wf2, ffn_b2, X + (size_t)ch * 4096 * D_, 4096, D_, FF_, 0);
    }
    residual_ln_k<<<M, blk, 0, stream>>>(P4, X, lnp(0, 2), lnp(0, 3), X, Xb);

    // ================= layer 1 (pruned) =================
    convt_k<<<dim3(24 * 2, 24), blk, 0, stream>>>(aw(1, 4), wg1, D_, D_, 24);
    mfma_gemm_k<1, 1><<<dim3(1536 / 128, 64), blk, 0, stream>>>(Xb, wg1, ab(1, 4), Qb, M, 1536, D_, NT);
    gather6_k<<<B_ * NG_, blk, 0, stream>>>(X, xg);
    skinny(xg, aw(1, 3), ab(1, 3), qg6, D_, D_, 0);
    gattn_part_k<<<dim3(NSPLIT_, NG_ * H_, B_), blk, 0, stream>>>(qg6, Qb, Kb, gpart);
    gattn_comb_k<float><<<dim3(NG_, H_, B_), dim3(64), 0, stream>>>(gpart, og6, NG_);
    skinny(og6, aw(1, 6), ab(1, 6), pr6, D_, D_, 0);
    residual_ln_k<<<B_ * NG_, blk, 0, stream>>>(xg, pr6, lnp(1, 0), lnp(1, 1), xa6, nullptr);
    skinny(xa6, ffn_w1 + (size_t)D_ * FF_, ffn_b1 + FF_, h6, FF_, D_, 1);
    skinny(h6, ffn_w2 + (size_t)FF_ * D_, ffn_b2 + D_, f6, D_, FF_, 0);
    residual_ln_k<<<B_ * NG_, blk, 0, stream>>>(xa6, f6, lnp(1, 2), lnp(1, 3), x26, nullptr);
    classifier_k<<<1, blk, 0, stream>>>(x26, cls_w, cls_b, out);
}

// Round 9
// 569.043 us; speedup vs baseline: 20.8853x; 1.1092x over previous
//
#include <hip/hip_runtime.h>
#include <hip/hip_bf16.h>
#include <math.h>

// ---------------- constants (problem shapes) ----------------
#define B_    2
#define SSRC_ 4093
#define D_    768
#define H_    12
#define DH_   64
#define FF_   3072
#define NG_   3
#define W_    256
#define S_    4096
#define NC_   16
#define NSPLIT_ 16
#define QB_   128   // queries per local-attn block (was 256)

typedef __attribute__((ext_vector_type(8))) short frag_ab;   // 8 bf16 (4 VGPRs)
typedef __attribute__((ext_vector_type(4))) float f32x4;     // 4 fp32 acc

// async global->LDS, 16B per lane (linear dest: base + lane*16)
#define GL16(gp, lp) __builtin_amdgcn_global_load_lds( \
    (const __attribute__((address_space(1))) void*)(gp), \
    (__attribute__((address_space(3))) void*)(lp), 16, 0, 0)

// ---------------- helpers ----------------
__device__ __forceinline__ float bflo(unsigned int w) {
    union { float f; unsigned int i; } c; c.i = w << 16; return c.f;
}
__device__ __forceinline__ float bfhi(unsigned int w) {
    union { float f; unsigned int i; } c; c.i = w & 0xffff0000u; return c.f;
}
__device__ __forceinline__ void unp8(uint4 t, float* o) {
    o[0] = bflo(t.x); o[1] = bfhi(t.x); o[2] = bflo(t.y); o[3] = bfhi(t.y);
    o[4] = bflo(t.z); o[5] = bfhi(t.z); o[6] = bflo(t.w); o[7] = bfhi(t.w);
}
__device__ __forceinline__ unsigned short f2bfu(float x) {
    __hip_bfloat16 h = __float2bfloat16(x);
    return *reinterpret_cast<unsigned short*>(&h);
}

__device__ __forceinline__ float block_sum(float v, float* red) {
    int tid = threadIdx.x;
    red[tid] = v;
    __syncthreads();
#pragma unroll
    for (int off = 128; off >= 1; off >>= 1) {
        if (tid < off) red[tid] += red[tid + off];
        __syncthreads();
    }
    float r = red[0];
    __syncthreads();
    return r;
}

__device__ __forceinline__ float block_max(float v, float* red) {
    int tid = threadIdx.x;
    red[tid] = v;
    __syncthreads();
#pragma unroll
    for (int off = 128; off >= 1; off >>= 1) {
        if (tid < off) red[tid] = fmaxf(red[tid], red[tid + off]);
        __syncthreads();
    }
    float r = red[0];
    __syncthreads();
    return r;
}

__device__ __forceinline__ void storeO(float* p, float v) { *p = v; }
__device__ __forceinline__ void storeO(__hip_bfloat16* p, float v) { *p = __float2bfloat16(v); }

// ---------------- embedding + LN (writes f32 X and bf16 Xb) ----------------
__global__ __launch_bounds__(256) void embed_ln_k(
    const int* __restrict__ src, const float* __restrict__ we,
    const float* __restrict__ pe, const float* __restrict__ gam,
    const float* __restrict__ bet, float* __restrict__ X,
    __hip_bfloat16* __restrict__ Xb) {
    __shared__ float red[256];
    int row = blockIdx.x;
    int b = row >> 12;
    int s = row & (S_ - 1);
    int tid = threadIdx.x;
    int id = (s < NG_) ? (50261 + s) : src[b * SSRC_ + (s - NG_)];
    const float* wr = we + (size_t)id * D_;
    const float* pr = pe + (size_t)s * D_;
    float v[3];
    float lsum = 0.f;
#pragma unroll
    for (int j = 0; j < 3; ++j) {
        int c = tid + j * 256;
        v[j] = wr[c] + pr[c];
        lsum += v[j];
    }
    float mu = block_sum(lsum, red) * (1.0f / 768.0f);
    float ls2 = 0.f;
#pragma unroll
    for (int j = 0; j < 3; ++j) { float d = v[j] - mu; ls2 += d * d; }
    float var = block_sum(ls2, red) * (1.0f / 768.0f);
    float rs = rsqrtf(var + 1e-5f);
    float* xr = X + (size_t)row * D_;
    __hip_bfloat16* xbr = Xb + (size_t)row * D_;
#pragma unroll
    for (int j = 0; j < 3; ++j) {
        int c = tid + j * 256;
        float o = (v[j] - mu) * rs * gam[c] + bet[c];
        xr[c] = o;
        xbr[c] = __float2bfloat16(o);
    }
}

// ---------------- residual + LN : out = LN(x + y), optional bf16 mirror ----------------
__global__ __launch_bounds__(256) void residual_ln_k(
    const float* __restrict__ x, const float* __restrict__ y,
    const float* __restrict__ gam, const float* __restrict__ bet,
    float* __restrict__ out, __hip_bfloat16* __restrict__ outb) {
    __shared__ float red[256];
    int row = blockIdx.x;
    int tid = threadIdx.x;
    const float* xr = x + (size_t)row * D_;
    const float* yr = y + (size_t)row * D_;
    float v[3];
    float lsum = 0.f;
#pragma unroll
    for (int j = 0; j < 3; ++j) {
        int c = tid + j * 256;
        v[j] = xr[c] + yr[c];
        lsum += v[j];
    }
    float mu = block_sum(lsum, red) * (1.0f / 768.0f);
    float ls2 = 0.f;
#pragma unroll
    for (int j = 0; j < 3; ++j) { float d = v[j] - mu; ls2 += d * d; }
    float var = block_sum(ls2, red) * (1.0f / 768.0f);
    float rs = rsqrtf(var + 1e-5f);
    float* orow = out + (size_t)row * D_;
    __hip_bfloat16* obr = outb ? outb + (size_t)row * D_ : nullptr;
#pragma unroll
    for (int j = 0; j < 3; ++j) {
        int c = tid + j * 256;
        float o = (v[j] - mu) * rs * gam[c] + bet[c];
        orow[c] = o;
        if (obr) obr[c] = __float2bfloat16(o);
    }
}

// ---------------- transpose-convert: nmat x (W[K,N] f32 -> WT[N,K] bf16) ----------------
__global__ __launch_bounds__(256) void convt_k(
    const float* __restrict__ W, __hip_bfloat16* __restrict__ WT,
    int K, int N, int npb /* = N/32 */) {
    __shared__ float tile[32][33];
    int mat = blockIdx.x / npb;
    int bx = blockIdx.x - mat * npb;
    int by = blockIdx.y;
    const float* Wm = W + (size_t)mat * K * N;
    __hip_bfloat16* WTm = WT + (size_t)mat * N * K;
    int tx = threadIdx.x & 31, ty = threadIdx.x >> 5;
#pragma unroll
    for (int i = 0; i < 32; i += 8)
        tile[ty + i][tx] = Wm[(size_t)(by * 32 + ty + i) * N + bx * 32 + tx];
    __syncthreads();
#pragma unroll
    for (int i = 0; i < 32; i += 8)
        WTm[(size_t)(bx * 32 + ty + i) * K + by * 32 + tx] = __float2bfloat16(tile[tx][ty + i]);
}

// ---------------- MFMA GEMM (global_load_lds staged, m97 structure) ----------------
template <int EPI, int SPLIT>
__global__ __launch_bounds__(256) void mfma_gemm_k(
    const __hip_bfloat16* __restrict__ A, const __hip_bfloat16* __restrict__ BT,
    const float* __restrict__ bias, void* __restrict__ Cout,
    int M, int N, int K, size_t matstride) {
    __shared__ __align__(16) __hip_bfloat16 As[4096];
    __shared__ __align__(16) __hip_bfloat16 Bs[4096];
    int tid = threadIdx.x;
    int lane = tid & 63;
    int w = tid >> 6, wr = w >> 1, wc = w & 1;
    int brow = blockIdx.y * 128, bcol = blockIdx.x * 128;
    int r0 = tid >> 2, k0 = (tid & 3) * 8;
    const __hip_bfloat16* Ag0 = A + (size_t)(brow + r0) * K + k0;
    const __hip_bfloat16* Ag1 = Ag0 + (size_t)64 * K;
    const __hip_bfloat16* Bg0 = BT + (size_t)(bcol + r0) * K + k0;
    const __hip_bfloat16* Bg1 = Bg0 + (size_t)64 * K;
    __hip_bfloat16* lA0 = &As[tid * 8];
    __hip_bfloat16* lA1 = &As[tid * 8 + 2048];
    __hip_bfloat16* lB0 = &Bs[tid * 8];
    __hip_bfloat16* lB1 = &Bs[tid * 8 + 2048];

    f32x4 acc[4][4];
#pragma unroll
    for (int m = 0; m < 4; ++m)
#pragma unroll
        for (int n = 0; n < 4; ++n) acc[m][n] = (f32x4){0.f, 0.f, 0.f, 0.f};

    int l15 = lane & 15, kb = lane >> 4;
    int aoff = (wr * 64 + l15) * 32 + kb * 8;
    int boff = (wc * 64 + l15) * 32 + kb * 8;

    for (int kt = 0; kt < K; kt += 32) {
        GL16(Ag0 + kt, lA0);
        GL16(Ag1 + kt, lA1);
        GL16(Bg0 + kt, lB0);
        GL16(Bg1 + kt, lB1);
        __syncthreads();
        frag_ab af[4], bf[4];
#pragma unroll
        for (int m = 0; m < 4; ++m) af[m] = *(const frag_ab*)&As[aoff + m * 512];
#pragma unroll
        for (int n = 0; n < 4; ++n) bf[n] = *(const frag_ab*)&Bs[boff + n * 512];
        __builtin_amdgcn_s_setprio(1);
#pragma unroll
        for (int m = 0; m < 4; ++m)
#pragma unroll
            for (int n = 0; n < 4; ++n)
                acc[m][n] = __builtin_amdgcn_mfma_f32_16x16x32_bf16(af[m], bf[n], acc[m][n], 0, 0, 0);
        __builtin_amdgcn_s_setprio(0);
        __syncthreads();
    }

#pragma unroll
    for (int m = 0; m < 4; ++m) {
        int rowb = brow + wr * 64 + m * 16 + (lane >> 4) * 4;
#pragma unroll
        for (int n = 0; n < 4; ++n) {
            int col = bcol + wc * 64 + n * 16 + l15;
            float bv = bias[col];
#pragma unroll
            for (int r = 0; r < 4; ++r) {
                float v = acc[m][n][r] + bv;
                size_t idx;
                if (SPLIT) {
                    int mat = col / 768;
                    idx = (size_t)mat * matstride + (size_t)(rowb + r) * 768 + (col - mat * 768);
                } else {
                    idx = (size_t)(rowb + r) * N + col;
                }
                if (EPI == 0) {
                    ((float*)Cout)[idx] = v;
                } else if (EPI == 1) {
                    ((__hip_bfloat16*)Cout)[idx] = __float2bfloat16(v);
                } else {
                    float g = 0.5f * v * (1.0f + erff(v * 0.70710678118654752f));
                    ((__hip_bfloat16*)Cout)[idx] = __float2bfloat16(g);
                }
            }
        }
    }
}

// ---------------- split-K skinny GEMM: M=6 rows ----------------
__global__ __launch_bounds__(256) void skinny_gemm_k(
    const float* __restrict__ A, const float* __restrict__ W,
    float* __restrict__ partial, int N, int K) {
    __shared__ float Asl[6][64];
    __shared__ float red[4][6][64];
    int tid = threadIdx.x;
    int cl = tid & 63;
    int kg = tid >> 6;
    int col = blockIdx.x * 64 + cl;
    int k0 = blockIdx.y * 64;
    for (int i = tid; i < 6 * 64; i += 256)
        Asl[i >> 6][i & 63] = A[(size_t)(i >> 6) * K + k0 + (i & 63)];
    __syncthreads();
    float acc[6] = {0.f, 0.f, 0.f, 0.f, 0.f, 0.f};
#pragma unroll
    for (int kk = 0; kk < 16; ++kk) {
        int k = kg * 16 + kk;
        float wv = W[(size_t)(k0 + k) * N + col];
#pragma unroll
        for (int m = 0; m < 6; ++m) acc[m] += Asl[m][k] * wv;
    }
#pragma unroll
    for (int m = 0; m < 6; ++m) red[kg][m][cl] = acc[m];
    __syncthreads();
    for (int i = tid; i < 6 * 64; i += 256) {
        int m = i >> 6, lane = i & 63;
        float s = red[0][m][lane] + red[1][m][lane] + red[2][m][lane] + red[3][m][lane];
        partial[(size_t)blockIdx.y * 6 * N + (size_t)m * N + blockIdx.x * 64 + lane] = s;
    }
}

__global__ __launch_bounds__(256) void skinny_reduce_k(
    const float* __restrict__ partial, const float* __restrict__ bias,
    float* __restrict__ outp, int N, int KS, int gelu) {
    int idx = blockIdx.x * 256 + threadIdx.x;
    if (idx >= 6 * N) return;
    int m = idx / N, col = idx - m * N;
    float s = bias[col];
    for (int kb = 0; kb < KS; ++kb)
        s += partial[(size_t)kb * 6 * N + (size_t)m * N + col];
    if (gelu) s = 0.5f * s * (1.0f + erff(s * 0.70710678118654752f));
    outp[(size_t)m * N + col] = s;
}

// ---------------- MFMA sliding-window local attention (128-query blocks) ----------------
// grid (S/QB, H, B), 256 threads = 4 waves x 32 queries each.
__global__ __launch_bounds__(256, 1) void local_attn_k(
    const __hip_bfloat16* __restrict__ Q, const __hip_bfloat16* __restrict__ K,
    const __hip_bfloat16* __restrict__ V, __hip_bfloat16* __restrict__ O) {
    __shared__ __align__(16) __hip_bfloat16 K_lds[64 * 72];
    __shared__ __align__(16) __hip_bfloat16 VT_lds[64 * 72];
    __shared__ __align__(16) __hip_bfloat16 P_lds[4][16 * 72];

    const int cq = blockIdx.x, h = blockIdx.y, b = blockIdx.z;
    const int tid = threadIdx.x;
    const int lane = tid & 63;
    const int w = tid >> 6;
    const int l15 = lane & 15, g4 = lane >> 4;
    const int cbase = cq * QB_;

    frag_ab qf[2][2];
#pragma unroll
    for (int qt = 0; qt < 2; ++qt) {
        int qa = cbase + w * 32 + qt * 16 + l15;
        const __hip_bfloat16* qp = Q + (size_t)(b * S_ + qa) * D_ + h * DH_ + g4 * 8;
        qf[qt][0] = *(const frag_ab*)qp;
        qf[qt][1] = *(const frag_ab*)(qp + 32);
    }

    f32x4 o[2][4];
#pragma unroll
    for (int qt = 0; qt < 2; ++qt)
#pragma unroll
        for (int dt = 0; dt < 4; ++dt) o[qt][dt] = (f32x4){0.f, 0.f, 0.f, 0.f};
    float mrun[2] = {-1e30f, -1e30f};
    float lrun[2] = {0.f, 0.f};

    int kw0 = cbase - W_; if (kw0 < 0) kw0 = 0;
    int kw1 = cbase + QB_ + W_; if (kw1 > S_) kw1 = S_;
    int ntiles = (kw1 - kw0) >> 6;

    char* Pw = (char*)P_lds[w];

    for (int t = 0; t < ntiles; ++t) {
        int k0 = kw0 + t * 64;
        __syncthreads();
        {
            const __hip_bfloat16* Kg = K + (size_t)(b * S_ + k0) * D_ + h * DH_;
            const __hip_bfloat16* Vg = V + (size_t)(b * S_ + k0) * D_ + h * DH_;
#pragma unroll
            for (int it = 0; it < 2; ++it) {
                int idx = tid + it * 256;
                int kk = idx >> 3, d0 = (idx & 7) * 8;
                uint4 kv = *(const uint4*)(Kg + (size_t)kk * D_ + d0);
                *(uint4*)&K_lds[kk * 72 + d0] = kv;
                uint4 vv = *(const uint4*)(Vg + (size_t)kk * D_ + d0);
                unsigned short vs[8];
                *(uint4*)vs = vv;
#pragma unroll
                for (int j = 0; j < 8; ++j) {
                    int dd = d0 + j;
                    int boff = dd * 144 + ((kk * 2) ^ (((dd >> 3) & 7) << 4));
                    *(unsigned short*)((char*)VT_lds + boff) = vs[j];
                }
            }
        }
        __syncthreads();

        frag_ab kf[4][2];
#pragma unroll
        for (int kt = 0; kt < 4; ++kt) {
            const char* kp = (const char*)K_lds + (kt * 16 + l15) * 144 + g4 * 16;
            kf[kt][0] = *(const frag_ab*)kp;
            kf[kt][1] = *(const frag_ab*)(kp + 64);
        }
        frag_ab vf[4][2];
#pragma unroll
        for (int dt = 0; dt < 4; ++dt) {
            int drow = dt * 16 + l15;
            int swz = ((drow >> 3) & 7) << 4;
            const char* vp = (const char*)VT_lds + drow * 144;
            vf[dt][0] = *(const frag_ab*)(vp + ((g4 * 16) ^ swz));
            vf[dt][1] = *(const frag_ab*)(vp + ((g4 * 16 + 64) ^ swz));
        }

#pragma unroll
        for (int qt = 0; qt < 2; ++qt) {
            f32x4 st[4];
            __builtin_amdgcn_s_setprio(1);
#pragma unroll
            for (int kt = 0; kt < 4; ++kt) {
                f32x4 z = (f32x4){0.f, 0.f, 0.f, 0.f};
                z = __builtin_amdgcn_mfma_f32_16x16x32_bf16(kf[kt][0], qf[qt][0], z, 0, 0, 0);
                z = __builtin_amdgcn_mfma_f32_16x16x32_bf16(kf[kt][1], qf[qt][1], z, 0, 0, 0);
                st[kt] = z;
            }
            __builtin_amdgcn_s_setprio(0);
            int qa = cbase + w * 32 + qt * 16 + l15;
            float sv[16];
            float mx = -1e30f;
#pragma unroll
            for (int kt = 0; kt < 4; ++kt)
#pragma unroll
                for (int r = 0; r < 4; ++r) {
                    int ka = k0 + kt * 16 + g4 * 4 + r;
                    float s = st[kt][r] * 0.125f;
                    bool bad = (ka < NG_) | (ka - qa > W_) | (qa - ka > W_);
                    s = bad ? -1e30f : s;
                    sv[kt * 4 + r] = s;
                    mx = fmaxf(mx, s);
                }
            mx = fmaxf(mx, __shfl_xor(mx, 16));
            mx = fmaxf(mx, __shfl_xor(mx, 32));
            float mnew = fmaxf(fmaxf(mrun[qt], mx), -60.0f);
            if (__any(mnew != mrun[qt])) {   // T13-lite: skip rescale when max unchanged
                float fsc = __expf(mrun[qt] - mnew);
                mrun[qt] = mnew;
#pragma unroll
                for (int dt = 0; dt < 4; ++dt) o[qt][dt] *= fsc;
                lrun[qt] *= fsc;
            }
            float psum = 0.f;
            unsigned short pb[16];
#pragma unroll
            for (int i = 0; i < 16; ++i) {
                float p = __expf(sv[i] - mrun[qt]);
                psum += p;
                pb[i] = f2bfu(p);
            }
            psum += __shfl_xor(psum, 16);
            psum += __shfl_xor(psum, 32);
            lrun[qt] += psum;
#pragma unroll
            for (int kt = 0; kt < 4; ++kt)
#pragma unroll
                for (int rp = 0; rp < 2; ++rp) {
                    unsigned vpk = (unsigned)pb[kt * 4 + rp * 2] | ((unsigned)pb[kt * 4 + rp * 2 + 1] << 16);
                    int kloc = kt * 16 + g4 * 4 + rp * 2;
                    *(unsigned*)(Pw + l15 * 144 + kloc * 2) = vpk;
                }
            frag_ab pf0 = *(const frag_ab*)(Pw + l15 * 144 + g4 * 16);
            frag_ab pf1 = *(const frag_ab*)(Pw + l15 * 144 + g4 * 16 + 64);
            __builtin_amdgcn_s_setprio(1);
#pragma unroll
            for (int dt = 0; dt < 4; ++dt) {
                o[qt][dt] = __builtin_amdgcn_mfma_f32_16x16x32_bf16(vf[dt][0], pf0, o[qt][dt], 0, 0, 0);
                o[qt][dt] = __builtin_amdgcn_mfma_f32_16x16x32_bf16(vf[dt][1], pf1, o[qt][dt], 0, 0, 0);
            }
            __builtin_amdgcn_s_setprio(0);
        }
    }

    // ---- 3 global keys (unmasked), scalar epilogue ----
    uint4 kgc[3][2];
    uint2 vgd[3][4];
#pragma unroll
    for (int gk = 0; gk < NG_; ++gk) {
        const __hip_bfloat16* kp = K + (size_t)(b * S_ + gk) * D_ + h * DH_ + g4 * 8;
        kgc[gk][0] = *(const uint4*)kp;
        kgc[gk][1] = *(const uint4*)(kp + 32);
        const __hip_bfloat16* vp = V + (size_t)(b * S_ + gk) * D_ + h * DH_ + g4 * 4;
#pragma unroll
        for (int dt = 0; dt < 4; ++dt)
            vgd[gk][dt] = *(const uint2*)(vp + dt * 16);
    }
#pragma unroll
    for (int qt = 0; qt < 2; ++qt) {
        float sg[3];
#pragma unroll
        for (int gk = 0; gk < NG_; ++gk) {
            float part = 0.f;
#pragma unroll
            for (int s = 0; s < 2; ++s) {
                uint4 qw = *(uint4*)&qf[qt][s];
                uint4 kw = kgc[gk][s];
                part += bflo(qw.x) * bflo(kw.x) + bfhi(qw.x) * bfhi(kw.x);
                part += bflo(qw.y) * bflo(kw.y) + bfhi(qw.y) * bfhi(kw.y);
                part += bflo(qw.z) * bflo(kw.z) + bfhi(qw.z) * bfhi(kw.z);
                part += bflo(qw.w) * bflo(kw.w) + bfhi(qw.w) * bfhi(kw.w);
            }
            part += __shfl_xor(part, 16);
            part += __shfl_xor(part, 32);
            sg[gk] = part * 0.125f;
        }
        float mx3 = fmaxf(fmaxf(sg[0], sg[1]), sg[2]);
        float mnew = fmaxf(fmaxf(mrun[qt], mx3), -60.0f);
        float fsc = __expf(mrun[qt] - mnew);
        mrun[qt] = mnew;
#pragma unroll
        for (int dt = 0; dt < 4; ++dt) o[qt][dt] *= fsc;
        lrun[qt] *= fsc;
        float pg[3];
        float psum = 0.f;
#pragma unroll
        for (int gk = 0; gk < NG_; ++gk) { pg[gk] = __expf(sg[gk] - mnew); psum += pg[gk]; }
        lrun[qt] += psum;
#pragma unroll
        for (int dt = 0; dt < 4; ++dt) {
#pragma unroll
            for (int gk = 0; gk < NG_; ++gk) {
                uint2 vv = vgd[gk][dt];
                o[qt][dt][0] += pg[gk] * bflo(vv.x);
                o[qt][dt][1] += pg[gk] * bfhi(vv.x);
                o[qt][dt][2] += pg[gk] * bflo(vv.y);
                o[qt][dt][3] += pg[gk] * bfhi(vv.y);
            }
        }
    }

#pragma unroll
    for (int qt = 0; qt < 2; ++qt) {
        float linv = 1.0f / lrun[qt];
        int qa = cbase + w * 32 + qt * 16 + l15;
        __hip_bfloat16* orow = O + (size_t)(b * S_ + qa) * D_ + h * DH_;
#pragma unroll
        for (int dt = 0; dt < 4; ++dt) {
            unsigned short pk[4];
#pragma unroll
            for (int r = 0; r < 4; ++r) pk[r] = f2bfu(o[qt][dt][r] * linv);
            *(uint2*)(orow + dt * 16 + g4 * 4) = *(uint2*)pk;
        }
    }
}

// ---------------- global attention, split-S flash decode ----------------
__global__ __launch_bounds__(256) void gattn_part_k(
    const float* __restrict__ qg, const __hip_bfloat16* __restrict__ KG,
    const __hip_bfloat16* __restrict__ VG, float* __restrict__ gpart) {
    __shared__ float sc[256];
    __shared__ float qs[DH_];
    __shared__ float red[256];
    __shared__ float rv[16][64];
    int split = blockIdx.x;
    int gh = blockIdx.y;
    int g = gh / H_, h = gh - g * H_;
    int b = blockIdx.z;
    int tid = threadIdx.x;
    if (tid < DH_) qs[tid] = qg[(size_t)(b * NG_ + g) * D_ + h * DH_ + tid] * 0.125f;
    __syncthreads();
    int s0 = split * (S_ / NSPLIT_);
    float acc = 0.f;
    {
        const __hip_bfloat16* kp = KG + (size_t)(b * S_ + s0 + tid) * D_ + h * DH_;
#pragma unroll
        for (int c8 = 0; c8 < 8; ++c8) {
            uint4 t = *(const uint4*)(kp + c8 * 8);
            float f[8]; unp8(t, f);
#pragma unroll
            for (int j = 0; j < 8; ++j) acc += qs[c8 * 8 + j] * f[j];
        }
    }
    float m = block_max(acc, red);
    float e = __expf(acc - m);
    sc[tid] = e;
    float l = block_sum(e, red);
    int sgq = tid >> 4, dq = (tid & 15) * 4;
    float a0 = 0.f, a1 = 0.f, a2 = 0.f, a3 = 0.f;
    const __hip_bfloat16* vbase = VG + (size_t)(b * S_ + s0 + sgq * 16) * D_ + h * DH_ + dq;
#pragma unroll
    for (int i = 0; i < 16; ++i) {
        float p = sc[sgq * 16 + i];
        uint2 vv = *(const uint2*)(vbase + (size_t)i * D_);
        a0 += p * bflo(vv.x); a1 += p * bfhi(vv.x);
        a2 += p * bflo(vv.y); a3 += p * bfhi(vv.y);
    }
    rv[sgq][dq] = a0; rv[sgq][dq + 1] = a1; rv[sgq][dq + 2] = a2; rv[sgq][dq + 3] = a3;
    __syncthreads();
    float* op = gpart + ((size_t)((b * NG_ + g) * H_ + h) * NSPLIT_ + split) * 66;
    if (tid == 0) { op[0] = m; op[1] = l; }
    if (tid < DH_) {
        float s = 0.f;
#pragma unroll
        for (int j = 0; j < 16; ++j) s += rv[j][tid];
        op[2 + tid] = s;
    }
}

template <typename TO>
__global__ __launch_bounds__(64) void gattn_comb_k(
    const float* __restrict__ gpart, TO* __restrict__ outp, int rowStride) {
    int g = blockIdx.x, h = blockIdx.y, b = blockIdx.z;
    int tid = threadIdx.x;
    const float* base = gpart + (size_t)((b * NG_ + g) * H_ + h) * NSPLIT_ * 66;
    float M = -1e30f;
#pragma unroll
    for (int p = 0; p < NSPLIT_; ++p) M = fmaxf(M, base[p * 66]);
    float l = 0.f, o = 0.f;
#pragma unroll
    for (int p = 0; p < NSPLIT_; ++p) {
        float wgt = __expf(base[p * 66] - M);
        l += wgt * base[p * 66 + 1];
        o += wgt * base[p * 66 + 2 + tid];
    }
    storeO(&outp[(size_t)(b * rowStride + g) * D_ + h * DH_ + tid], o / l);
}

// ---------------- gather the 6 global-token rows ----------------
__global__ void gather6_k(const float* __restrict__ X, float* __restrict__ xg) {
    int r = blockIdx.x;
    int b = r / NG_, g = r % NG_;
    for (int c = threadIdx.x; c < D_; c += blockDim.x)
        xg[(size_t)r * D_ + c] = X[(size_t)(b * S_ + g) * D_ + c];
}

// ---------------- classifier heads ----------------
__global__ __launch_bounds__(256) void classifier_k(
    const float* __restrict__ x26, const float* __restrict__ cw,
    const float* __restrict__ cb, float* __restrict__ out) {
    __shared__ float red[256];
    int tid = threadIdx.x;
    for (int i = 0; i < 3; ++i) {
        for (int b = 0; b < B_; ++b) {
            const float* xr = x26 + (size_t)(b * NG_ + i) * D_;
            const float* wr = cw + (size_t)i * D_;
            float p = 0.f;
            for (int c = tid; c < D_; c += 256) p += xr[c] * wr[c];
            float dotv = block_sum(p, red);
            if (tid == 0) out[i * B_ + b] = 1.0f / (1.0f + __expf(-(dotv + cb[i])));
        }
    }
    if (tid == 0) { out[6] = 1.0f; out[7] = 1.0f; }
}

// ---------------- host launcher ----------------
extern "C" void kernel_launch(void* const* d_in, const int* in_sizes, int n_in,
                              void* d_out, int out_size, void* d_ws, size_t ws_size,
                              hipStream_t stream) {
    const int*   src      = (const int*)d_in[0];
    const float* word_emb = (const float*)d_in[3];
    const float* pos_emb  = (const float*)d_in[4];
    const float* emb_ln   = (const float*)d_in[5];
    const float* attn_w   = (const float*)d_in[6];
    const float* attn_b   = (const float*)d_in[7];
    const float* ln_p     = (const float*)d_in[8];
    const float* ffn_w1   = (const float*)d_in[9];
    const float* ffn_b1   = (const float*)d_in[10];
    const float* ffn_w2   = (const float*)d_in[11];
    const float* ffn_b2   = (const float*)d_in[12];
    const float* cls_w    = (const float*)d_in[13];
    const float* cls_b    = (const float*)d_in[14];
    float* out = (float*)d_out;

    const size_t NT = (size_t)B_ * S_ * D_;  // 6291456 (elements)
    float* base = (float*)d_ws;
    float* X  = base;
    float* P4 = base + NT;
    __hip_bfloat16* Xb = (__hip_bfloat16*)(base + 2 * NT);
    __hip_bfloat16* Qb = (__hip_bfloat16*)(base + 5 * NT / 2);  // Qb,Kb,Vb contiguous (NT apart)
    __hip_bfloat16* Kb = (__hip_bfloat16*)(base + 3 * NT);
    __hip_bfloat16* Vb = (__hip_bfloat16*)(base + 7 * NT / 2);
    __hip_bfloat16* AOb = (__hip_bfloat16*)(base + 4 * NT);
    __hip_bfloat16* HCb = AOb;
    __hip_bfloat16* wq  = (__hip_bfloat16*)(base + 5 * NT);
    __hip_bfloat16* wg1 = wq + 3 * 589824;
    __hip_bfloat16* wo  = wg1 + 2 * 589824;
    __hip_bfloat16* wf1 = wo + 589824;
    __hip_bfloat16* wf2 = wf1 + 2359296;
    float* SM  = base + 5 * NT + 4128768;
    float* xg  = SM;
    float* qg6 = xg + 6 * D_;
    float* og6 = qg6 + 6 * D_;
    float* pr6 = og6 + 6 * D_;
    float* xa6 = pr6 + 6 * D_;
    float* h6  = xa6 + 6 * D_;
    float* f6  = h6 + 6 * FF_;
    float* x26 = f6 + 6 * D_;
    float* part = x26 + 6 * D_;
    float* gpart = part;

    const int M = B_ * S_;
    dim3 blk(256);

    auto aw = [&](int l, int i) { return attn_w + ((size_t)(l * 7 + i)) * D_ * D_; };
    auto ab = [&](int l, int i) { return attn_b + (size_t)(l * 7 + i) * D_; };
    auto lnp = [&](int l, int i) { return ln_p + (size_t)(l * 4 + i) * D_; };

    auto skinny = [&](const float* A6, const float* Wm, const float* bias,
                      float* out6, int N, int K, int gelu) {
        skinny_gemm_k<<<dim3(N / 64, K / 64), blk, 0, stream>>>(A6, Wm, part, N, K);
        skinny_reduce_k<<<dim3((6 * N + 255) / 256), blk, 0, stream>>>(part, bias, out6, N, K / 64, gelu);
    };

    embed_ln_k<<<M, blk, 0, stream>>>(src, word_emb, pos_emb, emb_ln, emb_ln + D_, X, Xb);

    // ================= layer 0 =================
    convt_k<<<dim3(24 * 3, 24), blk, 0, stream>>>(aw(0, 0), wq, D_, D_, 24);
    mfma_gemm_k<1, 1><<<dim3(2304 / 128, 64), blk, 0, stream>>>(Xb, wq, ab(0, 0), Qb, M, 2304, D_, NT);
    local_attn_k<<<dim3(S_ / QB_, H_, B_), blk, 0, stream>>>(Qb, Kb, Vb, AOb);
    convt_k<<<dim3(24 * 2, 24), blk, 0, stream>>>(aw(0, 4), wg1, D_, D_, 24);
    mfma_gemm_k<1, 1><<<dim3(1536 / 128, 64), blk, 0, stream>>>(Xb, wg1, ab(0, 4), Qb, M, 1536, D_, NT);
    gather6_k<<<B_ * NG_, blk, 0, stream>>>(X, xg);
    skinny(xg, aw(0, 3), ab(0, 3), qg6, D_, D_, 0);
    gattn_part_k<<<dim3(NSPLIT_, NG_ * H_, B_), blk, 0, stream>>>(qg6, Qb, Kb, gpart);
    gattn_comb_k<__hip_bfloat16><<<dim3(NG_, H_, B_), dim3(64), 0, stream>>>(gpart, AOb, S_);
    convt_k<<<dim3(24, 24), blk, 0, stream>>>(aw(0, 6), wo, D_, D_, 24);
    mfma_gemm_k<0, 0><<<dim3(6, 64), blk, 0, stream>>>(AOb, wo, ab(0, 6), P4, M, D_, D_, 0);
    residual_ln_k<<<M, blk, 0, stream>>>(X, P4, lnp(0, 0), lnp(0, 1), P4, Xb);
    convt_k<<<dim3(96, 24), blk, 0, stream>>>(ffn_w1, wf1, D_, FF_, 96);
    convt_k<<<dim3(24, 96), blk, 0, stream>>>(ffn_w2, wf2, FF_, D_, 24);
    for (int ch = 0; ch < 2; ++ch) {
        mfma_gemm_k<2, 0><<<dim3(24, 32), blk, 0, stream>>>(Xb + (size_t)ch * 4096 * D_, wf1, ffn_b1, HCb, 4096, FF_, D_, 0);
        mfma_gemm_k<0, 0><<<dim3(6, 32), blk, 0, stream>>>(HCb, wf2, ffn_b2, X + (size_t)ch * 4096 * D_, 4096, D_, FF_, 0);
    }
    residual_ln_k<<<M, blk, 0, stream>>>(P4, X, lnp(0, 2), lnp(0, 3), X, Xb);

    // ================= layer 1 (pruned) =================
    convt_k<<<dim3(24 * 2, 24), blk, 0, stream>>>(aw(1, 4), wg1, D_, D_, 24);
    mfma_gemm_k<1, 1><<<dim3(1536 / 128, 64), blk, 0, stream>>>(Xb, wg1, ab(1, 4), Qb, M, 1536, D_, NT);
    gather6_k<<<B_ * NG_, blk, 0, stream>>>(X, xg);
    skinny(xg, aw(1, 3), ab(1, 3), qg6, D_, D_, 0);
    gattn_part_k<<<dim3(NSPLIT_, NG_ * H_, B_), blk, 0, stream>>>(qg6, Qb, Kb, gpart);
    gattn_comb_k<float><<<dim3(NG_, H_, B_), dim3(64), 0, stream>>>(gpart, og6, NG_);
    skinny(og6, aw(1, 6), ab(1, 6), pr6, D_, D_, 0);
    residual_ln_k<<<B_ * NG_, blk, 0, stream>>>(xg, pr6, lnp(1, 0), lnp(1, 1), xa6, nullptr);
    skinny(xa6, ffn_w1 + (size_t)D_ * FF_, ffn_b1 + FF_, h6, FF_, D_, 1);
    skinny(h6, ffn_w2 + (size_t)FF_ * D_, ffn_b2 + D_, f6, D_, FF_, 0);
    residual_ln_k<<<B_ * NG_, blk, 0, stream>>>(xa6, f6, lnp(1, 2), lnp(1, 3), x26, nullptr);
    classifier_k<<<1, blk, 0, stream>>>(x26, cls_w, cls_b, out);
}

// Round 11
// 516.842 us; speedup vs baseline: 22.9947x; 1.1010x over previous
//
#include <hip/hip_runtime.h>
#include <hip/hip_bf16.h>
#include <math.h>

// ---------------- constants (problem shapes) ----------------
#define B_    2
#define SSRC_ 4093
#define D_    768
#define H_    12
#define DH_   64
#define FF_   3072
#define NG_   3
#define W_    256
#define S_    4096
#define NC_   16
#define NSPLIT_ 16
#define QB_   128

typedef __attribute__((ext_vector_type(8))) short frag_ab;   // 8 bf16 (4 VGPRs)
typedef __attribute__((ext_vector_type(4))) float f32x4;     // 4 fp32 acc

// async global->LDS, 16B per lane (linear dest: base + lane*16)
#define GL16(gp, lp) __builtin_amdgcn_global_load_lds( \
    (const __attribute__((address_space(1))) void*)(gp), \
    (__attribute__((address_space(3))) void*)(lp), 16, 0, 0)

// ---------------- helpers ----------------
__device__ __forceinline__ float bflo(unsigned int w) {
    union { float f; unsigned int i; } c; c.i = w << 16; return c.f;
}
__device__ __forceinline__ float bfhi(unsigned int w) {
    union { float f; unsigned int i; } c; c.i = w & 0xffff0000u; return c.f;
}
__device__ __forceinline__ void unp8(uint4 t, float* o) {
    o[0] = bflo(t.x); o[1] = bfhi(t.x); o[2] = bflo(t.y); o[3] = bfhi(t.y);
    o[4] = bflo(t.z); o[5] = bfhi(t.z); o[6] = bflo(t.w); o[7] = bfhi(t.w);
}
__device__ __forceinline__ unsigned short f2bfu(float x) {
    __hip_bfloat16 h = __float2bfloat16(x);
    return *reinterpret_cast<unsigned short*>(&h);
}

__device__ __forceinline__ float block_sum(float v, float* red) {
    int tid = threadIdx.x;
    red[tid] = v;
    __syncthreads();
#pragma unroll
    for (int off = 128; off >= 1; off >>= 1) {
        if (tid < off) red[tid] += red[tid + off];
        __syncthreads();
    }
    float r = red[0];
    __syncthreads();
    return r;
}

__device__ __forceinline__ float block_max(float v, float* red) {
    int tid = threadIdx.x;
    red[tid] = v;
    __syncthreads();
#pragma unroll
    for (int off = 128; off >= 1; off >>= 1) {
        if (tid < off) red[tid] = fmaxf(red[tid], red[tid + off]);
        __syncthreads();
    }
    float r = red[0];
    __syncthreads();
    return r;
}

__device__ __forceinline__ void storeO(float* p, float v) { *p = v; }
__device__ __forceinline__ void storeO(__hip_bfloat16* p, float v) { *p = __float2bfloat16(v); }

// ---------------- embedding + LN (writes f32 X and bf16 Xb) ----------------
__global__ __launch_bounds__(256) void embed_ln_k(
    const int* __restrict__ src, const float* __restrict__ we,
    const float* __restrict__ pe, const float* __restrict__ gam,
    const float* __restrict__ bet, float* __restrict__ X,
    __hip_bfloat16* __restrict__ Xb) {
    __shared__ float red[256];
    int row = blockIdx.x;
    int b = row >> 12;
    int s = row & (S_ - 1);
    int tid = threadIdx.x;
    int id = (s < NG_) ? (50261 + s) : src[b * SSRC_ + (s - NG_)];
    const float* wr = we + (size_t)id * D_;
    const float* pr = pe + (size_t)s * D_;
    float v[3];
    float lsum = 0.f;
#pragma unroll
    for (int j = 0; j < 3; ++j) {
        int c = tid + j * 256;
        v[j] = wr[c] + pr[c];
        lsum += v[j];
    }
    float mu = block_sum(lsum, red) * (1.0f / 768.0f);
    float ls2 = 0.f;
#pragma unroll
    for (int j = 0; j < 3; ++j) { float d = v[j] - mu; ls2 += d * d; }
    float var = block_sum(ls2, red) * (1.0f / 768.0f);
    float rs = rsqrtf(var + 1e-5f);
    float* xr = X + (size_t)row * D_;
    __hip_bfloat16* xbr = Xb + (size_t)row * D_;
#pragma unroll
    for (int j = 0; j < 3; ++j) {
        int c = tid + j * 256;
        float o = (v[j] - mu) * rs * gam[c] + bet[c];
        xr[c] = o;
        xbr[c] = __float2bfloat16(o);
    }
}

// ---------------- residual + LN : out = LN(x + y [+ y2]), optional bf16 mirror ----------------
__global__ __launch_bounds__(256) void residual_ln_k(
    const float* __restrict__ x, const float* __restrict__ y,
    const float* __restrict__ y2, const float* __restrict__ gam,
    const float* __restrict__ bet, float* __restrict__ out,
    __hip_bfloat16* __restrict__ outb) {
    __shared__ float red[256];
    int row = blockIdx.x;
    int tid = threadIdx.x;
    const float* xr = x + (size_t)row * D_;
    const float* yr = y + (size_t)row * D_;
    const float* y2r = y2 ? y2 + (size_t)row * D_ : nullptr;
    float v[3];
    float lsum = 0.f;
#pragma unroll
    for (int j = 0; j < 3; ++j) {
        int c = tid + j * 256;
        v[j] = xr[c] + yr[c];
        if (y2r) v[j] += y2r[c];
        lsum += v[j];
    }
    float mu = block_sum(lsum, red) * (1.0f / 768.0f);
    float ls2 = 0.f;
#pragma unroll
    for (int j = 0; j < 3; ++j) { float d = v[j] - mu; ls2 += d * d; }
    float var = block_sum(ls2, red) * (1.0f / 768.0f);
    float rs = rsqrtf(var + 1e-5f);
    float* orow = out + (size_t)row * D_;
    __hip_bfloat16* obr = outb ? outb + (size_t)row * D_ : nullptr;
#pragma unroll
    for (int j = 0; j < 3; ++j) {
        int c = tid + j * 256;
        float o = (v[j] - mu) * rs * gam[c] + bet[c];
        orow[c] = o;
        if (obr) obr[c] = __float2bfloat16(o);
    }
}

// ---------------- transpose-convert: nmat x (W[K,N] f32 -> WT[N,K] bf16) ----------------
__global__ __launch_bounds__(256) void convt_k(
    const float* __restrict__ W, __hip_bfloat16* __restrict__ WT,
    int K, int N, int npb /* = N/32 */) {
    __shared__ float tile[32][33];
    int mat = blockIdx.x / npb;
    int bx = blockIdx.x - mat * npb;
    int by = blockIdx.y;
    const float* Wm = W + (size_t)mat * K * N;
    __hip_bfloat16* WTm = WT + (size_t)mat * N * K;
    int tx = threadIdx.x & 31, ty = threadIdx.x >> 5;
#pragma unroll
    for (int i = 0; i < 32; i += 8)
        tile[ty + i][tx] = Wm[(size_t)(by * 32 + ty + i) * N + bx * 32 + tx];
    __syncthreads();
#pragma unroll
    for (int i = 0; i < 32; i += 8)
        WTm[(size_t)(bx * 32 + ty + i) * K + by * 32 + tx] = __float2bfloat16(tile[tx][ty + i]);
}

// ---------------- pack layer-0 mega bias: [ab0,ab1,ab2,ab4,ab5] -> 3840 ----------------
__global__ void pack_bias_k(const float* __restrict__ ab, float* __restrict__ dst) {
    int j = blockIdx.x * 256 + threadIdx.x;
    if (j >= 5 * 768) return;
    int mat = j / 768, c = j - mat * 768;
    int i = (mat < 3) ? mat : mat + 1;
    dst[j] = ab[i * 768 + c];
}

// ---------------- MFMA GEMM (global_load_lds staged, m97 structure) ----------------
// C[M,N] = A[M,K]bf16 @ BT[N,K]^T + bias
// EPI: 0 = f32 out, 1 = bf16 out, 2 = bf16 gelu(out)
// SPLIT: 1 => output col c -> matrix c/768 (stride matstride bf16 elems)
// gridDim.z > 1 => split-K: z-th K-slice, f32 partial at Cout + z*M*N (EPI must be 0);
//                 bias added only in z==0 slice.
template <int EPI, int SPLIT>
__global__ __launch_bounds__(256) void mfma_gemm_k(
    const __hip_bfloat16* __restrict__ A, const __hip_bfloat16* __restrict__ BT,
    const float* __restrict__ bias, void* __restrict__ Cout,
    int M, int N, int K, size_t matstride) {
    __shared__ __align__(16) __hip_bfloat16 As[4096];
    __shared__ __align__(16) __hip_bfloat16 Bs[4096];
    int tid = threadIdx.x;
    int lane = tid & 63;
    int w = tid >> 6, wr = w >> 1, wc = w & 1;
    int brow = blockIdx.y * 128, bcol = blockIdx.x * 128;
    int z = blockIdx.z, nz = gridDim.z;
    int Kz = K / nz;
    int r0 = tid >> 2, k0 = (tid & 3) * 8;
    const __hip_bfloat16* Ag0 = A + (size_t)(brow + r0) * K + z * Kz + k0;
    const __hip_bfloat16* Ag1 = Ag0 + (size_t)64 * K;
    const __hip_bfloat16* Bg0 = BT + (size_t)(bcol + r0) * K + z * Kz + k0;
    const __hip_bfloat16* Bg1 = Bg0 + (size_t)64 * K;
    __hip_bfloat16* lA0 = &As[tid * 8];
    __hip_bfloat16* lA1 = &As[tid * 8 + 2048];
    __hip_bfloat16* lB0 = &Bs[tid * 8];
    __hip_bfloat16* lB1 = &Bs[tid * 8 + 2048];

    f32x4 acc[4][4];
#pragma unroll
    for (int m = 0; m < 4; ++m)
#pragma unroll
        for (int n = 0; n < 4; ++n) acc[m][n] = (f32x4){0.f, 0.f, 0.f, 0.f};

    int l15 = lane & 15, kb = lane >> 4;
    int aoff = (wr * 64 + l15) * 32 + kb * 8;
    int boff = (wc * 64 + l15) * 32 + kb * 8;

    for (int kt = 0; kt < Kz; kt += 32) {
        GL16(Ag0 + kt, lA0);
        GL16(Ag1 + kt, lA1);
        GL16(Bg0 + kt, lB0);
        GL16(Bg1 + kt, lB1);
        __syncthreads();
        frag_ab af[4], bf[4];
#pragma unroll
        for (int m = 0; m < 4; ++m) af[m] = *(const frag_ab*)&As[aoff + m * 512];
#pragma unroll
        for (int n = 0; n < 4; ++n) bf[n] = *(const frag_ab*)&Bs[boff + n * 512];
        __builtin_amdgcn_s_setprio(1);
#pragma unroll
        for (int m = 0; m < 4; ++m)
#pragma unroll
            for (int n = 0; n < 4; ++n)
                acc[m][n] = __builtin_amdgcn_mfma_f32_16x16x32_bf16(af[m], bf[n], acc[m][n], 0, 0, 0);
        __builtin_amdgcn_s_setprio(0);
        __syncthreads();
    }

    size_t zoff = (size_t)z * M * N;
#pragma unroll
    for (int m = 0; m < 4; ++m) {
        int rowb = brow + wr * 64 + m * 16 + (lane >> 4) * 4;
#pragma unroll
        for (int n = 0; n < 4; ++n) {
            int col = bcol + wc * 64 + n * 16 + l15;
            float bv = (z == 0) ? bias[col] : 0.f;
#pragma unroll
            for (int r = 0; r < 4; ++r) {
                float v = acc[m][n][r] + bv;
                size_t idx;
                if (SPLIT) {
                    int mat = col / 768;
                    idx = (size_t)mat * matstride + (size_t)(rowb + r) * 768 + (col - mat * 768);
                } else {
                    idx = zoff + (size_t)(rowb + r) * N + col;
                }
                if (EPI == 0) {
                    ((float*)Cout)[idx] = v;
                } else if (EPI == 1) {
                    ((__hip_bfloat16*)Cout)[idx] = __float2bfloat16(v);
                } else {
                    float g = 0.5f * v * (1.0f + erff(v * 0.70710678118654752f));
                    ((__hip_bfloat16*)Cout)[idx] = __float2bfloat16(g);
                }
            }
        }
    }
}

// ---------------- split-K skinny GEMM: M=6 rows ----------------
__global__ __launch_bounds__(256) void skinny_gemm_k(
    const float* __restrict__ A, const float* __restrict__ W,
    float* __restrict__ partial, int N, int K) {
    __shared__ float Asl[6][64];
    __shared__ float red[4][6][64];
    int tid = threadIdx.x;
    int cl = tid & 63;
    int kg = tid >> 6;
    int col = blockIdx.x * 64 + cl;
    int k0 = blockIdx.y * 64;
    for (int i = tid; i < 6 * 64; i += 256)
        Asl[i >> 6][i & 63] = A[(size_t)(i >> 6) * K + k0 + (i & 63)];
    __syncthreads();
    float acc[6] = {0.f, 0.f, 0.f, 0.f, 0.f, 0.f};
#pragma unroll
    for (int kk = 0; kk < 16; ++kk) {
        int k = kg * 16 + kk;
        float wv = W[(size_t)(k0 + k) * N + col];
#pragma unroll
        for (int m = 0; m < 6; ++m) acc[m] += Asl[m][k] * wv;
    }
#pragma unroll
    for (int m = 0; m < 6; ++m) red[kg][m][cl] = acc[m];
    __syncthreads();
    for (int i = tid; i < 6 * 64; i += 256) {
        int m = i >> 6, lane = i & 63;
        float s = red[0][m][lane] + red[1][m][lane] + red[2][m][lane] + red[3][m][lane];
        partial[(size_t)blockIdx.y * 6 * N + (size_t)m * N + blockIdx.x * 64 + lane] = s;
    }
}

__global__ __launch_bounds__(256) void skinny_reduce_k(
    const float* __restrict__ partial, const float* __restrict__ bias,
    float* __restrict__ outp, int N, int KS, int gelu) {
    int idx = blockIdx.x * 256 + threadIdx.x;
    if (idx >= 6 * N) return;
    int m = idx / N, col = idx - m * N;
    float s = bias[col];
    for (int kb = 0; kb < KS; ++kb)
        s += partial[(size_t)kb * 6 * N + (size_t)m * N + col];
    if (gelu) s = 0.5f * s * (1.0f + erff(s * 0.70710678118654752f));
    outp[(size_t)m * N + col] = s;
}

// ---------------- MFMA sliding-window local attention (128-query blocks) ----------------
__global__ __launch_bounds__(256, 1) void local_attn_k(
    const __hip_bfloat16* __restrict__ Q, const __hip_bfloat16* __restrict__ K,
    const __hip_bfloat16* __restrict__ V, __hip_bfloat16* __restrict__ O) {
    __shared__ __align__(16) __hip_bfloat16 K_lds[64 * 72];
    __shared__ __align__(16) __hip_bfloat16 VT_lds[64 * 72];
    __shared__ __align__(16) __hip_bfloat16 P_lds[4][16 * 72];

    const int cq = blockIdx.x, h = blockIdx.y, b = blockIdx.z;
    const int tid = threadIdx.x;
    const int lane = tid & 63;
    const int w = tid >> 6;
    const int l15 = lane & 15, g4 = lane >> 4;
    const int cbase = cq * QB_;

    frag_ab qf[2][2];
#pragma unroll
    for (int qt = 0; qt < 2; ++qt) {
        int qa = cbase + w * 32 + qt * 16 + l15;
        const __hip_bfloat16* qp = Q + (size_t)(b * S_ + qa) * D_ + h * DH_ + g4 * 8;
        qf[qt][0] = *(const frag_ab*)qp;
        qf[qt][1] = *(const frag_ab*)(qp + 32);
    }

    f32x4 o[2][4];
#pragma unroll
    for (int qt = 0; qt < 2; ++qt)
#pragma unroll
        for (int dt = 0; dt < 4; ++dt) o[qt][dt] = (f32x4){0.f, 0.f, 0.f, 0.f};
    float mrun[2] = {-1e30f, -1e30f};
    float lrun[2] = {0.f, 0.f};

    int kw0 = cbase - W_; if (kw0 < 0) kw0 = 0;
    int kw1 = cbase + QB_ + W_; if (kw1 > S_) kw1 = S_;
    int ntiles = (kw1 - kw0) >> 6;

    char* Pw = (char*)P_lds[w];

    for (int t = 0; t < ntiles; ++t) {
        int k0 = kw0 + t * 64;
        __syncthreads();
        {
            const __hip_bfloat16* Kg = K + (size_t)(b * S_ + k0) * D_ + h * DH_;
            const __hip_bfloat16* Vg = V + (size_t)(b * S_ + k0) * D_ + h * DH_;
#pragma unroll
            for (int it = 0; it < 2; ++it) {
                int idx = tid + it * 256;
                int kk = idx >> 3, d0 = (idx & 7) * 8;
                uint4 kv = *(const uint4*)(Kg + (size_t)kk * D_ + d0);
                *(uint4*)&K_lds[kk * 72 + d0] = kv;
                uint4 vv = *(const uint4*)(Vg + (size_t)kk * D_ + d0);
                unsigned short vs[8];
                *(uint4*)vs = vv;
#pragma unroll
                for (int j = 0; j < 8; ++j) {
                    int dd = d0 + j;
                    int boff = dd * 144 + ((kk * 2) ^ (((dd >> 3) & 7) << 4));
                    *(unsigned short*)((char*)VT_lds + boff) = vs[j];
                }
            }
        }
        __syncthreads();

        frag_ab kf[4][2];
#pragma unroll
        for (int kt = 0; kt < 4; ++kt) {
            const char* kp = (const char*)K_lds + (kt * 16 + l15) * 144 + g4 * 16;
            kf[kt][0] = *(const frag_ab*)kp;
            kf[kt][1] = *(const frag_ab*)(kp + 64);
        }
        frag_ab vf[4][2];
#pragma unroll
        for (int dt = 0; dt < 4; ++dt) {
            int drow = dt * 16 + l15;
            int swz = ((drow >> 3) & 7) << 4;
            const char* vp = (const char*)VT_lds + drow * 144;
            vf[dt][0] = *(const frag_ab*)(vp + ((g4 * 16) ^ swz));
            vf[dt][1] = *(const frag_ab*)(vp + ((g4 * 16 + 64) ^ swz));
        }

#pragma unroll
        for (int qt = 0; qt < 2; ++qt) {
            f32x4 st[4];
            __builtin_amdgcn_s_setprio(1);
#pragma unroll
            for (int kt = 0; kt < 4; ++kt) {
                f32x4 z = (f32x4){0.f, 0.f, 0.f, 0.f};
                z = __builtin_amdgcn_mfma_f32_16x16x32_bf16(kf[kt][0], qf[qt][0], z, 0, 0, 0);
                z = __builtin_amdgcn_mfma_f32_16x16x32_bf16(kf[kt][1], qf[qt][1], z, 0, 0, 0);
                st[kt] = z;
            }
            __builtin_amdgcn_s_setprio(0);
            int qa = cbase + w * 32 + qt * 16 + l15;
            float sv[16];
            float mx = -1e30f;
#pragma unroll
            for (int kt = 0; kt < 4; ++kt)
#pragma unroll
                for (int r = 0; r < 4; ++r) {
                    int ka = k0 + kt * 16 + g4 * 4 + r;
                    float s = st[kt][r] * 0.125f;
                    bool bad = (ka < NG_) | (ka - qa > W_) | (qa - ka > W_);
                    s = bad ? -1e30f : s;
                    sv[kt * 4 + r] = s;
                    mx = fmaxf(mx, s);
                }
            mx = fmaxf(mx, __shfl_xor(mx, 16));
            mx = fmaxf(mx, __shfl_xor(mx, 32));
            float mnew = fmaxf(fmaxf(mrun[qt], mx), -60.0f);
            if (__any(mnew != mrun[qt])) {
                float fsc = __expf(mrun[qt] - mnew);
                mrun[qt] = mnew;
#pragma unroll
                for (int dt = 0; dt < 4; ++dt) o[qt][dt] *= fsc;
                lrun[qt] *= fsc;
            }
            float psum = 0.f;
            unsigned short pb[16];
#pragma unroll
            for (int i = 0; i < 16; ++i) {
                float p = __expf(sv[i] - mrun[qt]);
                psum += p;
                pb[i] = f2bfu(p);
            }
            psum += __shfl_xor(psum, 16);
            psum += __shfl_xor(psum, 32);
            lrun[qt] += psum;
#pragma unroll
            for (int kt = 0; kt < 4; ++kt)
#pragma unroll
                for (int rp = 0; rp < 2; ++rp) {
                    unsigned vpk = (unsigned)pb[kt * 4 + rp * 2] | ((unsigned)pb[kt * 4 + rp * 2 + 1] << 16);
                    int kloc = kt * 16 + g4 * 4 + rp * 2;
                    *(unsigned*)(Pw + l15 * 144 + kloc * 2) = vpk;
                }
            frag_ab pf0 = *(const frag_ab*)(Pw + l15 * 144 + g4 * 16);
            frag_ab pf1 = *(const frag_ab*)(Pw + l15 * 144 + g4 * 16 + 64);
            __builtin_amdgcn_s_setprio(1);
#pragma unroll
            for (int dt = 0; dt < 4; ++dt) {
                o[qt][dt] = __builtin_amdgcn_mfma_f32_16x16x32_bf16(vf[dt][0], pf0, o[qt][dt], 0, 0, 0);
                o[qt][dt] = __builtin_amdgcn_mfma_f32_16x16x32_bf16(vf[dt][1], pf1, o[qt][dt], 0, 0, 0);
            }
            __builtin_amdgcn_s_setprio(0);
        }
    }

    // ---- 3 global keys (unmasked), scalar epilogue ----
    uint4 kgc[3][2];
    uint2 vgd[3][4];
#pragma unroll
    for (int gk = 0; gk < NG_; ++gk) {
        const __hip_bfloat16* kp = K + (size_t)(b * S_ + gk) * D_ + h * DH_ + g4 * 8;
        kgc[gk][0] = *(const uint4*)kp;
        kgc[gk][1] = *(const uint4*)(kp + 32);
        const __hip_bfloat16* vp = V + (size_t)(b * S_ + gk) * D_ + h * DH_ + g4 * 4;
#pragma unroll
        for (int dt = 0; dt < 4; ++dt)
            vgd[gk][dt] = *(const uint2*)(vp + dt * 16);
    }
#pragma unroll
    for (int qt = 0; qt < 2; ++qt) {
        float sg[3];
#pragma unroll
        for (int gk = 0; gk < NG_; ++gk) {
            float part = 0.f;
#pragma unroll
            for (int s = 0; s < 2; ++s) {
                uint4 qw = *(uint4*)&qf[qt][s];
                uint4 kw = kgc[gk][s];
                part += bflo(qw.x) * bflo(kw.x) + bfhi(qw.x) * bfhi(kw.x);
                part += bflo(qw.y) * bflo(kw.y) + bfhi(qw.y) * bfhi(kw.y);
                part += bflo(qw.z) * bflo(kw.z) + bfhi(qw.z) * bfhi(kw.z);
                part += bflo(qw.w) * bflo(kw.w) + bfhi(qw.w) * bfhi(kw.w);
            }
            part += __shfl_xor(part, 16);
            part += __shfl_xor(part, 32);
            sg[gk] = part * 0.125f;
        }
        float mx3 = fmaxf(fmaxf(sg[0], sg[1]), sg[2]);
        float mnew = fmaxf(fmaxf(mrun[qt], mx3), -60.0f);
        float fsc = __expf(mrun[qt] - mnew);
        mrun[qt] = mnew;
#pragma unroll
        for (int dt = 0; dt < 4; ++dt) o[qt][dt] *= fsc;
        lrun[qt] *= fsc;
        float pg[3];
        float psum = 0.f;
#pragma unroll
        for (int gk = 0; gk < NG_; ++gk) { pg[gk] = __expf(sg[gk] - mnew); psum += pg[gk]; }
        lrun[qt] += psum;
#pragma unroll
        for (int dt = 0; dt < 4; ++dt) {
#pragma unroll
            for (int gk = 0; gk < NG_; ++gk) {
                uint2 vv = vgd[gk][dt];
                o[qt][dt][0] += pg[gk] * bflo(vv.x);
                o[qt][dt][1] += pg[gk] * bfhi(vv.x);
                o[qt][dt][2] += pg[gk] * bflo(vv.y);
                o[qt][dt][3] += pg[gk] * bfhi(vv.y);
            }
        }
    }

#pragma unroll
    for (int qt = 0; qt < 2; ++qt) {
        float linv = 1.0f / lrun[qt];
        int qa = cbase + w * 32 + qt * 16 + l15;
        __hip_bfloat16* orow = O + (size_t)(b * S_ + qa) * D_ + h * DH_;
#pragma unroll
        for (int dt = 0; dt < 4; ++dt) {
            unsigned short pk[4];
#pragma unroll
            for (int r = 0; r < 4; ++r) pk[r] = f2bfu(o[qt][dt][r] * linv);
            *(uint2*)(orow + dt * 16 + g4 * 4) = *(uint2*)pk;
        }
    }
}

// ---------------- global attention, split-S flash decode ----------------
__global__ __launch_bounds__(256) void gattn_part_k(
    const float* __restrict__ qg, const __hip_bfloat16* __restrict__ KG,
    const __hip_bfloat16* __restrict__ VG, float* __restrict__ gpart) {
    __shared__ float sc[256];
    __shared__ float qs[DH_];
    __shared__ float red[256];
    __shared__ float rv[16][64];
    int split = blockIdx.x;
    int gh = blockIdx.y;
    int g = gh / H_, h = gh - g * H_;
    int b = blockIdx.z;
    int tid = threadIdx.x;
    if (tid < DH_) qs[tid] = qg[(size_t)(b * NG_ + g) * D_ + h * DH_ + tid] * 0.125f;
    __syncthreads();
    int s0 = split * (S_ / NSPLIT_);
    float acc = 0.f;
    {
        const __hip_bfloat16* kp = KG + (size_t)(b * S_ + s0 + tid) * D_ + h * DH_;
#pragma unroll
        for (int c8 = 0; c8 < 8; ++c8) {
            uint4 t = *(const uint4*)(kp + c8 * 8);
            float f[8]; unp8(t, f);
#pragma unroll
            for (int j = 0; j < 8; ++j) acc += qs[c8 * 8 + j] * f[j];
        }
    }
    float m = block_max(acc, red);
    float e = __expf(acc - m);
    sc[tid] = e;
    float l = block_sum(e, red);
    int sgq = tid >> 4, dq = (tid & 15) * 4;
    float a0 = 0.f, a1 = 0.f, a2 = 0.f, a3 = 0.f;
    const __hip_bfloat16* vbase = VG + (size_t)(b * S_ + s0 + sgq * 16) * D_ + h * DH_ + dq;
#pragma unroll
    for (int i = 0; i < 16; ++i) {
        float p = sc[sgq * 16 + i];
        uint2 vv = *(const uint2*)(vbase + (size_t)i * D_);
        a0 += p * bflo(vv.x); a1 += p * bfhi(vv.x);
        a2 += p * bflo(vv.y); a3 += p * bfhi(vv.y);
    }
    rv[sgq][dq] = a0; rv[sgq][dq + 1] = a1; rv[sgq][dq + 2] = a2; rv[sgq][dq + 3] = a3;
    __syncthreads();
    float* op = gpart + ((size_t)((b * NG_ + g) * H_ + h) * NSPLIT_ + split) * 66;
    if (tid == 0) { op[0] = m; op[1] = l; }
    if (tid < DH_) {
        float s = 0.f;
#pragma unroll
        for (int j = 0; j < 16; ++j) s += rv[j][tid];
        op[2 + tid] = s;
    }
}

template <typename TO>
__global__ __launch_bounds__(64) void gattn_comb_k(
    const float* __restrict__ gpart, TO* __restrict__ outp, int rowStride) {
    int g = blockIdx.x, h = blockIdx.y, b = blockIdx.z;
    int tid = threadIdx.x;
    const float* base = gpart + (size_t)((b * NG_ + g) * H_ + h) * NSPLIT_ * 66;
    float M = -1e30f;
#pragma unroll
    for (int p = 0; p < NSPLIT_; ++p) M = fmaxf(M, base[p * 66]);
    float l = 0.f, o = 0.f;
#pragma unroll
    for (int p = 0; p < NSPLIT_; ++p) {
        float wgt = __expf(base[p * 66] - M);
        l += wgt * base[p * 66 + 1];
        o += wgt * base[p * 66 + 2 + tid];
    }
    storeO(&outp[(size_t)(b * rowStride + g) * D_ + h * DH_ + tid], o / l);
}

// ---------------- gather the 6 global-token rows ----------------
__global__ void gather6_k(const float* __restrict__ X, float* __restrict__ xg) {
    int r = blockIdx.x;
    int b = r / NG_, g = r % NG_;
    for (int c = threadIdx.x; c < D_; c += blockDim.x)
        xg[(size_t)r * D_ + c] = X[(size_t)(b * S_ + g) * D_ + c];
}

// ---------------- classifier heads ----------------
__global__ __launch_bounds__(256) void classifier_k(
    const float* __restrict__ x26, const float* __restrict__ cw,
    const float* __restrict__ cb, float* __restrict__ out) {
    __shared__ float red[256];
    int tid = threadIdx.x;
    for (int i = 0; i < 3; ++i) {
        for (int b = 0; b < B_; ++b) {
            const float* xr = x26 + (size_t)(b * NG_ + i) * D_;
            const float* wr = cw + (size_t)i * D_;
            float p = 0.f;
            for (int c = tid; c < D_; c += 256) p += xr[c] * wr[c];
            float dotv = block_sum(p, red);
            if (tid == 0) out[i * B_ + b] = 1.0f / (1.0f + __expf(-(dotv + cb[i])));
        }
    }
    if (tid == 0) { out[6] = 1.0f; out[7] = 1.0f; }
}

// ---------------- host launcher ----------------
extern "C" void kernel_launch(void* const* d_in, const int* in_sizes, int n_in,
                              void* d_out, int out_size, void* d_ws, size_t ws_size,
                              hipStream_t stream) {
    const int*   src      = (const int*)d_in[0];
    const float* word_emb = (const float*)d_in[3];
    const float* pos_emb  = (const float*)d_in[4];
    const float* emb_ln   = (const float*)d_in[5];
    const float* attn_w   = (const float*)d_in[6];
    const float* attn_b   = (const float*)d_in[7];
    const float* ln_p     = (const float*)d_in[8];
    const float* ffn_w1   = (const float*)d_in[9];
    const float* ffn_b1   = (const float*)d_in[10];
    const float* ffn_w2   = (const float*)d_in[11];
    const float* ffn_b2   = (const float*)d_in[12];
    const float* cls_w    = (const float*)d_in[13];
    const float* cls_b    = (const float*)d_in[14];
    float* out = (float*)d_out;

    const size_t NT = (size_t)B_ * S_ * D_;  // 6291456 elements
    // -------- workspace layout (floats), NO overlaps --------
    // X[0,NT) P4[NT,2NT) Xb[2NT,2.5NT) Q/K/V/KG/VG[2.5NT,5NT) AOb[5NT,5.5NT)
    // HCb[5.5NT,7.5NT)  (8192x3072 bf16 = 2NT floats!)  pj1[7.5NT,8.5NT) pj2[8.5NT,9.5NT)
    // weights >= 9.5NT
    float* base = (float*)d_ws;
    float* X  = base;
    float* P4 = base + NT;
    __hip_bfloat16* Xb  = (__hip_bfloat16*)(base + 2 * NT);
    __hip_bfloat16* Qb  = (__hip_bfloat16*)(base + 5 * NT / 2);
    __hip_bfloat16* Kb  = (__hip_bfloat16*)(base + 3 * NT);
    __hip_bfloat16* Vb  = (__hip_bfloat16*)(base + 7 * NT / 2);
    __hip_bfloat16* KGb = (__hip_bfloat16*)(base + 4 * NT);
    __hip_bfloat16* VGb = (__hip_bfloat16*)(base + 9 * NT / 2);
    __hip_bfloat16* AOb = (__hip_bfloat16*)(base + 5 * NT);
    __hip_bfloat16* HCb = (__hip_bfloat16*)(base + 11 * NT / 2);   // 2NT floats
    float* pj1 = base + 15 * NT / 2;
    float* pj2 = base + 17 * NT / 2;
    __hip_bfloat16* wq5 = (__hip_bfloat16*)(base + 19 * NT / 2);   // 5 x 768x768
    __hip_bfloat16* wo  = wq5 + 5 * 589824;
    __hip_bfloat16* wg1 = wo + 589824;                  // layer-1 kg/vg pair
    __hip_bfloat16* wf1 = wg1 + 2 * 589824;             // 3072x768
    __hip_bfloat16* wf2 = wf1 + 2359296;                // 768x3072
    float* SM  = (float*)(wf2 + 2359296);
    float* xg  = SM;
    float* qg6 = xg + 6 * D_;
    float* og6 = qg6 + 6 * D_;
    float* pr6 = og6 + 6 * D_;
    float* xa6 = pr6 + 6 * D_;
    float* h6  = xa6 + 6 * D_;
    float* f6  = h6 + 6 * FF_;
    float* x26 = f6 + 6 * D_;
    float* bias5 = x26 + 6 * D_;        // 3840
    float* part = bias5 + 5 * D_;       // split-K skinny partials
    float* gpart = part;                // aliased (never live simultaneously)

    const int M = B_ * S_;
    dim3 blk(256);

    auto aw = [&](int l, int i) { return attn_w + ((size_t)(l * 7 + i)) * D_ * D_; };
    auto ab = [&](int l, int i) { return attn_b + (size_t)(l * 7 + i) * D_; };
    auto lnp = [&](int l, int i) { return ln_p + (size_t)(l * 4 + i) * D_; };

    auto skinny = [&](const float* A6, const float* Wm, const float* bias,
                      float* out6, int N, int K, int gelu) {
        skinny_gemm_k<<<dim3(N / 64, K / 64), blk, 0, stream>>>(A6, Wm, part, N, K);
        skinny_reduce_k<<<dim3((6 * N + 255) / 256), blk, 0, stream>>>(part, bias, out6, N, K / 64, gelu);
    };

    embed_ln_k<<<M, blk, 0, stream>>>(src, word_emb, pos_emb, emb_ln, emb_ln + D_, X, Xb);

    // ================= layer 0 =================
    // mega projection: [Q,K,V,KG,VG] = Xb @ [wq wk wv wg1 wg2]^T  (N=3840)
    convt_k<<<dim3(24 * 3, 24), blk, 0, stream>>>(aw(0, 0), wq5, D_, D_, 24);
    convt_k<<<dim3(24 * 2, 24), blk, 0, stream>>>(aw(0, 4), wq5 + 3 * 589824, D_, D_, 24);
    pack_bias_k<<<15, blk, 0, stream>>>(ab(0, 0), bias5);
    mfma_gemm_k<1, 1><<<dim3(3840 / 128, 64), blk, 0, stream>>>(Xb, wq5, bias5, Qb, M, 3840, D_, NT);
    local_attn_k<<<dim3(S_ / QB_, H_, B_), blk, 0, stream>>>(Qb, Kb, Vb, AOb);
    gather6_k<<<B_ * NG_, blk, 0, stream>>>(X, xg);
    skinny(xg, aw(0, 3), ab(0, 3), qg6, D_, D_, 0);
    gattn_part_k<<<dim3(NSPLIT_, NG_ * H_, B_), blk, 0, stream>>>(qg6, KGb, VGb, gpart);
    gattn_comb_k<__hip_bfloat16><<<dim3(NG_, H_, B_), dim3(64), 0, stream>>>(gpart, AOb, S_);
    // attn output projection, split-K x2 -> pj1/pj2, combined in residual LN
    convt_k<<<dim3(24, 24), blk, 0, stream>>>(aw(0, 6), wo, D_, D_, 24);
    mfma_gemm_k<0, 0><<<dim3(6, 64, 2), blk, 0, stream>>>(AOb, wo, ab(0, 6), pj1, M, D_, D_, 0);
    residual_ln_k<<<M, blk, 0, stream>>>(X, pj1, pj2, lnp(0, 0), lnp(0, 1), P4, Xb);
    // FFN (full-M)
    convt_k<<<dim3(96, 24), blk, 0, stream>>>(ffn_w1, wf1, D_, FF_, 96);
    convt_k<<<dim3(24, 96), blk, 0, stream>>>(ffn_w2, wf2, FF_, D_, 24);
    mfma_gemm_k<2, 0><<<dim3(24, 64), blk, 0, stream>>>(Xb, wf1, ffn_b1, HCb, M, FF_, D_, 0);
    mfma_gemm_k<0, 0><<<dim3(6, 64, 2), blk, 0, stream>>>(HCb, wf2, ffn_b2, pj1, M, D_, FF_, 0);
    residual_ln_k<<<M, blk, 0, stream>>>(P4, pj1, pj2, lnp(0, 2), lnp(0, 3), X, Xb);

    // ================= layer 1 (pruned) =================
    convt_k<<<dim3(24 * 2, 24), blk, 0, stream>>>(aw(1, 4), wg1, D_, D_, 24);
    mfma_gemm_k<1, 1><<<dim3(1536 / 128, 64), blk, 0, stream>>>(Xb, wg1, ab(1, 4), KGb, M, 1536, D_, NT);
    gather6_k<<<B_ * NG_, blk, 0, stream>>>(X, xg);
    skinny(xg, aw(1, 3), ab(1, 3), qg6, D_, D_, 0);
    gattn_part_k<<<dim3(NSPLIT_, NG_ * H_, B_), blk, 0, stream>>>(qg6, KGb, VGb, gpart);
    gattn_comb_k<float><<<dim3(NG_, H_, B_), dim3(64), 0, stream>>>(gpart, og6, NG_);
    skinny(og6, aw(1, 6), ab(1, 6), pr6, D_, D_, 0);
    residual_ln_k<<<B_ * NG_, blk, 0, stream>>>(xg, pr6, nullptr, lnp(1, 0), lnp(1, 1), xa6, nullptr);
    skinny(xa6, ffn_w1 + (size_t)D_ * FF_, ffn_b1 + FF_, h6, FF_, D_, 1);
    skinny(h6, ffn_w2 + (size_t)FF_ * D_, ffn_b2 + D_, f6, D_, FF_, 0);
    residual_ln_k<<<B_ * NG_, blk, 0, stream>>>(xa6, f6, nullptr, lnp(1, 2), lnp(1, 3), x26, nullptr);
    classifier_k<<<1, blk, 0, stream>>>(x26, cls_w, cls_b, out);
}